// Round 2
// 936.170 us; speedup vs baseline: 1.0570x; 1.0570x over previous
//
#include <hip/hip_runtime.h>
#include <hip/hip_bf16.h>

// Problem constants
#define B_ 4
#define S1_ 64
#define S2_ 256
#define D_ 256
#define H_ 8
#define HD_ 32
#define F_ 1024
#define EPS_ 1e-5f
#define NEG_ 0.01f

typedef __attribute__((ext_vector_type(8))) short bfrag;   // 8 x bf16 (4 VGPRs)
typedef __attribute__((ext_vector_type(4))) float f32x4;   // MFMA C/D
typedef __attribute__((ext_vector_type(8))) unsigned short us8;

__device__ __forceinline__ unsigned short bf16rn(float f) {
    union { float f; unsigned int u; } c; c.f = f;
    unsigned int u = c.u;
    u = (u + 0x7FFFu + ((u >> 16) & 1u)) >> 16;   // round-to-nearest-even
    return (unsigned short)u;
}
__device__ __forceinline__ float bf2f(unsigned short s) {
    union { unsigned int u; float f; } c; c.u = ((unsigned int)s) << 16;
    return c.f;
}

// ---------------------------------------------------------------------------
// Weight transpose+cast: Wq/Wk [s][i][c] -> Wqk_bt [n=512][k=768] (n<256: q)
//                        Wv [i][c]      -> Wv_bt  [n=256][k=256]
// ---------------------------------------------------------------------------
__global__ __launch_bounds__(256) void k_cvt_qkv(
    const float* __restrict__ Wq, const float* __restrict__ Wk,
    const float* __restrict__ Wv,
    unsigned short* __restrict__ Wqk_bt, unsigned short* __restrict__ Wv_bt)
{
    const int blk = blockIdx.x;      // 0..767
    const int i   = threadIdx.x;     // 0..255 (in-channel)
    if (blk < 256) {
        const int n = blk;
        #pragma unroll
        for (int s = 0; s < 3; ++s)
            Wqk_bt[(size_t)n * 768 + s * 256 + i] = bf16rn(Wq[((size_t)s * 256 + i) * 256 + n]);
    } else if (blk < 512) {
        const int n = blk; const int c = blk - 256;
        #pragma unroll
        for (int s = 0; s < 3; ++s)
            Wqk_bt[(size_t)n * 768 + s * 256 + i] = bf16rn(Wk[((size_t)s * 256 + i) * 256 + c]);
    } else {
        const int c = blk - 512;
        Wv_bt[(size_t)c * 256 + i] = bf16rn(Wv[(size_t)i * 256 + c]);
    }
}

// Wo [k][n] -> Wo_bt [n=256][k=256]; W1 [k][n] -> W1bt [n=1024][k=256];
// W2 [f][d] -> W2bt [d=256][f=1024]
__global__ __launch_bounds__(256) void k_cvt_proj(
    const float* __restrict__ Wo, const float* __restrict__ W1,
    const float* __restrict__ W2,
    unsigned short* __restrict__ Wo_bt, unsigned short* __restrict__ W1bt,
    unsigned short* __restrict__ W2bt)
{
    const int blk = blockIdx.x;      // 0..1535
    const int t   = threadIdx.x;
    if (blk < 256) {
        Wo_bt[(size_t)blk * 256 + t] = bf16rn(Wo[(size_t)t * 256 + blk]);
    } else if (blk < 1280) {
        const int n = blk - 256;     // 0..1023
        W1bt[(size_t)n * 256 + t] = bf16rn(W1[(size_t)t * F_ + n]);
    } else {
        const int d = blk - 1280;    // 0..255
        for (int f = t; f < F_; f += 256)
            W2bt[(size_t)d * F_ + f] = bf16rn(W2[(size_t)f * D_ + d]);
    }
}

// ---------------------------------------------------------------------------
// Kernel 1: q/k time-conv + v projection as bf16 MFMA GEMM. (unchanged)
// ---------------------------------------------------------------------------
__global__ __launch_bounds__(256) void k_qkv_mfma(
    const float* __restrict__ x,
    const unsigned short* __restrict__ Wqk_bt,
    const unsigned short* __restrict__ Wv_bt,
    const float* __restrict__ bq, const float* __restrict__ bk,
    const float* __restrict__ bv,
    unsigned short* __restrict__ qb, unsigned short* __restrict__ kb,
    unsigned short* __restrict__ vb)
{
    __shared__ __align__(16) unsigned short xA[34][264];
    const int tid  = threadIdx.x;
    const int w    = tid >> 6;
    const int lane = tid & 63;
    const int col  = lane & 15;
    const int q4   = lane >> 4;
    const int bn   = blockIdx.x >> 3;           // (b*S1+n)
    const int t0   = (blockIdx.x & 7) * 32;
    const float* xb = x + (size_t)bn * S2_ * D_;

    for (int r = 0; r < 34; ++r) {
        const int t = t0 - 1 + r;
        xA[r][tid] = (t >= 0 && t < S2_) ? bf16rn(xb[(size_t)t * D_ + tid])
                                         : (unsigned short)0;
    }
    __syncthreads();

    // ---- q/k: K = 768, shift-major ----
    f32x4 accqk[8][2];
    #pragma unroll
    for (int t = 0; t < 8; ++t)
        #pragma unroll
        for (int mt = 0; mt < 2; ++mt)
            accqk[t][mt] = (f32x4){0.f, 0.f, 0.f, 0.f};

    for (int s = 0; s < 3; ++s) {
        bfrag a[2][8];
        #pragma unroll
        for (int mt = 0; mt < 2; ++mt)
            #pragma unroll
            for (int kc = 0; kc < 8; ++kc)
                a[mt][kc] = *(const bfrag*)&xA[mt * 16 + col + s][kc * 32 + q4 * 8];

        for (int t = 0; t < 8; ++t) {
            const unsigned short* bp =
                Wqk_bt + (size_t)((w * 8 + t) * 16 + col) * 768 + s * 256 + q4 * 8;
            #pragma unroll
            for (int kc = 0; kc < 8; ++kc) {
                bfrag b = *(const bfrag*)(bp + kc * 32);
                accqk[t][0] = __builtin_amdgcn_mfma_f32_16x16x32_bf16(a[0][kc], b, accqk[t][0], 0, 0, 0);
                accqk[t][1] = __builtin_amdgcn_mfma_f32_16x16x32_bf16(a[1][kc], b, accqk[t][1], 0, 0, 0);
            }
        }
    }

    #pragma unroll
    for (int t = 0; t < 8; ++t) {
        const int n = (w * 8 + t) * 16 + col;   // 0..511
        const float bias = (n < 256) ? bq[n] : bk[n - 256];
        unsigned short* dst = (n < 256) ? qb : kb;
        const int c = n & 255;
        #pragma unroll
        for (int mt = 0; mt < 2; ++mt)
            #pragma unroll
            for (int r = 0; r < 4; ++r)
                dst[((size_t)bn * S2_ + t0 + mt * 16 + q4 * 4 + r) * D_ + c]
                    = bf16rn(accqk[t][mt][r] + bias);
    }

    // ---- v: K = 256, center shift ----
    f32x4 accv[4][2];
    #pragma unroll
    for (int t = 0; t < 4; ++t) {
        accv[t][0] = (f32x4){0.f, 0.f, 0.f, 0.f};
        accv[t][1] = (f32x4){0.f, 0.f, 0.f, 0.f};
    }
    bfrag a1[2][8];
    #pragma unroll
    for (int mt = 0; mt < 2; ++mt)
        #pragma unroll
        for (int kc = 0; kc < 8; ++kc)
            a1[mt][kc] = *(const bfrag*)&xA[mt * 16 + col + 1][kc * 32 + q4 * 8];

    for (int t = 0; t < 4; ++t) {
        const unsigned short* bp =
            Wv_bt + (size_t)((w * 4 + t) * 16 + col) * 256 + q4 * 8;
        #pragma unroll
        for (int kc = 0; kc < 8; ++kc) {
            bfrag b = *(const bfrag*)(bp + kc * 32);
            accv[t][0] = __builtin_amdgcn_mfma_f32_16x16x32_bf16(a1[0][kc], b, accv[t][0], 0, 0, 0);
            accv[t][1] = __builtin_amdgcn_mfma_f32_16x16x32_bf16(a1[1][kc], b, accv[t][1], 0, 0, 0);
        }
    }

    #pragma unroll
    for (int t = 0; t < 4; ++t) {
        const int c = (w * 4 + t) * 16 + col;
        const float bias = bv[c];
        #pragma unroll
        for (int mt = 0; mt < 2; ++mt)
            #pragma unroll
            for (int r = 0; r < 4; ++r)
                vb[((size_t)bn * S2_ + t0 + mt * 16 + q4 * 4 + r) * D_ + c]
                    = bf16rn(accv[t][mt][r] + bias);
    }
}

// ---------------------------------------------------------------------------
// Kernel 2: MFMA attention. (unchanged)
// ---------------------------------------------------------------------------
__global__ __launch_bounds__(256) void k_attn_mfma(
    const unsigned short* __restrict__ qb, const unsigned short* __restrict__ kb,
    const unsigned short* __restrict__ vb, unsigned short* __restrict__ ob)
{
    __shared__ __align__(16) unsigned short Ks[256][40];   // keys, pad->bank spread
    __shared__ __align__(16) unsigned short Vt[32][264];   // V transposed [d][s]
    __shared__ __align__(16) unsigned short Pw[4][16][264];// per-wave P scratch

    const int bn   = blockIdx.x;
    const int h    = blockIdx.y;
    const int tid  = threadIdx.x;
    const int w    = tid >> 6;
    const int lane = tid & 63;
    const int col  = lane & 15;
    const int q4   = lane >> 4;
    const size_t base = (size_t)bn * S2_ * D_ + h * HD_;
    const float SCALE = 0.17677669529663687f;   // 1/sqrt(32)

    // ---- stage K rows (coalesced 64B/row) ----
    {
        const unsigned short* kr = kb + base + (size_t)tid * D_;
        #pragma unroll
        for (int j = 0; j < 4; ++j)
            *(us8*)&Ks[tid][j * 8] = *(const us8*)(kr + j * 8);
    }
    // ---- stage V transposed: thread (dv, sg) covers d=dv, s=sg*32..+31 ----
    {
        const int dv = tid & 31, sg = tid >> 5;
        for (int i = 0; i < 32; ++i) {
            const int s = sg * 32 + i;
            Vt[dv][s] = vb[base + (size_t)s * D_ + dv];
        }
    }
    __syncthreads();

    // ---- Q fragments direct from global (A-layout) ----
    const int r0w = w * 64;
    bfrag qa[4];
    #pragma unroll
    for (int mt = 0; mt < 4; ++mt)
        qa[mt] = *(const bfrag*)(qb + base + (size_t)(r0w + mt * 16 + col) * D_ + q4 * 8);

    for (int mt = 0; mt < 4; ++mt) {
        // ---- scores: 16 n-tiles, one MFMA each (K=32 = full HD) ----
        f32x4 sc[16];
        #pragma unroll
        for (int nt = 0; nt < 16; ++nt) {
            bfrag b = *(const bfrag*)&Ks[nt * 16 + col][q4 * 8];
            f32x4 z = {0.f, 0.f, 0.f, 0.f};
            sc[nt] = __builtin_amdgcn_mfma_f32_16x16x32_bf16(qa[mt], b, z, 0, 0, 0);
        }

        // ---- softmax over 256 cols; row r_global = r0w+mt*16+q4*4+r ----
        float mx[4] = {-1e30f, -1e30f, -1e30f, -1e30f};
        #pragma unroll
        for (int nt = 0; nt < 16; ++nt)
            #pragma unroll
            for (int r = 0; r < 4; ++r) {
                sc[nt][r] *= SCALE;
                mx[r] = fmaxf(mx[r], sc[nt][r]);
            }
        #pragma unroll
        for (int r = 0; r < 4; ++r) {
            mx[r] = fmaxf(mx[r], __shfl_xor(mx[r], 1));
            mx[r] = fmaxf(mx[r], __shfl_xor(mx[r], 2));
            mx[r] = fmaxf(mx[r], __shfl_xor(mx[r], 4));
            mx[r] = fmaxf(mx[r], __shfl_xor(mx[r], 8));
        }
        float l[4] = {0.f, 0.f, 0.f, 0.f};
        #pragma unroll
        for (int nt = 0; nt < 16; ++nt)
            #pragma unroll
            for (int r = 0; r < 4; ++r) {
                const float e = __expf(sc[nt][r] - mx[r]);
                sc[nt][r] = e;
                l[r] += e;
            }
        #pragma unroll
        for (int r = 0; r < 4; ++r) {
            l[r] += __shfl_xor(l[r], 1);
            l[r] += __shfl_xor(l[r], 2);
            l[r] += __shfl_xor(l[r], 4);
            l[r] += __shfl_xor(l[r], 8);
        }

        // ---- P -> per-wave LDS (bf16), even-lane packed u32 writes ----
        #pragma unroll
        for (int nt = 0; nt < 16; ++nt)
            #pragma unroll
            for (int r = 0; r < 4; ++r) {
                const float p  = sc[nt][r];
                const float po = __shfl_xor(p, 1);
                if ((lane & 1) == 0) {
                    const unsigned int packed =
                        (unsigned int)bf16rn(p) | ((unsigned int)bf16rn(po) << 16);
                    *(unsigned int*)&Pw[w][q4 * 4 + r][nt * 16 + col] = packed;
                }
            }
        // same-wave DS ordering: reads below see the writes (in-order DS pipe)

        // ---- PV: o[16 x 32] ----
        f32x4 oacc[2];
        oacc[0] = (f32x4){0.f, 0.f, 0.f, 0.f};
        oacc[1] = (f32x4){0.f, 0.f, 0.f, 0.f};
        #pragma unroll
        for (int kc = 0; kc < 8; ++kc) {
            bfrag pa = *(const bfrag*)&Pw[w][col][kc * 32 + q4 * 8];
            #pragma unroll
            for (int dt = 0; dt < 2; ++dt) {
                bfrag b = *(const bfrag*)&Vt[dt * 16 + col][kc * 32 + q4 * 8];
                oacc[dt] = __builtin_amdgcn_mfma_f32_16x16x32_bf16(pa, b, oacc[dt], 0, 0, 0);
            }
        }

        // ---- normalize + write ----
        float inv[4];
        #pragma unroll
        for (int r = 0; r < 4; ++r) inv[r] = 1.f / l[r];
        #pragma unroll
        for (int dt = 0; dt < 2; ++dt)
            #pragma unroll
            for (int r = 0; r < 4; ++r)
                ob[base + (size_t)(r0w + mt * 16 + q4 * 4 + r) * D_ + dt * 16 + col]
                    = bf16rn(oacc[dt][r] * inv[r]);
    }
}

// ---------------------------------------------------------------------------
// Kernel 3: o @ Wo + bo + residual(x) -> LN(g1,be1) -> h (fp32 out), MFMA.
// (unchanged)
// ---------------------------------------------------------------------------
__global__ __launch_bounds__(256) void k_oproj_mfma(
    const float* __restrict__ x, const unsigned short* __restrict__ ob,
    const unsigned short* __restrict__ Wo_bt, const float* __restrict__ bo,
    const float* __restrict__ g1, const float* __restrict__ be1,
    float* __restrict__ hout)
{
    __shared__ __align__(16) unsigned short oA[32][264];
    __shared__ float yS[32][260];
    __shared__ float red[32][8][2];
    __shared__ float mu_s[32], rs_s[32];

    const int tid  = threadIdx.x;
    const int w    = tid >> 6;
    const int lane = tid & 63;
    const int col  = lane & 15;
    const int q4   = lane >> 4;
    const size_t tok0 = (size_t)blockIdx.x * 32;

    for (int i = 0; i < 32; ++i)
        oA[i][tid] = ob[(tok0 + i) * D_ + tid];
    __syncthreads();

    bfrag a[2][8];
    #pragma unroll
    for (int mt = 0; mt < 2; ++mt)
        #pragma unroll
        for (int kc = 0; kc < 8; ++kc)
            a[mt][kc] = *(const bfrag*)&oA[mt * 16 + col][kc * 32 + q4 * 8];

    f32x4 acc[4][2];
    #pragma unroll
    for (int t = 0; t < 4; ++t) {
        acc[t][0] = (f32x4){0.f, 0.f, 0.f, 0.f};
        acc[t][1] = (f32x4){0.f, 0.f, 0.f, 0.f};
    }

    for (int t = 0; t < 4; ++t) {
        const unsigned short* bp =
            Wo_bt + (size_t)((w * 4 + t) * 16 + col) * 256 + q4 * 8;
        #pragma unroll
        for (int kc = 0; kc < 8; ++kc) {
            bfrag b = *(const bfrag*)(bp + kc * 32);
            acc[t][0] = __builtin_amdgcn_mfma_f32_16x16x32_bf16(a[0][kc], b, acc[t][0], 0, 0, 0);
            acc[t][1] = __builtin_amdgcn_mfma_f32_16x16x32_bf16(a[1][kc], b, acc[t][1], 0, 0, 0);
        }
    }

    #pragma unroll
    for (int t = 0; t < 4; ++t) {
        const int n = (w * 4 + t) * 16 + col;
        #pragma unroll
        for (int mt = 0; mt < 2; ++mt)
            #pragma unroll
            for (int r = 0; r < 4; ++r)
                yS[mt * 16 + q4 * 4 + r][n] = acc[t][mt][r];
    }
    __syncthreads();

    const float bod = bo[tid];
    for (int i = 0; i < 32; ++i)
        yS[i][tid] = yS[i][tid] + bod + x[(tok0 + i) * D_ + tid];
    __syncthreads();

    {
        const int tok = tid >> 3, p = tid & 7;
        float s = 0.f, s2 = 0.f;
        for (int d = p * 32; d < p * 32 + 32; ++d) {
            const float vv = yS[tok][d];
            s += vv; s2 = fmaf(vv, vv, s2);
        }
        red[tok][p][0] = s; red[tok][p][1] = s2;
    }
    __syncthreads();
    if (tid < 32) {
        float s = 0.f, s2 = 0.f;
        #pragma unroll
        for (int p = 0; p < 8; ++p) { s += red[tid][p][0]; s2 += red[tid][p][1]; }
        const float mu  = s * (1.f / 256.f);
        const float var = s2 * (1.f / 256.f) - mu * mu;
        mu_s[tid] = mu;
        rs_s[tid] = rsqrtf(var + EPS_);
    }
    __syncthreads();

    const float g = g1[tid], be = be1[tid];
    for (int i = 0; i < 32; ++i)
        hout[(tok0 + i) * D_ + tid] = (yS[i][tid] - mu_s[i]) * rs_s[i] * g + be;
}

// ---------------------------------------------------------------------------
// Kernel 4a: GEMM1 of FFN.  ff = leaky(h @ W1 + b1)  (bf16 out)
// M=65536, N=1024, K=256.  BM=128, BN=256, BK=64. 4 waves, each 64x128.
// Padded LDS (stride 72 bf16 = 144 B).
// ---------------------------------------------------------------------------
__global__ __launch_bounds__(256) void k_ffn1_gemm(
    const float* __restrict__ h,
    const unsigned short* __restrict__ W1bt, const float* __restrict__ b1,
    unsigned short* __restrict__ ff)
{
    __shared__ __align__(16) unsigned short As[128][72];
    __shared__ __align__(16) unsigned short Bs[256][72];

    const int tid  = threadIdx.x;
    const int w    = tid >> 6;
    const int lane = tid & 63;
    const int col  = lane & 15;
    const int q4   = lane >> 4;
    const int wr   = w >> 1;         // 0..1  (row half of C tile)
    const int wc   = w & 1;          // 0..1  (col half of C tile)
    const size_t tok0 = (size_t)blockIdx.x * 128;
    const int n0 = blockIdx.y * 256;

    f32x4 acc[4][8];
    #pragma unroll
    for (int m = 0; m < 4; ++m)
        #pragma unroll
        for (int n = 0; n < 8; ++n)
            acc[m][n] = (f32x4){0.f, 0.f, 0.f, 0.f};

    const int arow  = tid >> 1;
    const int ahalf = (tid & 1) * 32;

    for (int k0 = 0; k0 < 256; k0 += 64) {
        // ---- stage A (fp32 -> bf16), 128x64; 2 threads/row, 32 shorts each ----
        const float* ap = h + (tok0 + arow) * 256 + k0 + ahalf;
        #pragma unroll
        for (int j = 0; j < 4; ++j) {
            float4 f0 = *(const float4*)(ap + j * 8);
            float4 f1 = *(const float4*)(ap + j * 8 + 4);
            us8 v;
            v[0] = bf16rn(f0.x); v[1] = bf16rn(f0.y);
            v[2] = bf16rn(f0.z); v[3] = bf16rn(f0.w);
            v[4] = bf16rn(f1.x); v[5] = bf16rn(f1.y);
            v[6] = bf16rn(f1.z); v[7] = bf16rn(f1.w);
            *(us8*)&As[arow][ahalf + j * 8] = v;
        }
        // ---- stage B (bf16), 256x64; 1 thread/row, FULL 64 shorts ----
        const unsigned short* bp = W1bt + (size_t)(n0 + tid) * 256 + k0;
        #pragma unroll
        for (int j = 0; j < 8; ++j)
            *(us8*)&Bs[tid][j * 8] = *(const us8*)(bp + j * 8);
        __syncthreads();

        #pragma unroll
        for (int kk = 0; kk < 2; ++kk) {
            bfrag a[4], b[8];
            #pragma unroll
            for (int m = 0; m < 4; ++m)
                a[m] = *(const bfrag*)&As[wr * 64 + m * 16 + col][kk * 32 + q4 * 8];
            #pragma unroll
            for (int n = 0; n < 8; ++n)
                b[n] = *(const bfrag*)&Bs[wc * 128 + n * 16 + col][kk * 32 + q4 * 8];
            #pragma unroll
            for (int n = 0; n < 8; ++n)
                #pragma unroll
                for (int m = 0; m < 4; ++m)
                    acc[m][n] = __builtin_amdgcn_mfma_f32_16x16x32_bf16(a[m], b[n], acc[m][n], 0, 0, 0);
        }
        __syncthreads();
    }

    // ---- epilogue: + b1, leaky, bf16 store ----
    #pragma unroll
    for (int n = 0; n < 8; ++n) {
        const int nn = n0 + wc * 128 + n * 16 + col;
        const float bb = b1[nn];
        #pragma unroll
        for (int m = 0; m < 4; ++m)
            #pragma unroll
            for (int r = 0; r < 4; ++r) {
                float v = acc[m][n][r] + bb;
                v = (v > 0.f) ? v : NEG_ * v;
                ff[(tok0 + wr * 64 + m * 16 + q4 * 4 + r) * (size_t)F_ + nn] = bf16rn(v);
            }
    }
}

// ---------------------------------------------------------------------------
// Kernel 4b: GEMM2 of FFN + bias + residual + LN2 fused.
// out = LN(ff @ W2 + b2 + h).  M=65536, N=256 (full row), K=1024.
// BM=128, BN=256, BK=64. 4 waves, each 64x128. In-register LN stats.
// ---------------------------------------------------------------------------
__global__ __launch_bounds__(256) void k_ffn2_gemm(
    const unsigned short* __restrict__ ff,
    const unsigned short* __restrict__ W2bt, const float* __restrict__ b2,
    const float* __restrict__ h,
    const float* __restrict__ g2, const float* __restrict__ be2,
    float* __restrict__ out)
{
    __shared__ __align__(16) unsigned short As[128][72];
    __shared__ __align__(16) unsigned short Bs[256][72];
    __shared__ float red[128][2][2];   // [row][wc][{sum,sumsq}]

    const int tid  = threadIdx.x;
    const int w    = tid >> 6;
    const int lane = tid & 63;
    const int col  = lane & 15;
    const int q4   = lane >> 4;
    const int wr   = w >> 1;
    const int wc   = w & 1;
    const size_t tok0 = (size_t)blockIdx.x * 128;

    f32x4 acc[4][8];
    #pragma unroll
    for (int m = 0; m < 4; ++m)
        #pragma unroll
        for (int n = 0; n < 8; ++n)
            acc[m][n] = (f32x4){0.f, 0.f, 0.f, 0.f};

    const int arow  = tid >> 1;
    const int ahalf = (tid & 1) * 32;

    for (int k0 = 0; k0 < 1024; k0 += 64) {
        // ---- stage A (ff, already bf16), 128x64; 2 threads/row ----
        const unsigned short* ap = ff + (tok0 + arow) * (size_t)F_ + k0 + ahalf;
        #pragma unroll
        for (int j = 0; j < 4; ++j)
            *(us8*)&As[arow][ahalf + j * 8] = *(const us8*)(ap + j * 8);
        // ---- stage B (W2bt [d][f]), 256x64; 1 thread/row, FULL 64 shorts ----
        const unsigned short* bp = W2bt + (size_t)tid * F_ + k0;
        #pragma unroll
        for (int j = 0; j < 8; ++j)
            *(us8*)&Bs[tid][j * 8] = *(const us8*)(bp + j * 8);
        __syncthreads();

        #pragma unroll
        for (int kk = 0; kk < 2; ++kk) {
            bfrag a[4], b[8];
            #pragma unroll
            for (int m = 0; m < 4; ++m)
                a[m] = *(const bfrag*)&As[wr * 64 + m * 16 + col][kk * 32 + q4 * 8];
            #pragma unroll
            for (int n = 0; n < 8; ++n)
                b[n] = *(const bfrag*)&Bs[wc * 128 + n * 16 + col][kk * 32 + q4 * 8];
            #pragma unroll
            for (int n = 0; n < 8; ++n)
                #pragma unroll
                for (int m = 0; m < 4; ++m)
                    acc[m][n] = __builtin_amdgcn_mfma_f32_16x16x32_bf16(a[m], b[n], acc[m][n], 0, 0, 0);
        }
        __syncthreads();
    }

    // ---- epilogue: y = acc + b2 + h(residual); LN over 256 cols ----
    float b2v[8];
    #pragma unroll
    for (int n = 0; n < 8; ++n)
        b2v[n] = b2[wc * 128 + n * 16 + col];

    float s[4][4], s2[4][4];
    #pragma unroll
    for (int m = 0; m < 4; ++m)
        #pragma unroll
        for (int r = 0; r < 4; ++r) { s[m][r] = 0.f; s2[m][r] = 0.f; }

    #pragma unroll
    for (int m = 0; m < 4; ++m)
        #pragma unroll
        for (int r = 0; r < 4; ++r) {
            const size_t row = tok0 + wr * 64 + m * 16 + q4 * 4 + r;
            #pragma unroll
            for (int n = 0; n < 8; ++n) {
                const int nn = wc * 128 + n * 16 + col;
                const float y = acc[m][n][r] + b2v[n] + h[row * D_ + nn];
                acc[m][n][r] = y;
                s[m][r] += y;
                s2[m][r] = fmaf(y, y, s2[m][r]);
            }
        }

    // butterfly over the 16 col-lanes (same row)
    #pragma unroll
    for (int m = 0; m < 4; ++m)
        #pragma unroll
        for (int r = 0; r < 4; ++r) {
            #pragma unroll
            for (int d = 1; d < 16; d <<= 1) {
                s[m][r]  += __shfl_xor(s[m][r],  d);
                s2[m][r] += __shfl_xor(s2[m][r], d);
            }
        }

    if (col == 0) {
        #pragma unroll
        for (int m = 0; m < 4; ++m)
            #pragma unroll
            for (int r = 0; r < 4; ++r) {
                const int rl = wr * 64 + m * 16 + q4 * 4 + r;
                red[rl][wc][0] = s[m][r];
                red[rl][wc][1] = s2[m][r];
            }
    }
    __syncthreads();

    float mu[4][4], rs[4][4];
    #pragma unroll
    for (int m = 0; m < 4; ++m)
        #pragma unroll
        for (int r = 0; r < 4; ++r) {
            const int rl = wr * 64 + m * 16 + q4 * 4 + r;
            const float ts  = red[rl][0][0] + red[rl][1][0];
            const float ts2 = red[rl][0][1] + red[rl][1][1];
            const float m_  = ts * (1.f / 256.f);
            mu[m][r] = m_;
            rs[m][r] = rsqrtf(ts2 * (1.f / 256.f) - m_ * m_ + EPS_);
        }

    #pragma unroll
    for (int n = 0; n < 8; ++n) {
        const int nn = wc * 128 + n * 16 + col;
        const float gv = g2[nn], bev = be2[nn];
        #pragma unroll
        for (int m = 0; m < 4; ++m)
            #pragma unroll
            for (int r = 0; r < 4; ++r) {
                const size_t row = tok0 + wr * 64 + m * 16 + q4 * 4 + r;
                out[row * D_ + nn] = (acc[m][n][r] - mu[m][r]) * rs[m][r] * gv + bev;
            }
    }
}

// ---------------------------------------------------------------------------
extern "C" void kernel_launch(void* const* d_in, const int* in_sizes, int n_in,
                              void* d_out, int out_size, void* d_ws, size_t ws_size,
                              hipStream_t stream)
{
    const float* x   = (const float*)d_in[0];
    const float* Wq  = (const float*)d_in[1];
    const float* bq  = (const float*)d_in[2];
    const float* Wk  = (const float*)d_in[3];
    const float* bk  = (const float*)d_in[4];
    const float* Wv  = (const float*)d_in[5];
    const float* bv  = (const float*)d_in[6];
    const float* Wo  = (const float*)d_in[7];
    const float* bo  = (const float*)d_in[8];
    const float* W1  = (const float*)d_in[9];
    const float* b1  = (const float*)d_in[10];
    const float* W2  = (const float*)d_in[11];
    const float* b2  = (const float*)d_in[12];
    const float* g1  = (const float*)d_in[13];
    const float* be1 = (const float*)d_in[14];
    const float* g2  = (const float*)d_in[15];
    const float* be2 = (const float*)d_in[16];
    float* out = (float*)d_out;

    const size_t N = (size_t)B_ * S1_ * S2_ * D_;   // 16,777,216 elements

    // Dedicated, NON-ALIASED workspace layout:
    unsigned short* qb  = (unsigned short*)d_ws;
    unsigned short* kb  = qb + N;
    unsigned short* vb  = kb + N;
    unsigned short* ob  = vb + N;
    float*          h   = (float*)(ob + N);
    unsigned short* Wqk_bt = (unsigned short*)(h + N);
    unsigned short* Wv_bt  = Wqk_bt + (size_t)512 * 768;
    unsigned short* Wo_bt  = Wv_bt  + (size_t)256 * 256;
    unsigned short* W1bt   = Wo_bt  + (size_t)256 * 256;
    unsigned short* W2bt   = W1bt   + (size_t)F_ * D_;
    const size_t need = (size_t)(W2bt + (size_t)D_ * F_ - (unsigned short*)d_ws) * 2;
    if (ws_size < need) return;

    // ff (bf16, 65536 x 1024 = 134 MB) aliases qb..ob, all dead after attn/oproj.
    unsigned short* ff = qb;

    k_cvt_qkv   <<<dim3(768),  256, 0, stream>>>(Wq, Wk, Wv, Wqk_bt, Wv_bt);
    k_cvt_proj  <<<dim3(1536), 256, 0, stream>>>(Wo, W1, W2, Wo_bt, W1bt, W2bt);
    k_qkv_mfma  <<<dim3(B_ * S1_ * S2_ / 32), 256, 0, stream>>>(
                    x, Wqk_bt, Wv_bt, bq, bk, bv, qb, kb, vb);
    k_attn_mfma <<<dim3(B_ * S1_, H_), 256, 0, stream>>>(qb, kb, vb, ob);
    k_oproj_mfma<<<dim3(B_ * S1_ * S2_ / 32), 256, 0, stream>>>(
                    x, ob, Wo_bt, bo, g1, be1, h);
    k_ffn1_gemm <<<dim3(B_ * S1_ * S2_ / 128, F_ / 256), 256, 0, stream>>>(
                    h, W1bt, b1, ff);
    k_ffn2_gemm <<<dim3(B_ * S1_ * S2_ / 128), 256, 0, stream>>>(
                    ff, W2bt, b2, h, g2, be2, out);
}

// Round 4
// 780.550 us; speedup vs baseline: 1.2677x; 1.1994x over previous
//
#include <hip/hip_runtime.h>
#include <hip/hip_bf16.h>

// Problem constants
#define B_ 4
#define S1_ 64
#define S2_ 256
#define D_ 256
#define H_ 8
#define HD_ 32
#define F_ 1024
#define EPS_ 1e-5f
#define NEG_ 0.01f

typedef __attribute__((ext_vector_type(8))) short bfrag;   // 8 x bf16 (4 VGPRs)
typedef __attribute__((ext_vector_type(4))) float f32x4;   // MFMA C/D
typedef __attribute__((ext_vector_type(8))) unsigned short us8;

__device__ __forceinline__ unsigned short bf16rn(float f) {
    union { float f; unsigned int u; } c; c.f = f;
    unsigned int u = c.u;
    u = (u + 0x7FFFu + ((u >> 16) & 1u)) >> 16;   // round-to-nearest-even
    return (unsigned short)u;
}

// async global->LDS, 16B per lane. lds base must be wave-uniform; HW adds lane*16.
__device__ __forceinline__ void gload_lds16(const void* g, void* l) {
    __builtin_amdgcn_global_load_lds(
        (const __attribute__((address_space(1))) void*)g,
        (__attribute__((address_space(3))) void*)l,
        16, 0, 0);
}

// ---------------------------------------------------------------------------
// x (fp32) -> xb16 (bf16), flat cast. 8 elems/thread.
// ---------------------------------------------------------------------------
__global__ __launch_bounds__(256) void k_xcast(
    const float* __restrict__ x, unsigned short* __restrict__ xb16)
{
    const size_t i = ((size_t)blockIdx.x * 256 + threadIdx.x) * 8;
    float4 f0 = *(const float4*)(x + i);
    float4 f1 = *(const float4*)(x + i + 4);
    us8 v;
    v[0] = bf16rn(f0.x); v[1] = bf16rn(f0.y); v[2] = bf16rn(f0.z); v[3] = bf16rn(f0.w);
    v[4] = bf16rn(f1.x); v[5] = bf16rn(f1.y); v[6] = bf16rn(f1.z); v[7] = bf16rn(f1.w);
    *(us8*)(xb16 + i) = v;
}

// ---------------------------------------------------------------------------
// Weight pack: all weights are natively [k][n] in memory. Pack into MFMA
// fragment order per BK=64 chunk: frag index fi = (nt*2+kk)*64 + lane,
// content elem e: W[k0 + kk*32 + (lane>>4)*8 + e][n0 + nt*16 + (lane&15)].
// One chunk = 2048 frags * 16B = 32 KB.  Blocks:
//   0..11  q (Wq,  N=256, k0=blk*64)        -> Wq_pk
//  12..23  k (Wk)                            -> Wk_pk
//  24..27  v (Wv,  K=256)                    -> Wv_pk
//  28..43  W1 (N=1024: panel p=idx>>2, chunk c=idx&3) -> W1_pk
//  44..59  W2 (K=1024: 16 chunks)            -> W2_pk
//  60..63  Wo (K=256)                        -> Wo_pk
// ---------------------------------------------------------------------------
__global__ __launch_bounds__(256) void k_pack(
    const float* __restrict__ Wq, const float* __restrict__ Wk,
    const float* __restrict__ Wv, const float* __restrict__ Wo,
    const float* __restrict__ W1, const float* __restrict__ W2,
    unsigned short* __restrict__ Wq_pk, unsigned short* __restrict__ Wk_pk,
    unsigned short* __restrict__ Wv_pk, unsigned short* __restrict__ Wo_pk,
    unsigned short* __restrict__ W1_pk, unsigned short* __restrict__ W2_pk)
{
    const int blk = blockIdx.x;
    const float* src; unsigned short* dst; int Ntot = 256, n0 = 0, k0;
    if (blk < 12)      { src = Wq; k0 = blk * 64;        dst = Wq_pk + (size_t)blk * 16384; }
    else if (blk < 24) { src = Wk; k0 = (blk - 12) * 64; dst = Wk_pk + (size_t)(blk - 12) * 16384; }
    else if (blk < 28) { src = Wv; k0 = (blk - 24) * 64; dst = Wv_pk + (size_t)(blk - 24) * 16384; }
    else if (blk < 44) {
        const int i = blk - 28; const int p = i >> 2, c = i & 3;
        src = W1; Ntot = 1024; n0 = p * 256; k0 = c * 64;
        dst = W1_pk + (size_t)i * 16384;
    }
    else if (blk < 60) { src = W2; k0 = (blk - 44) * 64; dst = W2_pk + (size_t)(blk - 44) * 16384; }
    else               { src = Wo; k0 = (blk - 60) * 64; dst = Wo_pk + (size_t)(blk - 60) * 16384; }

    const int tid = threadIdx.x;
    for (int j = 0; j < 8; ++j) {
        const int fi = j * 256 + tid;
        const int lane = fi & 63;
        const int t2 = fi >> 6;          // nt*2+kk
        const int nt = t2 >> 1, kk = t2 & 1;
        const int col = lane & 15, q4 = lane >> 4;
        const int n = n0 + nt * 16 + col;
        const int kbase = k0 + kk * 32 + q4 * 8;
        us8 v;
        #pragma unroll
        for (int e = 0; e < 8; ++e)
            v[e] = bf16rn(src[(size_t)(kbase + e) * Ntot + n]);
        *(us8*)(dst + (size_t)fi * 8) = v;
    }
}

// ---------------------------------------------------------------------------
// Kernel 1: q/k time-conv + v as fragment-packed-B GEMMs.
// grid (512, 3): x = token-tile (bn*2+half, 128 tokens), y = {0:q,1:k,2:v}.
// BM=128, BN=256, BK=64. K=768 (q/k, shift s=c>>2) or 256 (v, s=1).
// A reg-staged from xb16 (padded LDS); B via global_load_lds (linear, packed).
// ---------------------------------------------------------------------------
__global__ __launch_bounds__(256) void k_qkv_gemm(
    const unsigned short* __restrict__ xb16,
    const unsigned short* __restrict__ Wq_pk, const unsigned short* __restrict__ Wk_pk,
    const unsigned short* __restrict__ Wv_pk,
    const float* __restrict__ bq, const float* __restrict__ bk,
    const float* __restrict__ bv,
    unsigned short* __restrict__ qb, unsigned short* __restrict__ kb,
    unsigned short* __restrict__ vb)
{
    __shared__ __align__(16) unsigned short As[128][72];
    __shared__ __align__(16) unsigned short Bs[16384];   // 32 KB, fragment-linear

    const int tid = threadIdx.x, w = tid >> 6, lane = tid & 63;
    const int col = lane & 15, q4 = lane >> 4;
    const int wr = w >> 1, wc = w & 1;
    const int y = blockIdx.y;
    const int bn = blockIdx.x >> 1, half = blockIdx.x & 1, t0 = half * 128;
    const int nch = (y == 2) ? 4 : 12;
    const unsigned short* Wpk = (y == 0) ? Wq_pk : (y == 1) ? Wk_pk : Wv_pk;

    f32x4 acc[4][8];
    #pragma unroll
    for (int m = 0; m < 4; ++m)
        #pragma unroll
        for (int n = 0; n < 8; ++n)
            acc[m][n] = (f32x4){0.f, 0.f, 0.f, 0.f};

    const int arow = tid >> 1, ahalf = (tid & 1) * 32;

    for (int c = 0; c < nch; ++c) {
        const int s  = (y == 2) ? 1 : (c >> 2);
        const int c0 = (y == 2) ? (c * 64) : ((c & 3) * 64);

        // A: issue global loads (conv-shifted row; clamp + zero at seq edges)
        const int trow = t0 + s - 1 + arow;
        const bool ok = (trow >= 0) && (trow < 256);
        const int trc = ok ? trow : (trow < 0 ? 0 : 255);
        const unsigned short* ap = xb16 + ((size_t)bn * 256 + trc) * 256 + c0 + ahalf;
        us8 av[4];
        #pragma unroll
        for (int j = 0; j < 4; ++j)
            av[j] = *(const us8*)(ap + j * 8);

        // B: async global->LDS, 8 x 1KB per wave, fully linear
        const char* wb = (const char*)(Wpk + (size_t)c * 16384);
        #pragma unroll
        for (int r = 0; r < 8; ++r) {
            const int boff = (r * 4 + w) * 1024;
            gload_lds16(wb + boff + lane * 16, ((char*)Bs) + boff);
        }

        // A: write to padded LDS (zero OOB rows)
        #pragma unroll
        for (int j = 0; j < 4; ++j) {
            us8 v = av[j];
            if (!ok) v = (us8){0, 0, 0, 0, 0, 0, 0, 0};
            *(us8*)&As[arow][ahalf + j * 8] = v;
        }
        __syncthreads();

        #pragma unroll
        for (int kk = 0; kk < 2; ++kk) {
            bfrag a[4], b[8];
            #pragma unroll
            for (int m = 0; m < 4; ++m)
                a[m] = *(const bfrag*)&As[wr * 64 + m * 16 + col][kk * 32 + q4 * 8];
            #pragma unroll
            for (int n = 0; n < 8; ++n)
                b[n] = *(const bfrag*)&Bs[(((wc * 8 + n) * 2 + kk) * 64 + lane) * 8];
            #pragma unroll
            for (int n = 0; n < 8; ++n)
                #pragma unroll
                for (int m = 0; m < 4; ++m)
                    acc[m][n] = __builtin_amdgcn_mfma_f32_16x16x32_bf16(a[m], b[n], acc[m][n], 0, 0, 0);
        }
        __syncthreads();
    }

    const float* bias = (y == 0) ? bq : (y == 1) ? bk : bv;
    unsigned short* dst = (y == 0) ? qb : (y == 1) ? kb : vb;
    #pragma unroll
    for (int n = 0; n < 8; ++n) {
        const int nn = wc * 128 + n * 16 + col;
        const float bb = bias[nn];
        #pragma unroll
        for (int m = 0; m < 4; ++m)
            #pragma unroll
            for (int r = 0; r < 4; ++r) {
                const size_t tok = (size_t)bn * 256 + t0 + wr * 64 + m * 16 + q4 * 4 + r;
                dst[tok * D_ + nn] = bf16rn(acc[m][n][r] + bb);
            }
    }
}

// ---------------------------------------------------------------------------
// Kernel 2: MFMA attention. (unchanged)
// ---------------------------------------------------------------------------
__global__ __launch_bounds__(256) void k_attn_mfma(
    const unsigned short* __restrict__ qb, const unsigned short* __restrict__ kb,
    const unsigned short* __restrict__ vb, unsigned short* __restrict__ ob)
{
    __shared__ __align__(16) unsigned short Ks[256][40];   // keys, pad->bank spread
    __shared__ __align__(16) unsigned short Vt[32][264];   // V transposed [d][s]
    __shared__ __align__(16) unsigned short Pw[4][16][264];// per-wave P scratch

    const int bn   = blockIdx.x;
    const int h    = blockIdx.y;
    const int tid  = threadIdx.x;
    const int w    = tid >> 6;
    const int lane = tid & 63;
    const int col  = lane & 15;
    const int q4   = lane >> 4;
    const size_t base = (size_t)bn * S2_ * D_ + h * HD_;
    const float SCALE = 0.17677669529663687f;   // 1/sqrt(32)

    // ---- stage K rows (coalesced 64B/row) ----
    {
        const unsigned short* kr = kb + base + (size_t)tid * D_;
        #pragma unroll
        for (int j = 0; j < 4; ++j)
            *(us8*)&Ks[tid][j * 8] = *(const us8*)(kr + j * 8);
    }
    // ---- stage V transposed: thread (dv, sg) covers d=dv, s=sg*32..+31 ----
    {
        const int dv = tid & 31, sg = tid >> 5;
        for (int i = 0; i < 32; ++i) {
            const int s = sg * 32 + i;
            Vt[dv][s] = vb[base + (size_t)s * D_ + dv];
        }
    }
    __syncthreads();

    // ---- Q fragments direct from global (A-layout) ----
    const int r0w = w * 64;
    bfrag qa[4];
    #pragma unroll
    for (int mt = 0; mt < 4; ++mt)
        qa[mt] = *(const bfrag*)(qb + base + (size_t)(r0w + mt * 16 + col) * D_ + q4 * 8);

    for (int mt = 0; mt < 4; ++mt) {
        // ---- scores: 16 n-tiles, one MFMA each (K=32 = full HD) ----
        f32x4 sc[16];
        #pragma unroll
        for (int nt = 0; nt < 16; ++nt) {
            bfrag b = *(const bfrag*)&Ks[nt * 16 + col][q4 * 8];
            f32x4 z = {0.f, 0.f, 0.f, 0.f};
            sc[nt] = __builtin_amdgcn_mfma_f32_16x16x32_bf16(qa[mt], b, z, 0, 0, 0);
        }

        // ---- softmax over 256 cols ----
        float mx[4] = {-1e30f, -1e30f, -1e30f, -1e30f};
        #pragma unroll
        for (int nt = 0; nt < 16; ++nt)
            #pragma unroll
            for (int r = 0; r < 4; ++r) {
                sc[nt][r] *= SCALE;
                mx[r] = fmaxf(mx[r], sc[nt][r]);
            }
        #pragma unroll
        for (int r = 0; r < 4; ++r) {
            mx[r] = fmaxf(mx[r], __shfl_xor(mx[r], 1));
            mx[r] = fmaxf(mx[r], __shfl_xor(mx[r], 2));
            mx[r] = fmaxf(mx[r], __shfl_xor(mx[r], 4));
            mx[r] = fmaxf(mx[r], __shfl_xor(mx[r], 8));
        }
        float l[4] = {0.f, 0.f, 0.f, 0.f};
        #pragma unroll
        for (int nt = 0; nt < 16; ++nt)
            #pragma unroll
            for (int r = 0; r < 4; ++r) {
                const float e = __expf(sc[nt][r] - mx[r]);
                sc[nt][r] = e;
                l[r] += e;
            }
        #pragma unroll
        for (int r = 0; r < 4; ++r) {
            l[r] += __shfl_xor(l[r], 1);
            l[r] += __shfl_xor(l[r], 2);
            l[r] += __shfl_xor(l[r], 4);
            l[r] += __shfl_xor(l[r], 8);
        }

        // ---- P -> per-wave LDS (bf16), even-lane packed u32 writes ----
        #pragma unroll
        for (int nt = 0; nt < 16; ++nt)
            #pragma unroll
            for (int r = 0; r < 4; ++r) {
                const float p  = sc[nt][r];
                const float po = __shfl_xor(p, 1);
                if ((lane & 1) == 0) {
                    const unsigned int packed =
                        (unsigned int)bf16rn(p) | ((unsigned int)bf16rn(po) << 16);
                    *(unsigned int*)&Pw[w][q4 * 4 + r][nt * 16 + col] = packed;
                }
            }

        // ---- PV: o[16 x 32] ----
        f32x4 oacc[2];
        oacc[0] = (f32x4){0.f, 0.f, 0.f, 0.f};
        oacc[1] = (f32x4){0.f, 0.f, 0.f, 0.f};
        #pragma unroll
        for (int kc = 0; kc < 8; ++kc) {
            bfrag pa = *(const bfrag*)&Pw[w][col][kc * 32 + q4 * 8];
            #pragma unroll
            for (int dt = 0; dt < 2; ++dt) {
                bfrag b = *(const bfrag*)&Vt[dt * 16 + col][kc * 32 + q4 * 8];
                oacc[dt] = __builtin_amdgcn_mfma_f32_16x16x32_bf16(pa, b, oacc[dt], 0, 0, 0);
            }
        }

        // ---- normalize + write ----
        float inv[4];
        #pragma unroll
        for (int r = 0; r < 4; ++r) inv[r] = 1.f / l[r];
        #pragma unroll
        for (int dt = 0; dt < 2; ++dt)
            #pragma unroll
            for (int r = 0; r < 4; ++r)
                ob[base + (size_t)(r0w + mt * 16 + q4 * 4 + r) * D_ + dt * 16 + col]
                    = bf16rn(oacc[dt][r] * inv[r]);
    }
}

// ---------------------------------------------------------------------------
// Kernel 3: o @ Wo + bo + residual(x) -> LN1 -> h (fp32), MFMA.
// Same GEMM skeleton. BM=128, BN=256(full row), K=256.
// ---------------------------------------------------------------------------
__global__ __launch_bounds__(256) void k_oproj_gemm(
    const unsigned short* __restrict__ ob,
    const unsigned short* __restrict__ Wo_pk, const float* __restrict__ bo,
    const float* __restrict__ x,
    const float* __restrict__ g1, const float* __restrict__ be1,
    float* __restrict__ hout)
{
    __shared__ __align__(16) unsigned short As[128][72];
    __shared__ __align__(16) unsigned short Bs[16384];
    __shared__ float red[128][2][2];

    const int tid = threadIdx.x, w = tid >> 6, lane = tid & 63;
    const int col = lane & 15, q4 = lane >> 4;
    const int wr = w >> 1, wc = w & 1;
    const size_t tok0 = (size_t)blockIdx.x * 128;

    f32x4 acc[4][8];
    #pragma unroll
    for (int m = 0; m < 4; ++m)
        #pragma unroll
        for (int n = 0; n < 8; ++n)
            acc[m][n] = (f32x4){0.f, 0.f, 0.f, 0.f};

    const int arow = tid >> 1, ahalf = (tid & 1) * 32;

    for (int c = 0; c < 4; ++c) {
        const unsigned short* ap = ob + (tok0 + arow) * D_ + c * 64 + ahalf;
        us8 av[4];
        #pragma unroll
        for (int j = 0; j < 4; ++j)
            av[j] = *(const us8*)(ap + j * 8);

        const char* wb = (const char*)(Wo_pk + (size_t)c * 16384);
        #pragma unroll
        for (int r = 0; r < 8; ++r) {
            const int boff = (r * 4 + w) * 1024;
            gload_lds16(wb + boff + lane * 16, ((char*)Bs) + boff);
        }

        #pragma unroll
        for (int j = 0; j < 4; ++j)
            *(us8*)&As[arow][ahalf + j * 8] = av[j];
        __syncthreads();

        #pragma unroll
        for (int kk = 0; kk < 2; ++kk) {
            bfrag a[4], b[8];
            #pragma unroll
            for (int m = 0; m < 4; ++m)
                a[m] = *(const bfrag*)&As[wr * 64 + m * 16 + col][kk * 32 + q4 * 8];
            #pragma unroll
            for (int n = 0; n < 8; ++n)
                b[n] = *(const bfrag*)&Bs[(((wc * 8 + n) * 2 + kk) * 64 + lane) * 8];
            #pragma unroll
            for (int n = 0; n < 8; ++n)
                #pragma unroll
                for (int m = 0; m < 4; ++m)
                    acc[m][n] = __builtin_amdgcn_mfma_f32_16x16x32_bf16(a[m], b[n], acc[m][n], 0, 0, 0);
        }
        __syncthreads();
    }

    // ---- epilogue: y = acc + bo + x(residual); LN over 256 cols ----
    float bov[8];
    #pragma unroll
    for (int n = 0; n < 8; ++n)
        bov[n] = bo[wc * 128 + n * 16 + col];

    float s[4][4], s2[4][4];
    #pragma unroll
    for (int m = 0; m < 4; ++m)
        #pragma unroll
        for (int r = 0; r < 4; ++r) { s[m][r] = 0.f; s2[m][r] = 0.f; }

    #pragma unroll
    for (int m = 0; m < 4; ++m)
        #pragma unroll
        for (int r = 0; r < 4; ++r) {
            const size_t row = tok0 + wr * 64 + m * 16 + q4 * 4 + r;
            #pragma unroll
            for (int n = 0; n < 8; ++n) {
                const int nn = wc * 128 + n * 16 + col;
                const float yv = acc[m][n][r] + bov[n] + x[row * D_ + nn];
                acc[m][n][r] = yv;
                s[m][r] += yv;
                s2[m][r] = fmaf(yv, yv, s2[m][r]);
            }
        }

    #pragma unroll
    for (int m = 0; m < 4; ++m)
        #pragma unroll
        for (int r = 0; r < 4; ++r) {
            #pragma unroll
            for (int d = 1; d < 16; d <<= 1) {
                s[m][r]  += __shfl_xor(s[m][r],  d);
                s2[m][r] += __shfl_xor(s2[m][r], d);
            }
        }

    if (col == 0) {
        #pragma unroll
        for (int m = 0; m < 4; ++m)
            #pragma unroll
            for (int r = 0; r < 4; ++r) {
                const int rl = wr * 64 + m * 16 + q4 * 4 + r;
                red[rl][wc][0] = s[m][r];
                red[rl][wc][1] = s2[m][r];
            }
    }
    __syncthreads();

    float mu[4][4], rs[4][4];
    #pragma unroll
    for (int m = 0; m < 4; ++m)
        #pragma unroll
        for (int r = 0; r < 4; ++r) {
            const int rl = wr * 64 + m * 16 + q4 * 4 + r;
            const float ts  = red[rl][0][0] + red[rl][1][0];
            const float ts2 = red[rl][0][1] + red[rl][1][1];
            const float m_  = ts * (1.f / 256.f);
            mu[m][r] = m_;
            rs[m][r] = rsqrtf(ts2 * (1.f / 256.f) - m_ * m_ + EPS_);
        }

    #pragma unroll
    for (int n = 0; n < 8; ++n) {
        const int nn = wc * 128 + n * 16 + col;
        const float gv = g1[nn], bev = be1[nn];
        #pragma unroll
        for (int m = 0; m < 4; ++m)
            #pragma unroll
            for (int r = 0; r < 4; ++r) {
                const size_t row = tok0 + wr * 64 + m * 16 + q4 * 4 + r;
                hout[row * D_ + nn] = (acc[m][n][r] - mu[m][r]) * rs[m][r] * gv + bev;
            }
    }
}

// ---------------------------------------------------------------------------
// Kernel 4a: ff = leaky(h @ W1 + b1).  A staged from fp32 h (reg cast).
// grid (512, 4): y = N-panel of 256. K=256 (4 chunks).
// ---------------------------------------------------------------------------
__global__ __launch_bounds__(256) void k_ffn1_gemm(
    const float* __restrict__ h,
    const unsigned short* __restrict__ W1_pk, const float* __restrict__ b1,
    unsigned short* __restrict__ ff)
{
    __shared__ __align__(16) unsigned short As[128][72];
    __shared__ __align__(16) unsigned short Bs[16384];

    const int tid = threadIdx.x, w = tid >> 6, lane = tid & 63;
    const int col = lane & 15, q4 = lane >> 4;
    const int wr = w >> 1, wc = w & 1;
    const size_t tok0 = (size_t)blockIdx.x * 128;
    const int y = blockIdx.y;                 // n-panel
    const unsigned short* Wpk = W1_pk + (size_t)y * 4 * 16384;

    f32x4 acc[4][8];
    #pragma unroll
    for (int m = 0; m < 4; ++m)
        #pragma unroll
        for (int n = 0; n < 8; ++n)
            acc[m][n] = (f32x4){0.f, 0.f, 0.f, 0.f};

    const int arow = tid >> 1, ahalf = (tid & 1) * 32;

    for (int c = 0; c < 4; ++c) {
        // A: fp32 -> bf16 in regs
        const float* ap = h + (tok0 + arow) * D_ + c * 64 + ahalf;
        us8 av[4];
        #pragma unroll
        for (int j = 0; j < 4; ++j) {
            float4 f0 = *(const float4*)(ap + j * 8);
            float4 f1 = *(const float4*)(ap + j * 8 + 4);
            us8 v;
            v[0] = bf16rn(f0.x); v[1] = bf16rn(f0.y);
            v[2] = bf16rn(f0.z); v[3] = bf16rn(f0.w);
            v[4] = bf16rn(f1.x); v[5] = bf16rn(f1.y);
            v[6] = bf16rn(f1.z); v[7] = bf16rn(f1.w);
            av[j] = v;
        }

        const char* wb = (const char*)(Wpk + (size_t)c * 16384);
        #pragma unroll
        for (int r = 0; r < 8; ++r) {
            const int boff = (r * 4 + w) * 1024;
            gload_lds16(wb + boff + lane * 16, ((char*)Bs) + boff);
        }

        #pragma unroll
        for (int j = 0; j < 4; ++j)
            *(us8*)&As[arow][ahalf + j * 8] = av[j];
        __syncthreads();

        #pragma unroll
        for (int kk = 0; kk < 2; ++kk) {
            bfrag a[4], b[8];
            #pragma unroll
            for (int m = 0; m < 4; ++m)
                a[m] = *(const bfrag*)&As[wr * 64 + m * 16 + col][kk * 32 + q4 * 8];
            #pragma unroll
            for (int n = 0; n < 8; ++n)
                b[n] = *(const bfrag*)&Bs[(((wc * 8 + n) * 2 + kk) * 64 + lane) * 8];
            #pragma unroll
            for (int n = 0; n < 8; ++n)
                #pragma unroll
                for (int m = 0; m < 4; ++m)
                    acc[m][n] = __builtin_amdgcn_mfma_f32_16x16x32_bf16(a[m], b[n], acc[m][n], 0, 0, 0);
        }
        __syncthreads();
    }

    #pragma unroll
    for (int n = 0; n < 8; ++n) {
        const int nglob = y * 256 + wc * 128 + n * 16 + col;
        const float bb = b1[nglob];
        #pragma unroll
        for (int m = 0; m < 4; ++m)
            #pragma unroll
            for (int r = 0; r < 4; ++r) {
                float v = acc[m][n][r] + bb;
                v = (v > 0.f) ? v : NEG_ * v;
                ff[(tok0 + wr * 64 + m * 16 + q4 * 4 + r) * (size_t)F_ + nglob] = bf16rn(v);
            }
    }
}

// ---------------------------------------------------------------------------
// Kernel 4b: out = LN2(ff @ W2 + b2 + h).  K=1024 (16 chunks), N=256 full row.
// ---------------------------------------------------------------------------
__global__ __launch_bounds__(256) void k_ffn2_gemm(
    const unsigned short* __restrict__ ff,
    const unsigned short* __restrict__ W2_pk, const float* __restrict__ b2,
    const float* __restrict__ h,
    const float* __restrict__ g2, const float* __restrict__ be2,
    float* __restrict__ out)
{
    __shared__ __align__(16) unsigned short As[128][72];
    __shared__ __align__(16) unsigned short Bs[16384];
    __shared__ float red[128][2][2];

    const int tid = threadIdx.x, w = tid >> 6, lane = tid & 63;
    const int col = lane & 15, q4 = lane >> 4;
    const int wr = w >> 1, wc = w & 1;
    const size_t tok0 = (size_t)blockIdx.x * 128;

    f32x4 acc[4][8];
    #pragma unroll
    for (int m = 0; m < 4; ++m)
        #pragma unroll
        for (int n = 0; n < 8; ++n)
            acc[m][n] = (f32x4){0.f, 0.f, 0.f, 0.f};

    const int arow = tid >> 1, ahalf = (tid & 1) * 32;

    for (int c = 0; c < 16; ++c) {
        const unsigned short* ap = ff + (tok0 + arow) * (size_t)F_ + c * 64 + ahalf;
        us8 av[4];
        #pragma unroll
        for (int j = 0; j < 4; ++j)
            av[j] = *(const us8*)(ap + j * 8);

        const char* wb = (const char*)(W2_pk + (size_t)c * 16384);
        #pragma unroll
        for (int r = 0; r < 8; ++r) {
            const int boff = (r * 4 + w) * 1024;
            gload_lds16(wb + boff + lane * 16, ((char*)Bs) + boff);
        }

        #pragma unroll
        for (int j = 0; j < 4; ++j)
            *(us8*)&As[arow][ahalf + j * 8] = av[j];
        __syncthreads();

        #pragma unroll
        for (int kk = 0; kk < 2; ++kk) {
            bfrag a[4], b[8];
            #pragma unroll
            for (int m = 0; m < 4; ++m)
                a[m] = *(const bfrag*)&As[wr * 64 + m * 16 + col][kk * 32 + q4 * 8];
            #pragma unroll
            for (int n = 0; n < 8; ++n)
                b[n] = *(const bfrag*)&Bs[(((wc * 8 + n) * 2 + kk) * 64 + lane) * 8];
            #pragma unroll
            for (int n = 0; n < 8; ++n)
                #pragma unroll
                for (int m = 0; m < 4; ++m)
                    acc[m][n] = __builtin_amdgcn_mfma_f32_16x16x32_bf16(a[m], b[n], acc[m][n], 0, 0, 0);
        }
        __syncthreads();
    }

    // ---- epilogue: y = acc + b2 + h(residual); LN over 256 cols ----
    float b2v[8];
    #pragma unroll
    for (int n = 0; n < 8; ++n)
        b2v[n] = b2[wc * 128 + n * 16 + col];

    float s[4][4], s2[4][4];
    #pragma unroll
    for (int m = 0; m < 4; ++m)
        #pragma unroll
        for (int r = 0; r < 4; ++r) { s[m][r] = 0.f; s2[m][r] = 0.f; }

    #pragma unroll
    for (int m = 0; m < 4; ++m)
        #pragma unroll
        for (int r = 0; r < 4; ++r) {
            const size_t row = tok0 + wr * 64 + m * 16 + q4 * 4 + r;
            #pragma unroll
            for (int n = 0; n < 8; ++n) {
                const int nn = wc * 128 + n * 16 + col;
                const float yv = acc[m][n][r] + b2v[n] + h[row * D_ + nn];
                acc[m][n][r] = yv;
                s[m][r] += yv;
                s2[m][r] = fmaf(yv, yv, s2[m][r]);
            }
        }

    #pragma unroll
    for (int m = 0; m < 4; ++m)
        #pragma unroll
        for (int r = 0; r < 4; ++r) {
            #pragma unroll
            for (int d = 1; d < 16; d <<= 1) {
                s[m][r]  += __shfl_xor(s[m][r],  d);
                s2[m][r] += __shfl_xor(s2[m][r], d);
            }
        }

    if (col == 0) {
        #pragma unroll
        for (int m = 0; m < 4; ++m)
            #pragma unroll
            for (int r = 0; r < 4; ++r) {
                const int rl = wr * 64 + m * 16 + q4 * 4 + r;
                red[rl][wc][0] = s[m][r];
                red[rl][wc][1] = s2[m][r];
            }
    }
    __syncthreads();

    float mu[4][4], rs[4][4];
    #pragma unroll
    for (int m = 0; m < 4; ++m)
        #pragma unroll
        for (int r = 0; r < 4; ++r) {
            const int rl = wr * 64 + m * 16 + q4 * 4 + r;
            const float ts  = red[rl][0][0] + red[rl][1][0];
            const float ts2 = red[rl][0][1] + red[rl][1][1];
            const float m_  = ts * (1.f / 256.f);
            mu[m][r] = m_;
            rs[m][r] = rsqrtf(ts2 * (1.f / 256.f) - m_ * m_ + EPS_);
        }

    #pragma unroll
    for (int n = 0; n < 8; ++n) {
        const int nn = wc * 128 + n * 16 + col;
        const float gv = g2[nn], bev = be2[nn];
        #pragma unroll
        for (int m = 0; m < 4; ++m)
            #pragma unroll
            for (int r = 0; r < 4; ++r) {
                const size_t row = tok0 + wr * 64 + m * 16 + q4 * 4 + r;
                out[row * D_ + nn] = (acc[m][n][r] - mu[m][r]) * rs[m][r] * gv + bev;
            }
    }
}

// ---------------------------------------------------------------------------
extern "C" void kernel_launch(void* const* d_in, const int* in_sizes, int n_in,
                              void* d_out, int out_size, void* d_ws, size_t ws_size,
                              hipStream_t stream)
{
    const float* x   = (const float*)d_in[0];
    const float* Wq  = (const float*)d_in[1];
    const float* bq  = (const float*)d_in[2];
    const float* Wk  = (const float*)d_in[3];
    const float* bk  = (const float*)d_in[4];
    const float* Wv  = (const float*)d_in[5];
    const float* bv  = (const float*)d_in[6];
    const float* Wo  = (const float*)d_in[7];
    const float* bo  = (const float*)d_in[8];
    const float* W1  = (const float*)d_in[9];
    const float* b1  = (const float*)d_in[10];
    const float* W2  = (const float*)d_in[11];
    const float* b2  = (const float*)d_in[12];
    const float* g1  = (const float*)d_in[13];
    const float* be1 = (const float*)d_in[14];
    const float* g2  = (const float*)d_in[15];
    const float* be2 = (const float*)d_in[16];
    float* out = (float*)d_out;

    const size_t N = (size_t)B_ * S1_ * S2_ * D_;   // 16,777,216 elements

    unsigned short* qb  = (unsigned short*)d_ws;
    unsigned short* kb  = qb + N;
    unsigned short* vb  = kb + N;
    unsigned short* ob  = vb + N;
    float*          h   = (float*)(ob + N);
    unsigned short* Wq_pk = (unsigned short*)(h + N);
    unsigned short* Wk_pk = Wq_pk + (size_t)12 * 16384;   // 196608
    unsigned short* Wv_pk = Wk_pk + (size_t)12 * 16384;
    unsigned short* Wo_pk = Wv_pk + (size_t)4 * 16384;    // 65536
    unsigned short* W1_pk = Wo_pk + (size_t)4 * 16384;
    unsigned short* W2_pk = W1_pk + (size_t)16 * 16384;   // 262144
    const size_t need = (size_t)(W2_pk + (size_t)16 * 16384 - (unsigned short*)d_ws) * 2;
    if (ws_size < need) return;

    // Aliases (lifetime-disjoint):
    unsigned short* xb16 = (unsigned short*)h;   // dead after k_qkv_gemm (h written after)
    unsigned short* ff   = qb;                   // spans qb..ob; all dead after oproj

    k_xcast     <<<dim3((unsigned)(N / 2048)), 256, 0, stream>>>(x, xb16);
    k_pack      <<<dim3(64), 256, 0, stream>>>(Wq, Wk, Wv, Wo, W1, W2,
                    Wq_pk, Wk_pk, Wv_pk, Wo_pk, W1_pk, W2_pk);
    k_qkv_gemm  <<<dim3(512, 3), 256, 0, stream>>>(
                    xb16, Wq_pk, Wk_pk, Wv_pk, bq, bk, bv, qb, kb, vb);
    k_attn_mfma <<<dim3(B_ * S1_, H_), 256, 0, stream>>>(qb, kb, vb, ob);
    k_oproj_gemm<<<dim3(512), 256, 0, stream>>>(
                    ob, Wo_pk, bo, x, g1, be1, h);
    k_ffn1_gemm <<<dim3(512, 4), 256, 0, stream>>>(h, W1_pk, b1, ff);
    k_ffn2_gemm <<<dim3(512), 256, 0, stream>>>(ff, W2_pk, b2, h, g2, be2, out);
}

// Round 5
// 762.347 us; speedup vs baseline: 1.2980x; 1.0239x over previous
//
#include <hip/hip_runtime.h>
#include <hip/hip_bf16.h>

// Problem constants
#define B_ 4
#define S1_ 64
#define S2_ 256
#define D_ 256
#define H_ 8
#define HD_ 32
#define F_ 1024
#define EPS_ 1e-5f
#define NEG_ 0.01f

typedef __attribute__((ext_vector_type(8))) short bfrag;   // 8 x bf16 (4 VGPRs)
typedef __attribute__((ext_vector_type(4))) float f32x4;   // MFMA C/D
typedef __attribute__((ext_vector_type(8))) unsigned short us8;
typedef __attribute__((ext_vector_type(4))) unsigned short us4;

__device__ __forceinline__ unsigned short bf16rn(float f) {
    union { float f; unsigned int u; } c; c.f = f;
    unsigned int u = c.u;
    u = (u + 0x7FFFu + ((u >> 16) & 1u)) >> 16;   // round-to-nearest-even
    return (unsigned short)u;
}

// async global->LDS, 16B per lane. lds base must be wave-uniform; HW adds lane*16.
__device__ __forceinline__ void gload_lds16(const void* g, void* l) {
    __builtin_amdgcn_global_load_lds(
        (const __attribute__((address_space(1))) void*)g,
        (__attribute__((address_space(3))) void*)l,
        16, 0, 0);
}

// ---------------------------------------------------------------------------
// x (fp32) -> xb16 (bf16), flat cast. 8 elems/thread.
// ---------------------------------------------------------------------------
__global__ __launch_bounds__(256) void k_xcast(
    const float* __restrict__ x, unsigned short* __restrict__ xb16)
{
    const size_t i = ((size_t)blockIdx.x * 256 + threadIdx.x) * 8;
    float4 f0 = *(const float4*)(x + i);
    float4 f1 = *(const float4*)(x + i + 4);
    us8 v;
    v[0] = bf16rn(f0.x); v[1] = bf16rn(f0.y); v[2] = bf16rn(f0.z); v[3] = bf16rn(f0.w);
    v[4] = bf16rn(f1.x); v[5] = bf16rn(f1.y); v[6] = bf16rn(f1.z); v[7] = bf16rn(f1.w);
    *(us8*)(xb16 + i) = v;
}

// ---------------------------------------------------------------------------
// Weight pack (unchanged): [k][n] -> MFMA fragment order per BK=64 chunk.
// ---------------------------------------------------------------------------
__global__ __launch_bounds__(256) void k_pack(
    const float* __restrict__ Wq, const float* __restrict__ Wk,
    const float* __restrict__ Wv, const float* __restrict__ Wo,
    const float* __restrict__ W1, const float* __restrict__ W2,
    unsigned short* __restrict__ Wq_pk, unsigned short* __restrict__ Wk_pk,
    unsigned short* __restrict__ Wv_pk, unsigned short* __restrict__ Wo_pk,
    unsigned short* __restrict__ W1_pk, unsigned short* __restrict__ W2_pk)
{
    const int blk = blockIdx.x;
    const float* src; unsigned short* dst; int Ntot = 256, n0 = 0, k0;
    if (blk < 12)      { src = Wq; k0 = blk * 64;        dst = Wq_pk + (size_t)blk * 16384; }
    else if (blk < 24) { src = Wk; k0 = (blk - 12) * 64; dst = Wk_pk + (size_t)(blk - 12) * 16384; }
    else if (blk < 28) { src = Wv; k0 = (blk - 24) * 64; dst = Wv_pk + (size_t)(blk - 24) * 16384; }
    else if (blk < 44) {
        const int i = blk - 28; const int p = i >> 2, c = i & 3;
        src = W1; Ntot = 1024; n0 = p * 256; k0 = c * 64;
        dst = W1_pk + (size_t)i * 16384;
    }
    else if (blk < 60) { src = W2; k0 = (blk - 44) * 64; dst = W2_pk + (size_t)(blk - 44) * 16384; }
    else               { src = Wo; k0 = (blk - 60) * 64; dst = Wo_pk + (size_t)(blk - 60) * 16384; }

    const int tid = threadIdx.x;
    for (int j = 0; j < 8; ++j) {
        const int fi = j * 256 + tid;
        const int lane = fi & 63;
        const int t2 = fi >> 6;          // nt*2+kk
        const int nt = t2 >> 1, kk = t2 & 1;
        const int col = lane & 15, q4 = lane >> 4;
        const int n = n0 + nt * 16 + col;
        const int kbase = k0 + kk * 32 + q4 * 8;
        us8 v;
        #pragma unroll
        for (int e = 0; e < 8; ++e)
            v[e] = bf16rn(src[(size_t)(kbase + e) * Ntot + n]);
        *(us8*)(dst + (size_t)fi * 8) = v;
    }
}

// ---------------------------------------------------------------------------
// Kernel 1: q/k time-conv + v as fragment-packed-B GEMMs.
// y==2 (v) now writes V TRANSPOSED: vbT[(bn*256 + ch)*256 + s]  (ch=h*32+dl)
// so attention can consume V^T fragments directly.
// ---------------------------------------------------------------------------
__global__ __launch_bounds__(256) void k_qkv_gemm(
    const unsigned short* __restrict__ xb16,
    const unsigned short* __restrict__ Wq_pk, const unsigned short* __restrict__ Wk_pk,
    const unsigned short* __restrict__ Wv_pk,
    const float* __restrict__ bq, const float* __restrict__ bk,
    const float* __restrict__ bv,
    unsigned short* __restrict__ qb, unsigned short* __restrict__ kb,
    unsigned short* __restrict__ vbT)
{
    __shared__ __align__(16) unsigned short As[128][72];
    __shared__ __align__(16) unsigned short Bs[16384];   // 32 KB, fragment-linear

    const int tid = threadIdx.x, w = tid >> 6, lane = tid & 63;
    const int col = lane & 15, q4 = lane >> 4;
    const int wr = w >> 1, wc = w & 1;
    const int y = blockIdx.y;
    const int bn = blockIdx.x >> 1, half = blockIdx.x & 1, t0 = half * 128;
    const int nch = (y == 2) ? 4 : 12;
    const unsigned short* Wpk = (y == 0) ? Wq_pk : (y == 1) ? Wk_pk : Wv_pk;

    f32x4 acc[4][8];
    #pragma unroll
    for (int m = 0; m < 4; ++m)
        #pragma unroll
        for (int n = 0; n < 8; ++n)
            acc[m][n] = (f32x4){0.f, 0.f, 0.f, 0.f};

    const int arow = tid >> 1, ahalf = (tid & 1) * 32;

    for (int c = 0; c < nch; ++c) {
        const int s  = (y == 2) ? 1 : (c >> 2);
        const int c0 = (y == 2) ? (c * 64) : ((c & 3) * 64);

        // A: issue global loads (conv-shifted row; clamp + zero at seq edges)
        const int trow = t0 + s - 1 + arow;
        const bool ok = (trow >= 0) && (trow < 256);
        const int trc = ok ? trow : (trow < 0 ? 0 : 255);
        const unsigned short* ap = xb16 + ((size_t)bn * 256 + trc) * 256 + c0 + ahalf;
        us8 av[4];
        #pragma unroll
        for (int j = 0; j < 4; ++j)
            av[j] = *(const us8*)(ap + j * 8);

        // B: async global->LDS, 8 x 1KB per wave, fully linear
        const char* wb = (const char*)(Wpk + (size_t)c * 16384);
        #pragma unroll
        for (int r = 0; r < 8; ++r) {
            const int boff = (r * 4 + w) * 1024;
            gload_lds16(wb + boff + lane * 16, ((char*)Bs) + boff);
        }

        // A: write to padded LDS (zero OOB rows)
        #pragma unroll
        for (int j = 0; j < 4; ++j) {
            us8 v = av[j];
            if (!ok) v = (us8){0, 0, 0, 0, 0, 0, 0, 0};
            *(us8*)&As[arow][ahalf + j * 8] = v;
        }
        __syncthreads();

        #pragma unroll
        for (int kk = 0; kk < 2; ++kk) {
            bfrag a[4], b[8];
            #pragma unroll
            for (int m = 0; m < 4; ++m)
                a[m] = *(const bfrag*)&As[wr * 64 + m * 16 + col][kk * 32 + q4 * 8];
            #pragma unroll
            for (int n = 0; n < 8; ++n)
                b[n] = *(const bfrag*)&Bs[(((wc * 8 + n) * 2 + kk) * 64 + lane) * 8];
            #pragma unroll
            for (int n = 0; n < 8; ++n)
                #pragma unroll
                for (int m = 0; m < 4; ++m)
                    acc[m][n] = __builtin_amdgcn_mfma_f32_16x16x32_bf16(a[m], b[n], acc[m][n], 0, 0, 0);
        }
        __syncthreads();
    }

    if (y == 2) {
        // V: write transposed, packed 4 consecutive s per store.
        #pragma unroll
        for (int n = 0; n < 8; ++n) {
            const int nn = wc * 128 + n * 16 + col;   // channel = h*32+dl
            const float bb = bv[nn];
            #pragma unroll
            for (int m = 0; m < 4; ++m) {
                const int s0 = t0 + wr * 64 + m * 16 + q4 * 4;
                us4 pk;
                #pragma unroll
                for (int r = 0; r < 4; ++r)
                    pk[r] = bf16rn(acc[m][n][r] + bb);
                *(us4*)(vbT + ((size_t)bn * 256 + nn) * 256 + s0) = pk;
            }
        }
    } else {
        const float* bias = (y == 0) ? bq : bk;
        unsigned short* dst = (y == 0) ? qb : kb;
        #pragma unroll
        for (int n = 0; n < 8; ++n) {
            const int nn = wc * 128 + n * 16 + col;
            const float bb = bias[nn];
            #pragma unroll
            for (int m = 0; m < 4; ++m)
                #pragma unroll
                for (int r = 0; r < 4; ++r) {
                    const size_t tok = (size_t)bn * 256 + t0 + wr * 64 + m * 16 + q4 * 4 + r;
                    dst[tok * D_ + nn] = bf16rn(acc[m][n][r] + bb);
                }
        }
    }
}

// ---------------------------------------------------------------------------
// Kernel 2: MFMA attention.  LDS = Ks + Pw only (54 KB -> 3 blocks/CU).
// V^T fragments read directly from vbT (L2-hot). Direct u16 P-writes.
// exp2-folded softmax.
// ---------------------------------------------------------------------------
__global__ __launch_bounds__(256) void k_attn_mfma(
    const unsigned short* __restrict__ qb, const unsigned short* __restrict__ kb,
    const unsigned short* __restrict__ vbT, unsigned short* __restrict__ ob)
{
    __shared__ __align__(16) unsigned short Ks[256][40];   // keys, pad->bank spread
    __shared__ __align__(16) unsigned short Pw[4][16][264];// per-wave P scratch

    const int bn   = blockIdx.x;
    const int h    = blockIdx.y;
    const int tid  = threadIdx.x;
    const int w    = tid >> 6;
    const int lane = tid & 63;
    const int col  = lane & 15;
    const int q4   = lane >> 4;
    const size_t base = (size_t)bn * S2_ * D_ + h * HD_;
    const unsigned short* vbase = vbT + ((size_t)bn * 256 + h * HD_) * 256;
    const float SCL2E = 0.17677669529663687f * 1.4426950408889634f; // 1/sqrt(32)*log2(e)

    // ---- stage K rows (us8 x4 per thread) ----
    {
        const unsigned short* kr = kb + base + (size_t)tid * D_;
        #pragma unroll
        for (int j = 0; j < 4; ++j)
            *(us8*)&Ks[tid][j * 8] = *(const us8*)(kr + j * 8);
    }
    __syncthreads();

    // ---- Q fragments direct from global (A-layout) ----
    const int r0w = w * 64;
    bfrag qa[4];
    #pragma unroll
    for (int mt = 0; mt < 4; ++mt)
        qa[mt] = *(const bfrag*)(qb + base + (size_t)(r0w + mt * 16 + col) * D_ + q4 * 8);

    for (int mt = 0; mt < 4; ++mt) {
        // ---- scores: 16 n-tiles, one MFMA each (K=32 = full HD) ----
        f32x4 sc[16];
        #pragma unroll
        for (int nt = 0; nt < 16; ++nt) {
            bfrag b = *(const bfrag*)&Ks[nt * 16 + col][q4 * 8];
            f32x4 z = {0.f, 0.f, 0.f, 0.f};
            sc[nt] = __builtin_amdgcn_mfma_f32_16x16x32_bf16(qa[mt], b, z, 0, 0, 0);
        }

        // ---- softmax over 256 cols (scale folded with log2e; exp2) ----
        float mx[4] = {-1e30f, -1e30f, -1e30f, -1e30f};
        #pragma unroll
        for (int nt = 0; nt < 16; ++nt)
            #pragma unroll
            for (int r = 0; r < 4; ++r) {
                sc[nt][r] *= SCL2E;
                mx[r] = fmaxf(mx[r], sc[nt][r]);
            }
        #pragma unroll
        for (int r = 0; r < 4; ++r) {
            mx[r] = fmaxf(mx[r], __shfl_xor(mx[r], 1));
            mx[r] = fmaxf(mx[r], __shfl_xor(mx[r], 2));
            mx[r] = fmaxf(mx[r], __shfl_xor(mx[r], 4));
            mx[r] = fmaxf(mx[r], __shfl_xor(mx[r], 8));
        }
        float l[4] = {0.f, 0.f, 0.f, 0.f};
        #pragma unroll
        for (int nt = 0; nt < 16; ++nt)
            #pragma unroll
            for (int r = 0; r < 4; ++r) {
                const float e = exp2f(sc[nt][r] - mx[r]);
                sc[nt][r] = e;
                l[r] += e;
            }
        #pragma unroll
        for (int r = 0; r < 4; ++r) {
            l[r] += __shfl_xor(l[r], 1);
            l[r] += __shfl_xor(l[r], 2);
            l[r] += __shfl_xor(l[r], 4);
            l[r] += __shfl_xor(l[r], 8);
        }

        // ---- P -> per-wave LDS (bf16), direct all-lane u16 stores ----
        #pragma unroll
        for (int nt = 0; nt < 16; ++nt)
            #pragma unroll
            for (int r = 0; r < 4; ++r)
                Pw[w][q4 * 4 + r][nt * 16 + col] = bf16rn(sc[nt][r]);
        // same-wave DS ordering: reads below see the writes (in-order DS pipe)

        // ---- V^T fragments direct from global (sc regs dead now) ----
        bfrag vf[2][8];
        #pragma unroll
        for (int kc = 0; kc < 8; ++kc)
            #pragma unroll
            for (int dt = 0; dt < 2; ++dt)
                vf[dt][kc] = *(const bfrag*)(vbase
                              + (size_t)(dt * 16 + col) * 256 + kc * 32 + q4 * 8);

        // ---- PV: o[16 x 32] ----
        f32x4 oacc[2];
        oacc[0] = (f32x4){0.f, 0.f, 0.f, 0.f};
        oacc[1] = (f32x4){0.f, 0.f, 0.f, 0.f};
        #pragma unroll
        for (int kc = 0; kc < 8; ++kc) {
            bfrag pa = *(const bfrag*)&Pw[w][col][kc * 32 + q4 * 8];
            #pragma unroll
            for (int dt = 0; dt < 2; ++dt)
                oacc[dt] = __builtin_amdgcn_mfma_f32_16x16x32_bf16(pa, vf[dt][kc], oacc[dt], 0, 0, 0);
        }

        // ---- normalize + write ----
        float inv[4];
        #pragma unroll
        for (int r = 0; r < 4; ++r) inv[r] = 1.f / l[r];
        #pragma unroll
        for (int dt = 0; dt < 2; ++dt)
            #pragma unroll
            for (int r = 0; r < 4; ++r)
                ob[base + (size_t)(r0w + mt * 16 + q4 * 4 + r) * D_ + dt * 16 + col]
                    = bf16rn(oacc[dt][r] * inv[r]);
    }
}

// ---------------------------------------------------------------------------
// Kernel 3: o @ Wo + bo + residual(x) -> LN1 -> h (fp32), MFMA. (unchanged)
// ---------------------------------------------------------------------------
__global__ __launch_bounds__(256) void k_oproj_gemm(
    const unsigned short* __restrict__ ob,
    const unsigned short* __restrict__ Wo_pk, const float* __restrict__ bo,
    const float* __restrict__ x,
    const float* __restrict__ g1, const float* __restrict__ be1,
    float* __restrict__ hout)
{
    __shared__ __align__(16) unsigned short As[128][72];
    __shared__ __align__(16) unsigned short Bs[16384];
    __shared__ float red[128][2][2];

    const int tid = threadIdx.x, w = tid >> 6, lane = tid & 63;
    const int col = lane & 15, q4 = lane >> 4;
    const int wr = w >> 1, wc = w & 1;
    const size_t tok0 = (size_t)blockIdx.x * 128;

    f32x4 acc[4][8];
    #pragma unroll
    for (int m = 0; m < 4; ++m)
        #pragma unroll
        for (int n = 0; n < 8; ++n)
            acc[m][n] = (f32x4){0.f, 0.f, 0.f, 0.f};

    const int arow = tid >> 1, ahalf = (tid & 1) * 32;

    for (int c = 0; c < 4; ++c) {
        const unsigned short* ap = ob + (tok0 + arow) * D_ + c * 64 + ahalf;
        us8 av[4];
        #pragma unroll
        for (int j = 0; j < 4; ++j)
            av[j] = *(const us8*)(ap + j * 8);

        const char* wb = (const char*)(Wo_pk + (size_t)c * 16384);
        #pragma unroll
        for (int r = 0; r < 8; ++r) {
            const int boff = (r * 4 + w) * 1024;
            gload_lds16(wb + boff + lane * 16, ((char*)Bs) + boff);
        }

        #pragma unroll
        for (int j = 0; j < 4; ++j)
            *(us8*)&As[arow][ahalf + j * 8] = av[j];
        __syncthreads();

        #pragma unroll
        for (int kk = 0; kk < 2; ++kk) {
            bfrag a[4], b[8];
            #pragma unroll
            for (int m = 0; m < 4; ++m)
                a[m] = *(const bfrag*)&As[wr * 64 + m * 16 + col][kk * 32 + q4 * 8];
            #pragma unroll
            for (int n = 0; n < 8; ++n)
                b[n] = *(const bfrag*)&Bs[(((wc * 8 + n) * 2 + kk) * 64 + lane) * 8];
            #pragma unroll
            for (int n = 0; n < 8; ++n)
                #pragma unroll
                for (int m = 0; m < 4; ++m)
                    acc[m][n] = __builtin_amdgcn_mfma_f32_16x16x32_bf16(a[m], b[n], acc[m][n], 0, 0, 0);
        }
        __syncthreads();
    }

    float bov[8];
    #pragma unroll
    for (int n = 0; n < 8; ++n)
        bov[n] = bo[wc * 128 + n * 16 + col];

    float s[4][4], s2[4][4];
    #pragma unroll
    for (int m = 0; m < 4; ++m)
        #pragma unroll
        for (int r = 0; r < 4; ++r) { s[m][r] = 0.f; s2[m][r] = 0.f; }

    #pragma unroll
    for (int m = 0; m < 4; ++m)
        #pragma unroll
        for (int r = 0; r < 4; ++r) {
            const size_t row = tok0 + wr * 64 + m * 16 + q4 * 4 + r;
            #pragma unroll
            for (int n = 0; n < 8; ++n) {
                const int nn = wc * 128 + n * 16 + col;
                const float yv = acc[m][n][r] + bov[n] + x[row * D_ + nn];
                acc[m][n][r] = yv;
                s[m][r] += yv;
                s2[m][r] = fmaf(yv, yv, s2[m][r]);
            }
        }

    #pragma unroll
    for (int m = 0; m < 4; ++m)
        #pragma unroll
        for (int r = 0; r < 4; ++r) {
            #pragma unroll
            for (int d = 1; d < 16; d <<= 1) {
                s[m][r]  += __shfl_xor(s[m][r],  d);
                s2[m][r] += __shfl_xor(s2[m][r], d);
            }
        }

    if (col == 0) {
        #pragma unroll
        for (int m = 0; m < 4; ++m)
            #pragma unroll
            for (int r = 0; r < 4; ++r) {
                const int rl = wr * 64 + m * 16 + q4 * 4 + r;
                red[rl][wc][0] = s[m][r];
                red[rl][wc][1] = s2[m][r];
            }
    }
    __syncthreads();

    float mu[4][4], rs[4][4];
    #pragma unroll
    for (int m = 0; m < 4; ++m)
        #pragma unroll
        for (int r = 0; r < 4; ++r) {
            const int rl = wr * 64 + m * 16 + q4 * 4 + r;
            const float ts  = red[rl][0][0] + red[rl][1][0];
            const float ts2 = red[rl][0][1] + red[rl][1][1];
            const float m_  = ts * (1.f / 256.f);
            mu[m][r] = m_;
            rs[m][r] = rsqrtf(ts2 * (1.f / 256.f) - m_ * m_ + EPS_);
        }

    #pragma unroll
    for (int n = 0; n < 8; ++n) {
        const int nn = wc * 128 + n * 16 + col;
        const float gv = g1[nn], bev = be1[nn];
        #pragma unroll
        for (int m = 0; m < 4; ++m)
            #pragma unroll
            for (int r = 0; r < 4; ++r) {
                const size_t row = tok0 + wr * 64 + m * 16 + q4 * 4 + r;
                hout[row * D_ + nn] = (acc[m][n][r] - mu[m][r]) * rs[m][r] * gv + bev;
            }
    }
}

// ---------------------------------------------------------------------------
// Kernel 4a: ff = leaky(h @ W1 + b1).  (unchanged)
// ---------------------------------------------------------------------------
__global__ __launch_bounds__(256) void k_ffn1_gemm(
    const float* __restrict__ h,
    const unsigned short* __restrict__ W1_pk, const float* __restrict__ b1,
    unsigned short* __restrict__ ff)
{
    __shared__ __align__(16) unsigned short As[128][72];
    __shared__ __align__(16) unsigned short Bs[16384];

    const int tid = threadIdx.x, w = tid >> 6, lane = tid & 63;
    const int col = lane & 15, q4 = lane >> 4;
    const int wr = w >> 1, wc = w & 1;
    const size_t tok0 = (size_t)blockIdx.x * 128;
    const int y = blockIdx.y;                 // n-panel
    const unsigned short* Wpk = W1_pk + (size_t)y * 4 * 16384;

    f32x4 acc[4][8];
    #pragma unroll
    for (int m = 0; m < 4; ++m)
        #pragma unroll
        for (int n = 0; n < 8; ++n)
            acc[m][n] = (f32x4){0.f, 0.f, 0.f, 0.f};

    const int arow = tid >> 1, ahalf = (tid & 1) * 32;

    for (int c = 0; c < 4; ++c) {
        const float* ap = h + (tok0 + arow) * D_ + c * 64 + ahalf;
        us8 av[4];
        #pragma unroll
        for (int j = 0; j < 4; ++j) {
            float4 f0 = *(const float4*)(ap + j * 8);
            float4 f1 = *(const float4*)(ap + j * 8 + 4);
            us8 v;
            v[0] = bf16rn(f0.x); v[1] = bf16rn(f0.y);
            v[2] = bf16rn(f0.z); v[3] = bf16rn(f0.w);
            v[4] = bf16rn(f1.x); v[5] = bf16rn(f1.y);
            v[6] = bf16rn(f1.z); v[7] = bf16rn(f1.w);
            av[j] = v;
        }

        const char* wb = (const char*)(Wpk + (size_t)c * 16384);
        #pragma unroll
        for (int r = 0; r < 8; ++r) {
            const int boff = (r * 4 + w) * 1024;
            gload_lds16(wb + boff + lane * 16, ((char*)Bs) + boff);
        }

        #pragma unroll
        for (int j = 0; j < 4; ++j)
            *(us8*)&As[arow][ahalf + j * 8] = av[j];
        __syncthreads();

        #pragma unroll
        for (int kk = 0; kk < 2; ++kk) {
            bfrag a[4], b[8];
            #pragma unroll
            for (int m = 0; m < 4; ++m)
                a[m] = *(const bfrag*)&As[wr * 64 + m * 16 + col][kk * 32 + q4 * 8];
            #pragma unroll
            for (int n = 0; n < 8; ++n)
                b[n] = *(const bfrag*)&Bs[(((wc * 8 + n) * 2 + kk) * 64 + lane) * 8];
            #pragma unroll
            for (int n = 0; n < 8; ++n)
                #pragma unroll
                for (int m = 0; m < 4; ++m)
                    acc[m][n] = __builtin_amdgcn_mfma_f32_16x16x32_bf16(a[m], b[n], acc[m][n], 0, 0, 0);
        }
        __syncthreads();
    }

    #pragma unroll
    for (int n = 0; n < 8; ++n) {
        const int nglob = y * 256 + wc * 128 + n * 16 + col;
        const float bb = b1[nglob];
        #pragma unroll
        for (int m = 0; m < 4; ++m)
            #pragma unroll
            for (int r = 0; r < 4; ++r) {
                float v = acc[m][n][r] + bb;
                v = (v > 0.f) ? v : NEG_ * v;
                ff[(tok0 + wr * 64 + m * 16 + q4 * 4 + r) * (size_t)F_ + nglob] = bf16rn(v);
            }
    }
}

// ---------------------------------------------------------------------------
// Kernel 4b: out = LN2(ff @ W2 + b2 + h).  (unchanged)
// ---------------------------------------------------------------------------
__global__ __launch_bounds__(256) void k_ffn2_gemm(
    const unsigned short* __restrict__ ff,
    const unsigned short* __restrict__ W2_pk, const float* __restrict__ b2,
    const float* __restrict__ h,
    const float* __restrict__ g2, const float* __restrict__ be2,
    float* __restrict__ out)
{
    __shared__ __align__(16) unsigned short As[128][72];
    __shared__ __align__(16) unsigned short Bs[16384];
    __shared__ float red[128][2][2];

    const int tid = threadIdx.x, w = tid >> 6, lane = tid & 63;
    const int col = lane & 15, q4 = lane >> 4;
    const int wr = w >> 1, wc = w & 1;
    const size_t tok0 = (size_t)blockIdx.x * 128;

    f32x4 acc[4][8];
    #pragma unroll
    for (int m = 0; m < 4; ++m)
        #pragma unroll
        for (int n = 0; n < 8; ++n)
            acc[m][n] = (f32x4){0.f, 0.f, 0.f, 0.f};

    const int arow = tid >> 1, ahalf = (tid & 1) * 32;

    for (int c = 0; c < 16; ++c) {
        const unsigned short* ap = ff + (tok0 + arow) * (size_t)F_ + c * 64 + ahalf;
        us8 av[4];
        #pragma unroll
        for (int j = 0; j < 4; ++j)
            av[j] = *(const us8*)(ap + j * 8);

        const char* wb = (const char*)(W2_pk + (size_t)c * 16384);
        #pragma unroll
        for (int r = 0; r < 8; ++r) {
            const int boff = (r * 4 + w) * 1024;
            gload_lds16(wb + boff + lane * 16, ((char*)Bs) + boff);
        }

        #pragma unroll
        for (int j = 0; j < 4; ++j)
            *(us8*)&As[arow][ahalf + j * 8] = av[j];
        __syncthreads();

        #pragma unroll
        for (int kk = 0; kk < 2; ++kk) {
            bfrag a[4], b[8];
            #pragma unroll
            for (int m = 0; m < 4; ++m)
                a[m] = *(const bfrag*)&As[wr * 64 + m * 16 + col][kk * 32 + q4 * 8];
            #pragma unroll
            for (int n = 0; n < 8; ++n)
                b[n] = *(const bfrag*)&Bs[(((wc * 8 + n) * 2 + kk) * 64 + lane) * 8];
            #pragma unroll
            for (int n = 0; n < 8; ++n)
                #pragma unroll
                for (int m = 0; m < 4; ++m)
                    acc[m][n] = __builtin_amdgcn_mfma_f32_16x16x32_bf16(a[m], b[n], acc[m][n], 0, 0, 0);
        }
        __syncthreads();
    }

    float b2v[8];
    #pragma unroll
    for (int n = 0; n < 8; ++n)
        b2v[n] = b2[wc * 128 + n * 16 + col];

    float s[4][4], s2[4][4];
    #pragma unroll
    for (int m = 0; m < 4; ++m)
        #pragma unroll
        for (int r = 0; r < 4; ++r) { s[m][r] = 0.f; s2[m][r] = 0.f; }

    #pragma unroll
    for (int m = 0; m < 4; ++m)
        #pragma unroll
        for (int r = 0; r < 4; ++r) {
            const size_t row = tok0 + wr * 64 + m * 16 + q4 * 4 + r;
            #pragma unroll
            for (int n = 0; n < 8; ++n) {
                const int nn = wc * 128 + n * 16 + col;
                const float yv = acc[m][n][r] + b2v[n] + h[row * D_ + nn];
                acc[m][n][r] = yv;
                s[m][r] += yv;
                s2[m][r] = fmaf(yv, yv, s2[m][r]);
            }
        }

    #pragma unroll
    for (int m = 0; m < 4; ++m)
        #pragma unroll
        for (int r = 0; r < 4; ++r) {
            #pragma unroll
            for (int d = 1; d < 16; d <<= 1) {
                s[m][r]  += __shfl_xor(s[m][r],  d);
                s2[m][r] += __shfl_xor(s2[m][r], d);
            }
        }

    if (col == 0) {
        #pragma unroll
        for (int m = 0; m < 4; ++m)
            #pragma unroll
            for (int r = 0; r < 4; ++r) {
                const int rl = wr * 64 + m * 16 + q4 * 4 + r;
                red[rl][wc][0] = s[m][r];
                red[rl][wc][1] = s2[m][r];
            }
    }
    __syncthreads();

    float mu[4][4], rs[4][4];
    #pragma unroll
    for (int m = 0; m < 4; ++m)
        #pragma unroll
        for (int r = 0; r < 4; ++r) {
            const int rl = wr * 64 + m * 16 + q4 * 4 + r;
            const float ts  = red[rl][0][0] + red[rl][1][0];
            const float ts2 = red[rl][0][1] + red[rl][1][1];
            const float m_  = ts * (1.f / 256.f);
            mu[m][r] = m_;
            rs[m][r] = rsqrtf(ts2 * (1.f / 256.f) - m_ * m_ + EPS_);
        }

    #pragma unroll
    for (int n = 0; n < 8; ++n) {
        const int nn = wc * 128 + n * 16 + col;
        const float gv = g2[nn], bev = be2[nn];
        #pragma unroll
        for (int m = 0; m < 4; ++m)
            #pragma unroll
            for (int r = 0; r < 4; ++r) {
                const size_t row = tok0 + wr * 64 + m * 16 + q4 * 4 + r;
                out[row * D_ + nn] = (acc[m][n][r] - mu[m][r]) * rs[m][r] * gv + bev;
            }
    }
}

// ---------------------------------------------------------------------------
extern "C" void kernel_launch(void* const* d_in, const int* in_sizes, int n_in,
                              void* d_out, int out_size, void* d_ws, size_t ws_size,
                              hipStream_t stream)
{
    const float* x   = (const float*)d_in[0];
    const float* Wq  = (const float*)d_in[1];
    const float* bq  = (const float*)d_in[2];
    const float* Wk  = (const float*)d_in[3];
    const float* bk  = (const float*)d_in[4];
    const float* Wv  = (const float*)d_in[5];
    const float* bv  = (const float*)d_in[6];
    const float* Wo  = (const float*)d_in[7];
    const float* bo  = (const float*)d_in[8];
    const float* W1  = (const float*)d_in[9];
    const float* b1  = (const float*)d_in[10];
    const float* W2  = (const float*)d_in[11];
    const float* b2  = (const float*)d_in[12];
    const float* g1  = (const float*)d_in[13];
    const float* be1 = (const float*)d_in[14];
    const float* g2  = (const float*)d_in[15];
    const float* be2 = (const float*)d_in[16];
    float* out = (float*)d_out;

    const size_t N = (size_t)B_ * S1_ * S2_ * D_;   // 16,777,216 elements

    unsigned short* qb  = (unsigned short*)d_ws;
    unsigned short* kb  = qb + N;
    unsigned short* vbT = kb + N;
    unsigned short* ob  = vbT + N;
    float*          h   = (float*)(ob + N);
    unsigned short* Wq_pk = (unsigned short*)(h + N);
    unsigned short* Wk_pk = Wq_pk + (size_t)12 * 16384;   // 196608
    unsigned short* Wv_pk = Wk_pk + (size_t)12 * 16384;
    unsigned short* Wo_pk = Wv_pk + (size_t)4 * 16384;    // 65536
    unsigned short* W1_pk = Wo_pk + (size_t)4 * 16384;
    unsigned short* W2_pk = W1_pk + (size_t)16 * 16384;   // 262144
    const size_t need = (size_t)(W2_pk + (size_t)16 * 16384 - (unsigned short*)d_ws) * 2;
    if (ws_size < need) return;

    // Aliases (lifetime-disjoint):
    unsigned short* xb16 = (unsigned short*)h;   // dead after k_qkv_gemm (h written after)
    unsigned short* ff   = qb;                   // spans qb..ob; all dead after oproj

    k_xcast     <<<dim3((unsigned)(N / 2048)), 256, 0, stream>>>(x, xb16);
    k_pack      <<<dim3(64), 256, 0, stream>>>(Wq, Wk, Wv, Wo, W1, W2,
                    Wq_pk, Wk_pk, Wv_pk, Wo_pk, W1_pk, W2_pk);
    k_qkv_gemm  <<<dim3(512, 3), 256, 0, stream>>>(
                    xb16, Wq_pk, Wk_pk, Wv_pk, bq, bk, bv, qb, kb, vbT);
    k_attn_mfma <<<dim3(B_ * S1_, H_), 256, 0, stream>>>(qb, kb, vbT, ob);
    k_oproj_gemm<<<dim3(512), 256, 0, stream>>>(
                    ob, Wo_pk, bo, x, g1, be1, h);
    k_ffn1_gemm <<<dim3(512, 4), 256, 0, stream>>>(h, W1_pk, b1, ff);
    k_ffn2_gemm <<<dim3(512), 256, 0, stream>>>(ff, W2_pk, b2, h, g2, be2, out);
}

// Round 6
// 660.139 us; speedup vs baseline: 1.4990x; 1.1548x over previous
//
#include <hip/hip_runtime.h>
#include <hip/hip_bf16.h>

// Problem constants
#define B_ 4
#define S1_ 64
#define S2_ 256
#define D_ 256
#define H_ 8
#define HD_ 32
#define F_ 1024
#define EPS_ 1e-5f
#define NEG_ 0.01f

typedef __attribute__((ext_vector_type(8))) short bfrag;   // 8 x bf16 (4 VGPRs)
typedef __attribute__((ext_vector_type(4))) float f32x4;   // MFMA C/D
typedef __attribute__((ext_vector_type(8))) unsigned short us8;
typedef __attribute__((ext_vector_type(4))) unsigned short us4;

__device__ __forceinline__ unsigned short bf16rn(float f) {
    union { float f; unsigned int u; } c; c.f = f;
    unsigned int u = c.u;
    u = (u + 0x7FFFu + ((u >> 16) & 1u)) >> 16;   // round-to-nearest-even
    return (unsigned short)u;
}

// async global->LDS, 16B per lane. lds base must be wave-uniform; HW adds lane*16.
__device__ __forceinline__ void gload_lds16(const void* g, void* l) {
    __builtin_amdgcn_global_load_lds(
        (const __attribute__((address_space(1))) void*)g,
        (__attribute__((address_space(3))) void*)l,
        16, 0, 0);
}

// ---------------------------------------------------------------------------
// x (fp32) -> xb16 (bf16), flat cast. 8 elems/thread.
// ---------------------------------------------------------------------------
__global__ __launch_bounds__(256) void k_xcast(
    const float* __restrict__ x, unsigned short* __restrict__ xb16)
{
    const size_t i = ((size_t)blockIdx.x * 256 + threadIdx.x) * 8;
    float4 f0 = *(const float4*)(x + i);
    float4 f1 = *(const float4*)(x + i + 4);
    us8 v;
    v[0] = bf16rn(f0.x); v[1] = bf16rn(f0.y); v[2] = bf16rn(f0.z); v[3] = bf16rn(f0.w);
    v[4] = bf16rn(f1.x); v[5] = bf16rn(f1.y); v[6] = bf16rn(f1.z); v[7] = bf16rn(f1.w);
    *(us8*)(xb16 + i) = v;
}

// ---------------------------------------------------------------------------
// Weight pack (unchanged): [k][n] -> MFMA fragment order per BK=64 chunk.
// ---------------------------------------------------------------------------
__global__ __launch_bounds__(256) void k_pack(
    const float* __restrict__ Wq, const float* __restrict__ Wk,
    const float* __restrict__ Wv, const float* __restrict__ Wo,
    const float* __restrict__ W1, const float* __restrict__ W2,
    unsigned short* __restrict__ Wq_pk, unsigned short* __restrict__ Wk_pk,
    unsigned short* __restrict__ Wv_pk, unsigned short* __restrict__ Wo_pk,
    unsigned short* __restrict__ W1_pk, unsigned short* __restrict__ W2_pk)
{
    const int blk = blockIdx.x;
    const float* src; unsigned short* dst; int Ntot = 256, n0 = 0, k0;
    if (blk < 12)      { src = Wq; k0 = blk * 64;        dst = Wq_pk + (size_t)blk * 16384; }
    else if (blk < 24) { src = Wk; k0 = (blk - 12) * 64; dst = Wk_pk + (size_t)(blk - 12) * 16384; }
    else if (blk < 28) { src = Wv; k0 = (blk - 24) * 64; dst = Wv_pk + (size_t)(blk - 24) * 16384; }
    else if (blk < 44) {
        const int i = blk - 28; const int p = i >> 2, c = i & 3;
        src = W1; Ntot = 1024; n0 = p * 256; k0 = c * 64;
        dst = W1_pk + (size_t)i * 16384;
    }
    else if (blk < 60) { src = W2; k0 = (blk - 44) * 64; dst = W2_pk + (size_t)(blk - 44) * 16384; }
    else               { src = Wo; k0 = (blk - 60) * 64; dst = Wo_pk + (size_t)(blk - 60) * 16384; }

    const int tid = threadIdx.x;
    for (int j = 0; j < 8; ++j) {
        const int fi = j * 256 + tid;
        const int lane = fi & 63;
        const int t2 = fi >> 6;          // nt*2+kk
        const int nt = t2 >> 1, kk = t2 & 1;
        const int col = lane & 15, q4 = lane >> 4;
        const int n = n0 + nt * 16 + col;
        const int kbase = k0 + kk * 32 + q4 * 8;
        us8 v;
        #pragma unroll
        for (int e = 0; e < 8; ++e)
            v[e] = bf16rn(src[(size_t)(kbase + e) * Ntot + n]);
        *(us8*)(dst + (size_t)fi * 8) = v;
    }
}

// ---------------------------------------------------------------------------
// Kernel 1: q/k time-conv + v as fragment-packed-B GEMMs.
// Epilogues write q/k/v in ATTENTION-FRAGMENT order per (bn,h):
//   qpk/kpk: frag fi = tile(s>>4)*64 + (s&15) + 16*(hd>>3), elem = hd&7
//   vpk:     frag fi = ((s>>5)*2 + (d>>4))*64 + (d&15) + 16*((s>>3)&3), elem = s&7
// Each (bn,h) slab = 16 frags * 64 lanes * 8 shorts = 8192 shorts (16 KB).
// ---------------------------------------------------------------------------
__global__ __launch_bounds__(256) void k_qkv_gemm(
    const unsigned short* __restrict__ xb16,
    const unsigned short* __restrict__ Wq_pk, const unsigned short* __restrict__ Wk_pk,
    const unsigned short* __restrict__ Wv_pk,
    const float* __restrict__ bq, const float* __restrict__ bk,
    const float* __restrict__ bv,
    unsigned short* __restrict__ qpk, unsigned short* __restrict__ kpk,
    unsigned short* __restrict__ vpk)
{
    __shared__ __align__(16) unsigned short As[128][72];
    __shared__ __align__(16) unsigned short Bs[16384];   // 32 KB, fragment-linear

    const int tid = threadIdx.x, w = tid >> 6, lane = tid & 63;
    const int col = lane & 15, q4 = lane >> 4;
    const int wr = w >> 1, wc = w & 1;
    const int y = blockIdx.y;
    const int bn = blockIdx.x >> 1, half = blockIdx.x & 1, t0 = half * 128;
    const int nch = (y == 2) ? 4 : 12;
    const unsigned short* Wpk = (y == 0) ? Wq_pk : (y == 1) ? Wk_pk : Wv_pk;

    f32x4 acc[4][8];
    #pragma unroll
    for (int m = 0; m < 4; ++m)
        #pragma unroll
        for (int n = 0; n < 8; ++n)
            acc[m][n] = (f32x4){0.f, 0.f, 0.f, 0.f};

    const int arow = tid >> 1, ahalf = (tid & 1) * 32;

    for (int c = 0; c < nch; ++c) {
        const int s  = (y == 2) ? 1 : (c >> 2);
        const int c0 = (y == 2) ? (c * 64) : ((c & 3) * 64);

        // A: issue global loads (conv-shifted row; clamp + zero at seq edges)
        const int trow = t0 + s - 1 + arow;
        const bool ok = (trow >= 0) && (trow < 256);
        const int trc = ok ? trow : (trow < 0 ? 0 : 255);
        const unsigned short* ap = xb16 + ((size_t)bn * 256 + trc) * 256 + c0 + ahalf;
        us8 av[4];
        #pragma unroll
        for (int j = 0; j < 4; ++j)
            av[j] = *(const us8*)(ap + j * 8);

        // B: async global->LDS, 8 x 1KB per wave, fully linear
        const char* wb = (const char*)(Wpk + (size_t)c * 16384);
        #pragma unroll
        for (int r = 0; r < 8; ++r) {
            const int boff = (r * 4 + w) * 1024;
            gload_lds16(wb + boff + lane * 16, ((char*)Bs) + boff);
        }

        // A: write to padded LDS (zero OOB rows)
        #pragma unroll
        for (int j = 0; j < 4; ++j) {
            us8 v = av[j];
            if (!ok) v = (us8){0, 0, 0, 0, 0, 0, 0, 0};
            *(us8*)&As[arow][ahalf + j * 8] = v;
        }
        __syncthreads();

        #pragma unroll
        for (int kk = 0; kk < 2; ++kk) {
            bfrag a[4], b[8];
            #pragma unroll
            for (int m = 0; m < 4; ++m)
                a[m] = *(const bfrag*)&As[wr * 64 + m * 16 + col][kk * 32 + q4 * 8];
            #pragma unroll
            for (int n = 0; n < 8; ++n)
                b[n] = *(const bfrag*)&Bs[(((wc * 8 + n) * 2 + kk) * 64 + lane) * 8];
            #pragma unroll
            for (int n = 0; n < 8; ++n)
                #pragma unroll
                for (int m = 0; m < 4; ++m)
                    acc[m][n] = __builtin_amdgcn_mfma_f32_16x16x32_bf16(a[m], b[n], acc[m][n], 0, 0, 0);
        }
        __syncthreads();
    }

    if (y == 2) {
        // V: fragment-packed (PV B-operand order), us4 stores (4 consecutive s).
        #pragma unroll
        for (int n = 0; n < 8; ++n) {
            const int nn = wc * 128 + n * 16 + col;
            const int hh = nn >> 5, d = nn & 31;
            const float bb = bv[nn];
            #pragma unroll
            for (int m = 0; m < 4; ++m) {
                const int s0 = t0 + wr * 64 + m * 16 + q4 * 4;
                us4 pk;
                #pragma unroll
                for (int r = 0; r < 4; ++r)
                    pk[r] = bf16rn(acc[m][n][r] + bb);
                const int kc = (s0 >> 5) & 7, q3 = (s0 >> 3) & 3, e0 = s0 & 7;
                *(us4*)(vpk + (((((size_t)bn * 8 + hh) * 8 + kc) * 2 + (d >> 4)) * 64
                               + (d & 15) + 16 * q3) * 8 + e0) = pk;
            }
        }
    } else {
        // Q/K: fragment-packed (QK A/B operand order), scalar u16 stores.
        unsigned short* dst = (y == 0) ? qpk : kpk;
        const float* bias = (y == 0) ? bq : bk;
        #pragma unroll
        for (int n = 0; n < 8; ++n) {
            const int nn = wc * 128 + n * 16 + col;
            const int hh = nn >> 5, hd = nn & 31;
            const float bb = bias[nn];
            #pragma unroll
            for (int m = 0; m < 4; ++m) {
                const int tile = (t0 >> 4) + wr * 4 + m;
                unsigned short* dp = dst
                    + ((((size_t)bn * 8 + hh) * 16 + tile) * 64 + 16 * (hd >> 3)) * 8
                    + (hd & 7);
                #pragma unroll
                for (int r = 0; r < 4; ++r)
                    dp[(q4 * 4 + r) * 8] = bf16rn(acc[m][n][r] + bb);
            }
        }
    }
}

// ---------------------------------------------------------------------------
// Kernel 2: MFMA attention. LDS = Pw (33.8 KB) + KsL (16 KB) = 50.2 KB
// -> 3 blocks/CU (real fit). K staged via global_load_lds (linear packed);
// Q A-frags and V B-frags read directly from packed global (L2-hot).
// One barrier per block; no scalar staging.
// ---------------------------------------------------------------------------
__global__ __launch_bounds__(256) void k_attn_mfma(
    const unsigned short* __restrict__ qpk, const unsigned short* __restrict__ kpk,
    const unsigned short* __restrict__ vpk, unsigned short* __restrict__ ob)
{
    __shared__ __align__(16) unsigned short KsL[8192];     // 16 KB, frag-linear
    __shared__ __align__(16) unsigned short Pw[4][16][264];// per-wave P scratch

    const int bn   = blockIdx.x;
    const int h    = blockIdx.y;
    const int tid  = threadIdx.x;
    const int w    = tid >> 6;
    const int lane = tid & 63;
    const int col  = lane & 15;
    const int q4   = lane >> 4;
    const size_t bhi = (size_t)bn * 8 + h;
    const size_t obase = (size_t)bn * S2_ * D_ + h * HD_;
    const unsigned short* qbase = qpk + bhi * 8192;
    const unsigned short* vbase = vpk + bhi * 8192;
    const float SCL2E = 0.17677669529663687f * 1.4426950408889634f; // 1/sqrt(32)*log2(e)

    // ---- stage K frags via async DMA: 16 x 1KB chunks, wave-linear ----
    {
        const char* kb = (const char*)(kpk + bhi * 8192);
        #pragma unroll
        for (int r = 0; r < 4; ++r) {
            const int fi = r * 4 + w;
            gload_lds16(kb + fi * 1024 + lane * 16, ((char*)KsL) + fi * 1024);
        }
    }
    __syncthreads();

    for (int mt = 0; mt < 4; ++mt) {
        // ---- Q A-frag (one 16B load, frag-linear) ----
        bfrag qa = *(const bfrag*)(qbase + ((size_t)(w * 4 + mt) * 64 + lane) * 8);

        // ---- scores: 16 n-tiles, one MFMA each (K=32 = full HD) ----
        f32x4 sc[16];
        #pragma unroll
        for (int nt = 0; nt < 16; ++nt) {
            bfrag kf = *(const bfrag*)&KsL[(nt * 64 + lane) * 8];
            f32x4 z = {0.f, 0.f, 0.f, 0.f};
            sc[nt] = __builtin_amdgcn_mfma_f32_16x16x32_bf16(qa, kf, z, 0, 0, 0);
        }

        // ---- softmax over 256 cols (scale folded with log2e; exp2) ----
        float mx[4] = {-1e30f, -1e30f, -1e30f, -1e30f};
        #pragma unroll
        for (int nt = 0; nt < 16; ++nt)
            #pragma unroll
            for (int r = 0; r < 4; ++r) {
                sc[nt][r] *= SCL2E;
                mx[r] = fmaxf(mx[r], sc[nt][r]);
            }
        #pragma unroll
        for (int r = 0; r < 4; ++r) {
            mx[r] = fmaxf(mx[r], __shfl_xor(mx[r], 1));
            mx[r] = fmaxf(mx[r], __shfl_xor(mx[r], 2));
            mx[r] = fmaxf(mx[r], __shfl_xor(mx[r], 4));
            mx[r] = fmaxf(mx[r], __shfl_xor(mx[r], 8));
        }
        float l[4] = {0.f, 0.f, 0.f, 0.f};
        #pragma unroll
        for (int nt = 0; nt < 16; ++nt)
            #pragma unroll
            for (int r = 0; r < 4; ++r) {
                const float e = exp2f(sc[nt][r] - mx[r]);
                sc[nt][r] = e;
                l[r] += e;
            }
        #pragma unroll
        for (int r = 0; r < 4; ++r) {
            l[r] += __shfl_xor(l[r], 1);
            l[r] += __shfl_xor(l[r], 2);
            l[r] += __shfl_xor(l[r], 4);
            l[r] += __shfl_xor(l[r], 8);
        }

        // ---- P -> per-wave LDS (bf16), direct all-lane u16 stores ----
        #pragma unroll
        for (int nt = 0; nt < 16; ++nt)
            #pragma unroll
            for (int r = 0; r < 4; ++r)
                Pw[w][q4 * 4 + r][nt * 16 + col] = bf16rn(sc[nt][r]);
        // same-wave DS ordering: reads below see the writes (in-order DS pipe)

        // ---- PV: o[16 x 32], V B-frags direct from packed global ----
        f32x4 oacc[2];
        oacc[0] = (f32x4){0.f, 0.f, 0.f, 0.f};
        oacc[1] = (f32x4){0.f, 0.f, 0.f, 0.f};
        #pragma unroll
        for (int kc = 0; kc < 8; ++kc) {
            bfrag pa = *(const bfrag*)&Pw[w][col][kc * 32 + q4 * 8];
            bfrag v0 = *(const bfrag*)(vbase + ((size_t)(kc * 2 + 0) * 64 + lane) * 8);
            bfrag v1 = *(const bfrag*)(vbase + ((size_t)(kc * 2 + 1) * 64 + lane) * 8);
            oacc[0] = __builtin_amdgcn_mfma_f32_16x16x32_bf16(pa, v0, oacc[0], 0, 0, 0);
            oacc[1] = __builtin_amdgcn_mfma_f32_16x16x32_bf16(pa, v1, oacc[1], 0, 0, 0);
        }

        // ---- normalize + write ----
        const int r0w = w * 64;
        float inv[4];
        #pragma unroll
        for (int r = 0; r < 4; ++r) inv[r] = 1.f / l[r];
        #pragma unroll
        for (int dt = 0; dt < 2; ++dt)
            #pragma unroll
            for (int r = 0; r < 4; ++r)
                ob[obase + (size_t)(r0w + mt * 16 + q4 * 4 + r) * D_ + dt * 16 + col]
                    = bf16rn(oacc[dt][r] * inv[r]);
    }
}

// ---------------------------------------------------------------------------
// Kernel 3: o @ Wo + bo + residual(x) -> LN1 -> h (fp32), MFMA. (unchanged)
// ---------------------------------------------------------------------------
__global__ __launch_bounds__(256) void k_oproj_gemm(
    const unsigned short* __restrict__ ob,
    const unsigned short* __restrict__ Wo_pk, const float* __restrict__ bo,
    const float* __restrict__ x,
    const float* __restrict__ g1, const float* __restrict__ be1,
    float* __restrict__ hout)
{
    __shared__ __align__(16) unsigned short As[128][72];
    __shared__ __align__(16) unsigned short Bs[16384];
    __shared__ float red[128][2][2];

    const int tid = threadIdx.x, w = tid >> 6, lane = tid & 63;
    const int col = lane & 15, q4 = lane >> 4;
    const int wr = w >> 1, wc = w & 1;
    const size_t tok0 = (size_t)blockIdx.x * 128;

    f32x4 acc[4][8];
    #pragma unroll
    for (int m = 0; m < 4; ++m)
        #pragma unroll
        for (int n = 0; n < 8; ++n)
            acc[m][n] = (f32x4){0.f, 0.f, 0.f, 0.f};

    const int arow = tid >> 1, ahalf = (tid & 1) * 32;

    for (int c = 0; c < 4; ++c) {
        const unsigned short* ap = ob + (tok0 + arow) * D_ + c * 64 + ahalf;
        us8 av[4];
        #pragma unroll
        for (int j = 0; j < 4; ++j)
            av[j] = *(const us8*)(ap + j * 8);

        const char* wb = (const char*)(Wo_pk + (size_t)c * 16384);
        #pragma unroll
        for (int r = 0; r < 8; ++r) {
            const int boff = (r * 4 + w) * 1024;
            gload_lds16(wb + boff + lane * 16, ((char*)Bs) + boff);
        }

        #pragma unroll
        for (int j = 0; j < 4; ++j)
            *(us8*)&As[arow][ahalf + j * 8] = av[j];
        __syncthreads();

        #pragma unroll
        for (int kk = 0; kk < 2; ++kk) {
            bfrag a[4], b[8];
            #pragma unroll
            for (int m = 0; m < 4; ++m)
                a[m] = *(const bfrag*)&As[wr * 64 + m * 16 + col][kk * 32 + q4 * 8];
            #pragma unroll
            for (int n = 0; n < 8; ++n)
                b[n] = *(const bfrag*)&Bs[(((wc * 8 + n) * 2 + kk) * 64 + lane) * 8];
            #pragma unroll
            for (int n = 0; n < 8; ++n)
                #pragma unroll
                for (int m = 0; m < 4; ++m)
                    acc[m][n] = __builtin_amdgcn_mfma_f32_16x16x32_bf16(a[m], b[n], acc[m][n], 0, 0, 0);
        }
        __syncthreads();
    }

    float bov[8];
    #pragma unroll
    for (int n = 0; n < 8; ++n)
        bov[n] = bo[wc * 128 + n * 16 + col];

    float s[4][4], s2[4][4];
    #pragma unroll
    for (int m = 0; m < 4; ++m)
        #pragma unroll
        for (int r = 0; r < 4; ++r) { s[m][r] = 0.f; s2[m][r] = 0.f; }

    #pragma unroll
    for (int m = 0; m < 4; ++m)
        #pragma unroll
        for (int r = 0; r < 4; ++r) {
            const size_t row = tok0 + wr * 64 + m * 16 + q4 * 4 + r;
            #pragma unroll
            for (int n = 0; n < 8; ++n) {
                const int nn = wc * 128 + n * 16 + col;
                const float yv = acc[m][n][r] + bov[n] + x[row * D_ + nn];
                acc[m][n][r] = yv;
                s[m][r] += yv;
                s2[m][r] = fmaf(yv, yv, s2[m][r]);
            }
        }

    #pragma unroll
    for (int m = 0; m < 4; ++m)
        #pragma unroll
        for (int r = 0; r < 4; ++r) {
            #pragma unroll
            for (int d = 1; d < 16; d <<= 1) {
                s[m][r]  += __shfl_xor(s[m][r],  d);
                s2[m][r] += __shfl_xor(s2[m][r], d);
            }
        }

    if (col == 0) {
        #pragma unroll
        for (int m = 0; m < 4; ++m)
            #pragma unroll
            for (int r = 0; r < 4; ++r) {
                const int rl = wr * 64 + m * 16 + q4 * 4 + r;
                red[rl][wc][0] = s[m][r];
                red[rl][wc][1] = s2[m][r];
            }
    }
    __syncthreads();

    float mu[4][4], rs[4][4];
    #pragma unroll
    for (int m = 0; m < 4; ++m)
        #pragma unroll
        for (int r = 0; r < 4; ++r) {
            const int rl = wr * 64 + m * 16 + q4 * 4 + r;
            const float ts  = red[rl][0][0] + red[rl][1][0];
            const float ts2 = red[rl][0][1] + red[rl][1][1];
            const float m_  = ts * (1.f / 256.f);
            mu[m][r] = m_;
            rs[m][r] = rsqrtf(ts2 * (1.f / 256.f) - m_ * m_ + EPS_);
        }

    #pragma unroll
    for (int n = 0; n < 8; ++n) {
        const int nn = wc * 128 + n * 16 + col;
        const float gv = g1[nn], bev = be1[nn];
        #pragma unroll
        for (int m = 0; m < 4; ++m)
            #pragma unroll
            for (int r = 0; r < 4; ++r) {
                const size_t row = tok0 + wr * 64 + m * 16 + q4 * 4 + r;
                hout[row * D_ + nn] = (acc[m][n][r] - mu[m][r]) * rs[m][r] * gv + bev;
            }
    }
}

// ---------------------------------------------------------------------------
// Kernel 4a: ff = leaky(h @ W1 + b1).  (unchanged)
// ---------------------------------------------------------------------------
__global__ __launch_bounds__(256) void k_ffn1_gemm(
    const float* __restrict__ h,
    const unsigned short* __restrict__ W1_pk, const float* __restrict__ b1,
    unsigned short* __restrict__ ff)
{
    __shared__ __align__(16) unsigned short As[128][72];
    __shared__ __align__(16) unsigned short Bs[16384];

    const int tid = threadIdx.x, w = tid >> 6, lane = tid & 63;
    const int col = lane & 15, q4 = lane >> 4;
    const int wr = w >> 1, wc = w & 1;
    const size_t tok0 = (size_t)blockIdx.x * 128;
    const int y = blockIdx.y;                 // n-panel
    const unsigned short* Wpk = W1_pk + (size_t)y * 4 * 16384;

    f32x4 acc[4][8];
    #pragma unroll
    for (int m = 0; m < 4; ++m)
        #pragma unroll
        for (int n = 0; n < 8; ++n)
            acc[m][n] = (f32x4){0.f, 0.f, 0.f, 0.f};

    const int arow = tid >> 1, ahalf = (tid & 1) * 32;

    for (int c = 0; c < 4; ++c) {
        const float* ap = h + (tok0 + arow) * D_ + c * 64 + ahalf;
        us8 av[4];
        #pragma unroll
        for (int j = 0; j < 4; ++j) {
            float4 f0 = *(const float4*)(ap + j * 8);
            float4 f1 = *(const float4*)(ap + j * 8 + 4);
            us8 v;
            v[0] = bf16rn(f0.x); v[1] = bf16rn(f0.y);
            v[2] = bf16rn(f0.z); v[3] = bf16rn(f0.w);
            v[4] = bf16rn(f1.x); v[5] = bf16rn(f1.y);
            v[6] = bf16rn(f1.z); v[7] = bf16rn(f1.w);
            av[j] = v;
        }

        const char* wb = (const char*)(Wpk + (size_t)c * 16384);
        #pragma unroll
        for (int r = 0; r < 8; ++r) {
            const int boff = (r * 4 + w) * 1024;
            gload_lds16(wb + boff + lane * 16, ((char*)Bs) + boff);
        }

        #pragma unroll
        for (int j = 0; j < 4; ++j)
            *(us8*)&As[arow][ahalf + j * 8] = av[j];
        __syncthreads();

        #pragma unroll
        for (int kk = 0; kk < 2; ++kk) {
            bfrag a[4], b[8];
            #pragma unroll
            for (int m = 0; m < 4; ++m)
                a[m] = *(const bfrag*)&As[wr * 64 + m * 16 + col][kk * 32 + q4 * 8];
            #pragma unroll
            for (int n = 0; n < 8; ++n)
                b[n] = *(const bfrag*)&Bs[(((wc * 8 + n) * 2 + kk) * 64 + lane) * 8];
            #pragma unroll
            for (int n = 0; n < 8; ++n)
                #pragma unroll
                for (int m = 0; m < 4; ++m)
                    acc[m][n] = __builtin_amdgcn_mfma_f32_16x16x32_bf16(a[m], b[n], acc[m][n], 0, 0, 0);
        }
        __syncthreads();
    }

    #pragma unroll
    for (int n = 0; n < 8; ++n) {
        const int nglob = y * 256 + wc * 128 + n * 16 + col;
        const float bb = b1[nglob];
        #pragma unroll
        for (int m = 0; m < 4; ++m)
            #pragma unroll
            for (int r = 0; r < 4; ++r) {
                float v = acc[m][n][r] + bb;
                v = (v > 0.f) ? v : NEG_ * v;
                ff[(tok0 + wr * 64 + m * 16 + q4 * 4 + r) * (size_t)F_ + nglob] = bf16rn(v);
            }
    }
}

// ---------------------------------------------------------------------------
// Kernel 4b: out = LN2(ff @ W2 + b2 + h).  (unchanged)
// ---------------------------------------------------------------------------
__global__ __launch_bounds__(256) void k_ffn2_gemm(
    const unsigned short* __restrict__ ff,
    const unsigned short* __restrict__ W2_pk, const float* __restrict__ b2,
    const float* __restrict__ h,
    const float* __restrict__ g2, const float* __restrict__ be2,
    float* __restrict__ out)
{
    __shared__ __align__(16) unsigned short As[128][72];
    __shared__ __align__(16) unsigned short Bs[16384];
    __shared__ float red[128][2][2];

    const int tid = threadIdx.x, w = tid >> 6, lane = tid & 63;
    const int col = lane & 15, q4 = lane >> 4;
    const int wr = w >> 1, wc = w & 1;
    const size_t tok0 = (size_t)blockIdx.x * 128;

    f32x4 acc[4][8];
    #pragma unroll
    for (int m = 0; m < 4; ++m)
        #pragma unroll
        for (int n = 0; n < 8; ++n)
            acc[m][n] = (f32x4){0.f, 0.f, 0.f, 0.f};

    const int arow = tid >> 1, ahalf = (tid & 1) * 32;

    for (int c = 0; c < 16; ++c) {
        const unsigned short* ap = ff + (tok0 + arow) * (size_t)F_ + c * 64 + ahalf;
        us8 av[4];
        #pragma unroll
        for (int j = 0; j < 4; ++j)
            av[j] = *(const us8*)(ap + j * 8);

        const char* wb = (const char*)(W2_pk + (size_t)c * 16384);
        #pragma unroll
        for (int r = 0; r < 8; ++r) {
            const int boff = (r * 4 + w) * 1024;
            gload_lds16(wb + boff + lane * 16, ((char*)Bs) + boff);
        }

        #pragma unroll
        for (int j = 0; j < 4; ++j)
            *(us8*)&As[arow][ahalf + j * 8] = av[j];
        __syncthreads();

        #pragma unroll
        for (int kk = 0; kk < 2; ++kk) {
            bfrag a[4], b[8];
            #pragma unroll
            for (int m = 0; m < 4; ++m)
                a[m] = *(const bfrag*)&As[wr * 64 + m * 16 + col][kk * 32 + q4 * 8];
            #pragma unroll
            for (int n = 0; n < 8; ++n)
                b[n] = *(const bfrag*)&Bs[(((wc * 8 + n) * 2 + kk) * 64 + lane) * 8];
            #pragma unroll
            for (int n = 0; n < 8; ++n)
                #pragma unroll
                for (int m = 0; m < 4; ++m)
                    acc[m][n] = __builtin_amdgcn_mfma_f32_16x16x32_bf16(a[m], b[n], acc[m][n], 0, 0, 0);
        }
        __syncthreads();
    }

    float b2v[8];
    #pragma unroll
    for (int n = 0; n < 8; ++n)
        b2v[n] = b2[wc * 128 + n * 16 + col];

    float s[4][4], s2[4][4];
    #pragma unroll
    for (int m = 0; m < 4; ++m)
        #pragma unroll
        for (int r = 0; r < 4; ++r) { s[m][r] = 0.f; s2[m][r] = 0.f; }

    #pragma unroll
    for (int m = 0; m < 4; ++m)
        #pragma unroll
        for (int r = 0; r < 4; ++r) {
            const size_t row = tok0 + wr * 64 + m * 16 + q4 * 4 + r;
            #pragma unroll
            for (int n = 0; n < 8; ++n) {
                const int nn = wc * 128 + n * 16 + col;
                const float yv = acc[m][n][r] + b2v[n] + h[row * D_ + nn];
                acc[m][n][r] = yv;
                s[m][r] += yv;
                s2[m][r] = fmaf(yv, yv, s2[m][r]);
            }
        }

    #pragma unroll
    for (int m = 0; m < 4; ++m)
        #pragma unroll
        for (int r = 0; r < 4; ++r) {
            #pragma unroll
            for (int d = 1; d < 16; d <<= 1) {
                s[m][r]  += __shfl_xor(s[m][r],  d);
                s2[m][r] += __shfl_xor(s2[m][r], d);
            }
        }

    if (col == 0) {
        #pragma unroll
        for (int m = 0; m < 4; ++m)
            #pragma unroll
            for (int r = 0; r < 4; ++r) {
                const int rl = wr * 64 + m * 16 + q4 * 4 + r;
                red[rl][wc][0] = s[m][r];
                red[rl][wc][1] = s2[m][r];
            }
    }
    __syncthreads();

    float mu[4][4], rs[4][4];
    #pragma unroll
    for (int m = 0; m < 4; ++m)
        #pragma unroll
        for (int r = 0; r < 4; ++r) {
            const int rl = wr * 64 + m * 16 + q4 * 4 + r;
            const float ts  = red[rl][0][0] + red[rl][1][0];
            const float ts2 = red[rl][0][1] + red[rl][1][1];
            const float m_  = ts * (1.f / 256.f);
            mu[m][r] = m_;
            rs[m][r] = rsqrtf(ts2 * (1.f / 256.f) - m_ * m_ + EPS_);
        }

    #pragma unroll
    for (int n = 0; n < 8; ++n) {
        const int nn = wc * 128 + n * 16 + col;
        const float gv = g2[nn], bev = be2[nn];
        #pragma unroll
        for (int m = 0; m < 4; ++m)
            #pragma unroll
            for (int r = 0; r < 4; ++r) {
                const size_t row = tok0 + wr * 64 + m * 16 + q4 * 4 + r;
                out[row * D_ + nn] = (acc[m][n][r] - mu[m][r]) * rs[m][r] * gv + bev;
            }
    }
}

// ---------------------------------------------------------------------------
extern "C" void kernel_launch(void* const* d_in, const int* in_sizes, int n_in,
                              void* d_out, int out_size, void* d_ws, size_t ws_size,
                              hipStream_t stream)
{
    const float* x   = (const float*)d_in[0];
    const float* Wq  = (const float*)d_in[1];
    const float* bq  = (const float*)d_in[2];
    const float* Wk  = (const float*)d_in[3];
    const float* bk  = (const float*)d_in[4];
    const float* Wv  = (const float*)d_in[5];
    const float* bv  = (const float*)d_in[6];
    const float* Wo  = (const float*)d_in[7];
    const float* bo  = (const float*)d_in[8];
    const float* W1  = (const float*)d_in[9];
    const float* b1  = (const float*)d_in[10];
    const float* W2  = (const float*)d_in[11];
    const float* b2  = (const float*)d_in[12];
    const float* g1  = (const float*)d_in[13];
    const float* be1 = (const float*)d_in[14];
    const float* g2  = (const float*)d_in[15];
    const float* be2 = (const float*)d_in[16];
    float* out = (float*)d_out;

    const size_t N = (size_t)B_ * S1_ * S2_ * D_;   // 16,777,216 elements

    unsigned short* qpk = (unsigned short*)d_ws;    // frag-packed per (bn,h)
    unsigned short* kpk = qpk + N;
    unsigned short* vpk = kpk + N;
    unsigned short* ob  = vpk + N;
    float*          h   = (float*)(ob + N);
    unsigned short* Wq_pk = (unsigned short*)(h + N);
    unsigned short* Wk_pk = Wq_pk + (size_t)12 * 16384;   // 196608
    unsigned short* Wv_pk = Wk_pk + (size_t)12 * 16384;
    unsigned short* Wo_pk = Wv_pk + (size_t)4 * 16384;    // 65536
    unsigned short* W1_pk = Wo_pk + (size_t)4 * 16384;
    unsigned short* W2_pk = W1_pk + (size_t)16 * 16384;   // 262144
    const size_t need = (size_t)(W2_pk + (size_t)16 * 16384 - (unsigned short*)d_ws) * 2;
    if (ws_size < need) return;

    // Aliases (lifetime-disjoint):
    unsigned short* xb16 = (unsigned short*)h;   // dead after k_qkv_gemm (h written after)
    unsigned short* ff   = qpk;                  // spans qpk..ob; all dead after oproj

    k_xcast     <<<dim3((unsigned)(N / 2048)), 256, 0, stream>>>(x, xb16);
    k_pack      <<<dim3(64), 256, 0, stream>>>(Wq, Wk, Wv, Wo, W1, W2,
                    Wq_pk, Wk_pk, Wv_pk, Wo_pk, W1_pk, W2_pk);
    k_qkv_gemm  <<<dim3(512, 3), 256, 0, stream>>>(
                    xb16, Wq_pk, Wk_pk, Wv_pk, bq, bk, bv, qpk, kpk, vpk);
    k_attn_mfma <<<dim3(B_ * S1_, H_), 256, 0, stream>>>(qpk, kpk, vpk, ob);
    k_oproj_gemm<<<dim3(512), 256, 0, stream>>>(
                    ob, Wo_pk, bo, x, g1, be1, h);
    k_ffn1_gemm <<<dim3(512, 4), 256, 0, stream>>>(h, W1_pk, b1, ff);
    k_ffn2_gemm <<<dim3(512), 256, 0, stream>>>(ff, W2_pk, b2, h, g2, be2, out);
}

// Round 7
// 602.786 us; speedup vs baseline: 1.6416x; 1.0951x over previous
//
#include <hip/hip_runtime.h>
#include <hip/hip_bf16.h>

// Problem constants
#define B_ 4
#define S1_ 64
#define S2_ 256
#define D_ 256
#define H_ 8
#define HD_ 32
#define F_ 1024
#define EPS_ 1e-5f
#define NEG_ 0.01f

typedef __attribute__((ext_vector_type(8))) short bfrag;   // 8 x bf16 (4 VGPRs)
typedef __attribute__((ext_vector_type(4))) float f32x4;   // MFMA C/D
typedef __attribute__((ext_vector_type(8))) unsigned short us8;
typedef __attribute__((ext_vector_type(4))) unsigned short us4;

__device__ __forceinline__ unsigned short bf16rn(float f) {
    union { float f; unsigned int u; } c; c.f = f;
    unsigned int u = c.u;
    u = (u + 0x7FFFu + ((u >> 16) & 1u)) >> 16;   // round-to-nearest-even
    return (unsigned short)u;
}
__device__ __forceinline__ float bf2f(unsigned short s) {
    union { unsigned int u; float f; } c; c.u = ((unsigned int)s) << 16;
    return c.f;
}

// async global->LDS, 16B per lane. lds base must be wave-uniform; HW adds lane*16.
__device__ __forceinline__ void gload_lds16(const void* g, void* l) {
    __builtin_amdgcn_global_load_lds(
        (const __attribute__((address_space(1))) void*)g,
        (__attribute__((address_space(3))) void*)l,
        16, 0, 0);
}

// ---------------------------------------------------------------------------
// x (fp32) -> xb16 (bf16), flat cast. 8 elems/thread.
// ---------------------------------------------------------------------------
__global__ __launch_bounds__(256) void k_xcast(
    const float* __restrict__ x, unsigned short* __restrict__ xb16)
{
    const size_t i = ((size_t)blockIdx.x * 256 + threadIdx.x) * 8;
    float4 f0 = *(const float4*)(x + i);
    float4 f1 = *(const float4*)(x + i + 4);
    us8 v;
    v[0] = bf16rn(f0.x); v[1] = bf16rn(f0.y); v[2] = bf16rn(f0.z); v[3] = bf16rn(f0.w);
    v[4] = bf16rn(f1.x); v[5] = bf16rn(f1.y); v[6] = bf16rn(f1.z); v[7] = bf16rn(f1.w);
    *(us8*)(xb16 + i) = v;
}

// ---------------------------------------------------------------------------
// Weight pack (unchanged): [k][n] -> MFMA fragment order per BK=64 chunk.
// ---------------------------------------------------------------------------
__global__ __launch_bounds__(256) void k_pack(
    const float* __restrict__ Wq, const float* __restrict__ Wk,
    const float* __restrict__ Wv, const float* __restrict__ Wo,
    const float* __restrict__ W1, const float* __restrict__ W2,
    unsigned short* __restrict__ Wq_pk, unsigned short* __restrict__ Wk_pk,
    unsigned short* __restrict__ Wv_pk, unsigned short* __restrict__ Wo_pk,
    unsigned short* __restrict__ W1_pk, unsigned short* __restrict__ W2_pk)
{
    const int blk = blockIdx.x;
    const float* src; unsigned short* dst; int Ntot = 256, n0 = 0, k0;
    if (blk < 12)      { src = Wq; k0 = blk * 64;        dst = Wq_pk + (size_t)blk * 16384; }
    else if (blk < 24) { src = Wk; k0 = (blk - 12) * 64; dst = Wk_pk + (size_t)(blk - 12) * 16384; }
    else if (blk < 28) { src = Wv; k0 = (blk - 24) * 64; dst = Wv_pk + (size_t)(blk - 24) * 16384; }
    else if (blk < 44) {
        const int i = blk - 28; const int p = i >> 2, c = i & 3;
        src = W1; Ntot = 1024; n0 = p * 256; k0 = c * 64;
        dst = W1_pk + (size_t)i * 16384;
    }
    else if (blk < 60) { src = W2; k0 = (blk - 44) * 64; dst = W2_pk + (size_t)(blk - 44) * 16384; }
    else               { src = Wo; k0 = (blk - 60) * 64; dst = Wo_pk + (size_t)(blk - 60) * 16384; }

    const int tid = threadIdx.x;
    for (int j = 0; j < 8; ++j) {
        const int fi = j * 256 + tid;
        const int lane = fi & 63;
        const int t2 = fi >> 6;          // nt*2+kk
        const int nt = t2 >> 1, kk = t2 & 1;
        const int col = lane & 15, q4 = lane >> 4;
        const int n = n0 + nt * 16 + col;
        const int kbase = k0 + kk * 32 + q4 * 8;
        us8 v;
        #pragma unroll
        for (int e = 0; e < 8; ++e)
            v[e] = bf16rn(src[(size_t)(kbase + e) * Ntot + n]);
        *(us8*)(dst + (size_t)fi * 8) = v;
    }
}

// ---------------------------------------------------------------------------
// Kernel 1: q/k time-conv + v as fragment-packed-B GEMMs. (unchanged)
// ---------------------------------------------------------------------------
__global__ __launch_bounds__(256) void k_qkv_gemm(
    const unsigned short* __restrict__ xb16,
    const unsigned short* __restrict__ Wq_pk, const unsigned short* __restrict__ Wk_pk,
    const unsigned short* __restrict__ Wv_pk,
    const float* __restrict__ bq, const float* __restrict__ bk,
    const float* __restrict__ bv,
    unsigned short* __restrict__ qpk, unsigned short* __restrict__ kpk,
    unsigned short* __restrict__ vpk)
{
    __shared__ __align__(16) unsigned short As[128][72];
    __shared__ __align__(16) unsigned short Bs[16384];   // 32 KB, fragment-linear

    const int tid = threadIdx.x, w = tid >> 6, lane = tid & 63;
    const int col = lane & 15, q4 = lane >> 4;
    const int wr = w >> 1, wc = w & 1;
    const int y = blockIdx.y;
    const int bn = blockIdx.x >> 1, half = blockIdx.x & 1, t0 = half * 128;
    const int nch = (y == 2) ? 4 : 12;
    const unsigned short* Wpk = (y == 0) ? Wq_pk : (y == 1) ? Wk_pk : Wv_pk;

    f32x4 acc[4][8];
    #pragma unroll
    for (int m = 0; m < 4; ++m)
        #pragma unroll
        for (int n = 0; n < 8; ++n)
            acc[m][n] = (f32x4){0.f, 0.f, 0.f, 0.f};

    const int arow = tid >> 1, ahalf = (tid & 1) * 32;

    for (int c = 0; c < nch; ++c) {
        const int s  = (y == 2) ? 1 : (c >> 2);
        const int c0 = (y == 2) ? (c * 64) : ((c & 3) * 64);

        // A: issue global loads (conv-shifted row; clamp + zero at seq edges)
        const int trow = t0 + s - 1 + arow;
        const bool ok = (trow >= 0) && (trow < 256);
        const int trc = ok ? trow : (trow < 0 ? 0 : 255);
        const unsigned short* ap = xb16 + ((size_t)bn * 256 + trc) * 256 + c0 + ahalf;
        us8 av[4];
        #pragma unroll
        for (int j = 0; j < 4; ++j)
            av[j] = *(const us8*)(ap + j * 8);

        // B: async global->LDS, 8 x 1KB per wave, fully linear
        const char* wb = (const char*)(Wpk + (size_t)c * 16384);
        #pragma unroll
        for (int r = 0; r < 8; ++r) {
            const int boff = (r * 4 + w) * 1024;
            gload_lds16(wb + boff + lane * 16, ((char*)Bs) + boff);
        }

        // A: write to padded LDS (zero OOB rows)
        #pragma unroll
        for (int j = 0; j < 4; ++j) {
            us8 v = av[j];
            if (!ok) v = (us8){0, 0, 0, 0, 0, 0, 0, 0};
            *(us8*)&As[arow][ahalf + j * 8] = v;
        }
        __syncthreads();

        #pragma unroll
        for (int kk = 0; kk < 2; ++kk) {
            bfrag a[4], b[8];
            #pragma unroll
            for (int m = 0; m < 4; ++m)
                a[m] = *(const bfrag*)&As[wr * 64 + m * 16 + col][kk * 32 + q4 * 8];
            #pragma unroll
            for (int n = 0; n < 8; ++n)
                b[n] = *(const bfrag*)&Bs[(((wc * 8 + n) * 2 + kk) * 64 + lane) * 8];
            #pragma unroll
            for (int n = 0; n < 8; ++n)
                #pragma unroll
                for (int m = 0; m < 4; ++m)
                    acc[m][n] = __builtin_amdgcn_mfma_f32_16x16x32_bf16(a[m], b[n], acc[m][n], 0, 0, 0);
        }
        __syncthreads();
    }

    if (y == 2) {
        // V: fragment-packed (PV B-operand order), us4 stores (4 consecutive s).
        #pragma unroll
        for (int n = 0; n < 8; ++n) {
            const int nn = wc * 128 + n * 16 + col;
            const int hh = nn >> 5, d = nn & 31;
            const float bb = bv[nn];
            #pragma unroll
            for (int m = 0; m < 4; ++m) {
                const int s0 = t0 + wr * 64 + m * 16 + q4 * 4;
                us4 pk;
                #pragma unroll
                for (int r = 0; r < 4; ++r)
                    pk[r] = bf16rn(acc[m][n][r] + bb);
                const int kc = (s0 >> 5) & 7, q3 = (s0 >> 3) & 3, e0 = s0 & 7;
                *(us4*)(vpk + (((((size_t)bn * 8 + hh) * 8 + kc) * 2 + (d >> 4)) * 64
                               + (d & 15) + 16 * q3) * 8 + e0) = pk;
            }
        }
    } else {
        // Q/K: fragment-packed (QK A/B operand order), scalar u16 stores.
        unsigned short* dst = (y == 0) ? qpk : kpk;
        const float* bias = (y == 0) ? bq : bk;
        #pragma unroll
        for (int n = 0; n < 8; ++n) {
            const int nn = wc * 128 + n * 16 + col;
            const int hh = nn >> 5, hd = nn & 31;
            const float bb = bias[nn];
            #pragma unroll
            for (int m = 0; m < 4; ++m) {
                const int tile = (t0 >> 4) + wr * 4 + m;
                unsigned short* dp = dst
                    + ((((size_t)bn * 8 + hh) * 16 + tile) * 64 + 16 * (hd >> 3)) * 8
                    + (hd & 7);
                #pragma unroll
                for (int r = 0; r < 4; ++r)
                    dp[(q4 * 4 + r) * 8] = bf16rn(acc[m][n][r] + bb);
            }
        }
    }
}

// ---------------------------------------------------------------------------
// Kernel 2: MFMA attention. (unchanged)
// ---------------------------------------------------------------------------
__global__ __launch_bounds__(256) void k_attn_mfma(
    const unsigned short* __restrict__ qpk, const unsigned short* __restrict__ kpk,
    const unsigned short* __restrict__ vpk, unsigned short* __restrict__ ob)
{
    __shared__ __align__(16) unsigned short KsL[8192];     // 16 KB, frag-linear
    __shared__ __align__(16) unsigned short Pw[4][16][264];// per-wave P scratch

    const int bn   = blockIdx.x;
    const int h    = blockIdx.y;
    const int tid  = threadIdx.x;
    const int w    = tid >> 6;
    const int lane = tid & 63;
    const int col  = lane & 15;
    const int q4   = lane >> 4;
    const size_t bhi = (size_t)bn * 8 + h;
    const size_t obase = (size_t)bn * S2_ * D_ + h * HD_;
    const unsigned short* qbase = qpk + bhi * 8192;
    const unsigned short* vbase = vpk + bhi * 8192;
    const float SCL2E = 0.17677669529663687f * 1.4426950408889634f; // 1/sqrt(32)*log2(e)

    // ---- stage K frags via async DMA: 16 x 1KB chunks, wave-linear ----
    {
        const char* kb = (const char*)(kpk + bhi * 8192);
        #pragma unroll
        for (int r = 0; r < 4; ++r) {
            const int fi = r * 4 + w;
            gload_lds16(kb + fi * 1024 + lane * 16, ((char*)KsL) + fi * 1024);
        }
    }
    __syncthreads();

    for (int mt = 0; mt < 4; ++mt) {
        // ---- Q A-frag (one 16B load, frag-linear) ----
        bfrag qa = *(const bfrag*)(qbase + ((size_t)(w * 4 + mt) * 64 + lane) * 8);

        // ---- scores: 16 n-tiles, one MFMA each (K=32 = full HD) ----
        f32x4 sc[16];
        #pragma unroll
        for (int nt = 0; nt < 16; ++nt) {
            bfrag kf = *(const bfrag*)&KsL[(nt * 64 + lane) * 8];
            f32x4 z = {0.f, 0.f, 0.f, 0.f};
            sc[nt] = __builtin_amdgcn_mfma_f32_16x16x32_bf16(qa, kf, z, 0, 0, 0);
        }

        // ---- softmax over 256 cols (scale folded with log2e; exp2) ----
        float mx[4] = {-1e30f, -1e30f, -1e30f, -1e30f};
        #pragma unroll
        for (int nt = 0; nt < 16; ++nt)
            #pragma unroll
            for (int r = 0; r < 4; ++r) {
                sc[nt][r] *= SCL2E;
                mx[r] = fmaxf(mx[r], sc[nt][r]);
            }
        #pragma unroll
        for (int r = 0; r < 4; ++r) {
            mx[r] = fmaxf(mx[r], __shfl_xor(mx[r], 1));
            mx[r] = fmaxf(mx[r], __shfl_xor(mx[r], 2));
            mx[r] = fmaxf(mx[r], __shfl_xor(mx[r], 4));
            mx[r] = fmaxf(mx[r], __shfl_xor(mx[r], 8));
        }
        float l[4] = {0.f, 0.f, 0.f, 0.f};
        #pragma unroll
        for (int nt = 0; nt < 16; ++nt)
            #pragma unroll
            for (int r = 0; r < 4; ++r) {
                const float e = exp2f(sc[nt][r] - mx[r]);
                sc[nt][r] = e;
                l[r] += e;
            }
        #pragma unroll
        for (int r = 0; r < 4; ++r) {
            l[r] += __shfl_xor(l[r], 1);
            l[r] += __shfl_xor(l[r], 2);
            l[r] += __shfl_xor(l[r], 4);
            l[r] += __shfl_xor(l[r], 8);
        }

        // ---- P -> per-wave LDS (bf16), direct all-lane u16 stores ----
        #pragma unroll
        for (int nt = 0; nt < 16; ++nt)
            #pragma unroll
            for (int r = 0; r < 4; ++r)
                Pw[w][q4 * 4 + r][nt * 16 + col] = bf16rn(sc[nt][r]);
        // same-wave DS ordering: reads below see the writes (in-order DS pipe)

        // ---- PV: o[16 x 32], V B-frags direct from packed global ----
        f32x4 oacc[2];
        oacc[0] = (f32x4){0.f, 0.f, 0.f, 0.f};
        oacc[1] = (f32x4){0.f, 0.f, 0.f, 0.f};
        #pragma unroll
        for (int kc = 0; kc < 8; ++kc) {
            bfrag pa = *(const bfrag*)&Pw[w][col][kc * 32 + q4 * 8];
            bfrag v0 = *(const bfrag*)(vbase + ((size_t)(kc * 2 + 0) * 64 + lane) * 8);
            bfrag v1 = *(const bfrag*)(vbase + ((size_t)(kc * 2 + 1) * 64 + lane) * 8);
            oacc[0] = __builtin_amdgcn_mfma_f32_16x16x32_bf16(pa, v0, oacc[0], 0, 0, 0);
            oacc[1] = __builtin_amdgcn_mfma_f32_16x16x32_bf16(pa, v1, oacc[1], 0, 0, 0);
        }

        // ---- normalize + write ----
        const int r0w = w * 64;
        float inv[4];
        #pragma unroll
        for (int r = 0; r < 4; ++r) inv[r] = 1.f / l[r];
        #pragma unroll
        for (int dt = 0; dt < 2; ++dt)
            #pragma unroll
            for (int r = 0; r < 4; ++r)
                ob[obase + (size_t)(r0w + mt * 16 + q4 * 4 + r) * D_ + dt * 16 + col]
                    = bf16rn(oacc[dt][r] * inv[r]);
    }
}

// ---------------------------------------------------------------------------
// Kernel 3: o @ Wo + bo + residual(x) -> LN1 -> hb (bf16), MFMA.
// hb lives in the old xb16 region (outside ff's span).
// ---------------------------------------------------------------------------
__global__ __launch_bounds__(256) void k_oproj_gemm(
    const unsigned short* __restrict__ ob,
    const unsigned short* __restrict__ Wo_pk, const float* __restrict__ bo,
    const float* __restrict__ x,
    const float* __restrict__ g1, const float* __restrict__ be1,
    unsigned short* __restrict__ hb)
{
    __shared__ __align__(16) unsigned short As[128][72];
    __shared__ __align__(16) unsigned short Bs[16384];
    __shared__ float red[128][2][2];

    const int tid = threadIdx.x, w = tid >> 6, lane = tid & 63;
    const int col = lane & 15, q4 = lane >> 4;
    const int wr = w >> 1, wc = w & 1;
    const size_t tok0 = (size_t)blockIdx.x * 128;

    f32x4 acc[4][8];
    #pragma unroll
    for (int m = 0; m < 4; ++m)
        #pragma unroll
        for (int n = 0; n < 8; ++n)
            acc[m][n] = (f32x4){0.f, 0.f, 0.f, 0.f};

    const int arow = tid >> 1, ahalf = (tid & 1) * 32;

    for (int c = 0; c < 4; ++c) {
        const unsigned short* ap = ob + (tok0 + arow) * D_ + c * 64 + ahalf;
        us8 av[4];
        #pragma unroll
        for (int j = 0; j < 4; ++j)
            av[j] = *(const us8*)(ap + j * 8);

        const char* wb = (const char*)(Wo_pk + (size_t)c * 16384);
        #pragma unroll
        for (int r = 0; r < 8; ++r) {
            const int boff = (r * 4 + w) * 1024;
            gload_lds16(wb + boff + lane * 16, ((char*)Bs) + boff);
        }

        #pragma unroll
        for (int j = 0; j < 4; ++j)
            *(us8*)&As[arow][ahalf + j * 8] = av[j];
        __syncthreads();

        #pragma unroll
        for (int kk = 0; kk < 2; ++kk) {
            bfrag a[4], b[8];
            #pragma unroll
            for (int m = 0; m < 4; ++m)
                a[m] = *(const bfrag*)&As[wr * 64 + m * 16 + col][kk * 32 + q4 * 8];
            #pragma unroll
            for (int n = 0; n < 8; ++n)
                b[n] = *(const bfrag*)&Bs[(((wc * 8 + n) * 2 + kk) * 64 + lane) * 8];
            #pragma unroll
            for (int n = 0; n < 8; ++n)
                #pragma unroll
                for (int m = 0; m < 4; ++m)
                    acc[m][n] = __builtin_amdgcn_mfma_f32_16x16x32_bf16(a[m], b[n], acc[m][n], 0, 0, 0);
        }
        __syncthreads();
    }

    float bov[8];
    #pragma unroll
    for (int n = 0; n < 8; ++n)
        bov[n] = bo[wc * 128 + n * 16 + col];

    float s[4][4], s2[4][4];
    #pragma unroll
    for (int m = 0; m < 4; ++m)
        #pragma unroll
        for (int r = 0; r < 4; ++r) { s[m][r] = 0.f; s2[m][r] = 0.f; }

    #pragma unroll
    for (int m = 0; m < 4; ++m)
        #pragma unroll
        for (int r = 0; r < 4; ++r) {
            const size_t row = tok0 + wr * 64 + m * 16 + q4 * 4 + r;
            #pragma unroll
            for (int n = 0; n < 8; ++n) {
                const int nn = wc * 128 + n * 16 + col;
                const float yv = acc[m][n][r] + bov[n] + x[row * D_ + nn];
                acc[m][n][r] = yv;
                s[m][r] += yv;
                s2[m][r] = fmaf(yv, yv, s2[m][r]);
            }
        }

    #pragma unroll
    for (int m = 0; m < 4; ++m)
        #pragma unroll
        for (int r = 0; r < 4; ++r) {
            #pragma unroll
            for (int d = 1; d < 16; d <<= 1) {
                s[m][r]  += __shfl_xor(s[m][r],  d);
                s2[m][r] += __shfl_xor(s2[m][r], d);
            }
        }

    if (col == 0) {
        #pragma unroll
        for (int m = 0; m < 4; ++m)
            #pragma unroll
            for (int r = 0; r < 4; ++r) {
                const int rl = wr * 64 + m * 16 + q4 * 4 + r;
                red[rl][wc][0] = s[m][r];
                red[rl][wc][1] = s2[m][r];
            }
    }
    __syncthreads();

    float mu[4][4], rs[4][4];
    #pragma unroll
    for (int m = 0; m < 4; ++m)
        #pragma unroll
        for (int r = 0; r < 4; ++r) {
            const int rl = wr * 64 + m * 16 + q4 * 4 + r;
            const float ts  = red[rl][0][0] + red[rl][1][0];
            const float ts2 = red[rl][0][1] + red[rl][1][1];
            const float m_  = ts * (1.f / 256.f);
            mu[m][r] = m_;
            rs[m][r] = rsqrtf(ts2 * (1.f / 256.f) - m_ * m_ + EPS_);
        }

    #pragma unroll
    for (int n = 0; n < 8; ++n) {
        const int nn = wc * 128 + n * 16 + col;
        const float gv = g1[nn], bev = be1[nn];
        #pragma unroll
        for (int m = 0; m < 4; ++m)
            #pragma unroll
            for (int r = 0; r < 4; ++r) {
                const size_t row = tok0 + wr * 64 + m * 16 + q4 * 4 + r;
                hb[row * D_ + nn] = bf16rn((acc[m][n][r] - mu[m][r]) * rs[m][r] * gv + bev);
            }
    }
}

// ---------------------------------------------------------------------------
// Kernel 4a: ff = leaky(hb @ W1 + b1).  A direct us8 loads from bf16 hb.
// grid (512, 4): y = N-panel of 256. K=256 (4 chunks).
// ---------------------------------------------------------------------------
__global__ __launch_bounds__(256) void k_ffn1_gemm(
    const unsigned short* __restrict__ hb,
    const unsigned short* __restrict__ W1_pk, const float* __restrict__ b1,
    unsigned short* __restrict__ ff)
{
    __shared__ __align__(16) unsigned short As[128][72];
    __shared__ __align__(16) unsigned short Bs[16384];

    const int tid = threadIdx.x, w = tid >> 6, lane = tid & 63;
    const int col = lane & 15, q4 = lane >> 4;
    const int wr = w >> 1, wc = w & 1;
    const size_t tok0 = (size_t)blockIdx.x * 128;
    const int y = blockIdx.y;                 // n-panel
    const unsigned short* Wpk = W1_pk + (size_t)y * 4 * 16384;

    f32x4 acc[4][8];
    #pragma unroll
    for (int m = 0; m < 4; ++m)
        #pragma unroll
        for (int n = 0; n < 8; ++n)
            acc[m][n] = (f32x4){0.f, 0.f, 0.f, 0.f};

    const int arow = tid >> 1, ahalf = (tid & 1) * 32;

    for (int c = 0; c < 4; ++c) {
        const unsigned short* ap = hb + (tok0 + arow) * D_ + c * 64 + ahalf;
        us8 av[4];
        #pragma unroll
        for (int j = 0; j < 4; ++j)
            av[j] = *(const us8*)(ap + j * 8);

        const char* wb = (const char*)(Wpk + (size_t)c * 16384);
        #pragma unroll
        for (int r = 0; r < 8; ++r) {
            const int boff = (r * 4 + w) * 1024;
            gload_lds16(wb + boff + lane * 16, ((char*)Bs) + boff);
        }

        #pragma unroll
        for (int j = 0; j < 4; ++j)
            *(us8*)&As[arow][ahalf + j * 8] = av[j];
        __syncthreads();

        #pragma unroll
        for (int kk = 0; kk < 2; ++kk) {
            bfrag a[4], b[8];
            #pragma unroll
            for (int m = 0; m < 4; ++m)
                a[m] = *(const bfrag*)&As[wr * 64 + m * 16 + col][kk * 32 + q4 * 8];
            #pragma unroll
            for (int n = 0; n < 8; ++n)
                b[n] = *(const bfrag*)&Bs[(((wc * 8 + n) * 2 + kk) * 64 + lane) * 8];
            #pragma unroll
            for (int n = 0; n < 8; ++n)
                #pragma unroll
                for (int m = 0; m < 4; ++m)
                    acc[m][n] = __builtin_amdgcn_mfma_f32_16x16x32_bf16(a[m], b[n], acc[m][n], 0, 0, 0);
        }
        __syncthreads();
    }

    #pragma unroll
    for (int n = 0; n < 8; ++n) {
        const int nglob = y * 256 + wc * 128 + n * 16 + col;
        const float bb = b1[nglob];
        #pragma unroll
        for (int m = 0; m < 4; ++m)
            #pragma unroll
            for (int r = 0; r < 4; ++r) {
                float v = acc[m][n][r] + bb;
                v = (v > 0.f) ? v : NEG_ * v;
                ff[(tok0 + wr * 64 + m * 16 + q4 * 4 + r) * (size_t)F_ + nglob] = bf16rn(v);
            }
    }
}

// ---------------------------------------------------------------------------
// Kernel 4b: out = LN2(ff @ W2 + b2 + hb).  K=1024 (16 chunks), N=256 full row.
// ---------------------------------------------------------------------------
__global__ __launch_bounds__(256) void k_ffn2_gemm(
    const unsigned short* __restrict__ ff,
    const unsigned short* __restrict__ W2_pk, const float* __restrict__ b2,
    const unsigned short* __restrict__ hb,
    const float* __restrict__ g2, const float* __restrict__ be2,
    float* __restrict__ out)
{
    __shared__ __align__(16) unsigned short As[128][72];
    __shared__ __align__(16) unsigned short Bs[16384];
    __shared__ float red[128][2][2];

    const int tid = threadIdx.x, w = tid >> 6, lane = tid & 63;
    const int col = lane & 15, q4 = lane >> 4;
    const int wr = w >> 1, wc = w & 1;
    const size_t tok0 = (size_t)blockIdx.x * 128;

    f32x4 acc[4][8];
    #pragma unroll
    for (int m = 0; m < 4; ++m)
        #pragma unroll
        for (int n = 0; n < 8; ++n)
            acc[m][n] = (f32x4){0.f, 0.f, 0.f, 0.f};

    const int arow = tid >> 1, ahalf = (tid & 1) * 32;

    for (int c = 0; c < 16; ++c) {
        const unsigned short* ap = ff + (tok0 + arow) * (size_t)F_ + c * 64 + ahalf;
        us8 av[4];
        #pragma unroll
        for (int j = 0; j < 4; ++j)
            av[j] = *(const us8*)(ap + j * 8);

        const char* wb = (const char*)(W2_pk + (size_t)c * 16384);
        #pragma unroll
        for (int r = 0; r < 8; ++r) {
            const int boff = (r * 4 + w) * 1024;
            gload_lds16(wb + boff + lane * 16, ((char*)Bs) + boff);
        }

        #pragma unroll
        for (int j = 0; j < 4; ++j)
            *(us8*)&As[arow][ahalf + j * 8] = av[j];
        __syncthreads();

        #pragma unroll
        for (int kk = 0; kk < 2; ++kk) {
            bfrag a[4], b[8];
            #pragma unroll
            for (int m = 0; m < 4; ++m)
                a[m] = *(const bfrag*)&As[wr * 64 + m * 16 + col][kk * 32 + q4 * 8];
            #pragma unroll
            for (int n = 0; n < 8; ++n)
                b[n] = *(const bfrag*)&Bs[(((wc * 8 + n) * 2 + kk) * 64 + lane) * 8];
            #pragma unroll
            for (int n = 0; n < 8; ++n)
                #pragma unroll
                for (int m = 0; m < 4; ++m)
                    acc[m][n] = __builtin_amdgcn_mfma_f32_16x16x32_bf16(a[m], b[n], acc[m][n], 0, 0, 0);
        }
        __syncthreads();
    }

    float b2v[8];
    #pragma unroll
    for (int n = 0; n < 8; ++n)
        b2v[n] = b2[wc * 128 + n * 16 + col];

    float s[4][4], s2[4][4];
    #pragma unroll
    for (int m = 0; m < 4; ++m)
        #pragma unroll
        for (int r = 0; r < 4; ++r) { s[m][r] = 0.f; s2[m][r] = 0.f; }

    #pragma unroll
    for (int m = 0; m < 4; ++m)
        #pragma unroll
        for (int r = 0; r < 4; ++r) {
            const size_t row = tok0 + wr * 64 + m * 16 + q4 * 4 + r;
            #pragma unroll
            for (int n = 0; n < 8; ++n) {
                const int nn = wc * 128 + n * 16 + col;
                const float yv = acc[m][n][r] + b2v[n] + bf2f(hb[row * D_ + nn]);
                acc[m][n][r] = yv;
                s[m][r] += yv;
                s2[m][r] = fmaf(yv, yv, s2[m][r]);
            }
        }

    #pragma unroll
    for (int m = 0; m < 4; ++m)
        #pragma unroll
        for (int r = 0; r < 4; ++r) {
            #pragma unroll
            for (int d = 1; d < 16; d <<= 1) {
                s[m][r]  += __shfl_xor(s[m][r],  d);
                s2[m][r] += __shfl_xor(s2[m][r], d);
            }
        }

    if (col == 0) {
        #pragma unroll
        for (int m = 0; m < 4; ++m)
            #pragma unroll
            for (int r = 0; r < 4; ++r) {
                const int rl = wr * 64 + m * 16 + q4 * 4 + r;
                red[rl][wc][0] = s[m][r];
                red[rl][wc][1] = s2[m][r];
            }
    }
    __syncthreads();

    float mu[4][4], rs[4][4];
    #pragma unroll
    for (int m = 0; m < 4; ++m)
        #pragma unroll
        for (int r = 0; r < 4; ++r) {
            const int rl = wr * 64 + m * 16 + q4 * 4 + r;
            const float ts  = red[rl][0][0] + red[rl][1][0];
            const float ts2 = red[rl][0][1] + red[rl][1][1];
            const float m_  = ts * (1.f / 256.f);
            mu[m][r] = m_;
            rs[m][r] = rsqrtf(ts2 * (1.f / 256.f) - m_ * m_ + EPS_);
        }

    #pragma unroll
    for (int n = 0; n < 8; ++n) {
        const int nn = wc * 128 + n * 16 + col;
        const float gv = g2[nn], bev = be2[nn];
        #pragma unroll
        for (int m = 0; m < 4; ++m)
            #pragma unroll
            for (int r = 0; r < 4; ++r) {
                const size_t row = tok0 + wr * 64 + m * 16 + q4 * 4 + r;
                out[row * D_ + nn] = (acc[m][n][r] - mu[m][r]) * rs[m][r] * gv + bev;
            }
    }
}

// ---------------------------------------------------------------------------
extern "C" void kernel_launch(void* const* d_in, const int* in_sizes, int n_in,
                              void* d_out, int out_size, void* d_ws, size_t ws_size,
                              hipStream_t stream)
{
    const float* x   = (const float*)d_in[0];
    const float* Wq  = (const float*)d_in[1];
    const float* bq  = (const float*)d_in[2];
    const float* Wk  = (const float*)d_in[3];
    const float* bk  = (const float*)d_in[4];
    const float* Wv  = (const float*)d_in[5];
    const float* bv  = (const float*)d_in[6];
    const float* Wo  = (const float*)d_in[7];
    const float* bo  = (const float*)d_in[8];
    const float* W1  = (const float*)d_in[9];
    const float* b1  = (const float*)d_in[10];
    const float* W2  = (const float*)d_in[11];
    const float* b2  = (const float*)d_in[12];
    const float* g1  = (const float*)d_in[13];
    const float* be1 = (const float*)d_in[14];
    const float* g2  = (const float*)d_in[15];
    const float* be2 = (const float*)d_in[16];
    float* out = (float*)d_out;

    const size_t N = (size_t)B_ * S1_ * S2_ * D_;   // 16,777,216 elements

    unsigned short* qpk = (unsigned short*)d_ws;    // frag-packed per (bn,h)
    unsigned short* kpk = qpk + N;
    unsigned short* vpk = kpk + N;
    unsigned short* ob  = vpk + N;
    float*          h   = (float*)(ob + N);         // region reserved (2N shorts)
    unsigned short* Wq_pk = (unsigned short*)(h + N);
    unsigned short* Wk_pk = Wq_pk + (size_t)12 * 16384;   // 196608
    unsigned short* Wv_pk = Wk_pk + (size_t)12 * 16384;
    unsigned short* Wo_pk = Wv_pk + (size_t)4 * 16384;    // 65536
    unsigned short* W1_pk = Wo_pk + (size_t)4 * 16384;
    unsigned short* W2_pk = W1_pk + (size_t)16 * 16384;   // 262144
    const size_t need = (size_t)(W2_pk + (size_t)16 * 16384 - (unsigned short*)d_ws) * 2;
    if (ws_size < need) return;

    // Aliases (lifetime-disjoint):
    unsigned short* xb16 = (unsigned short*)h;   // dead after k_qkv_gemm
    unsigned short* hb   = (unsigned short*)h;   // written by oproj (after xb16 dead)
    unsigned short* ff   = qpk;                  // spans qpk..ob; all dead after oproj

    k_xcast     <<<dim3((unsigned)(N / 2048)), 256, 0, stream>>>(x, xb16);
    k_pack      <<<dim3(64), 256, 0, stream>>>(Wq, Wk, Wv, Wo, W1, W2,
                    Wq_pk, Wk_pk, Wv_pk, Wo_pk, W1_pk, W2_pk);
    k_qkv_gemm  <<<dim3(512, 3), 256, 0, stream>>>(
                    xb16, Wq_pk, Wk_pk, Wv_pk, bq, bk, bv, qpk, kpk, vpk);
    k_attn_mfma <<<dim3(B_ * S1_, H_), 256, 0, stream>>>(qpk, kpk, vpk, ob);
    k_oproj_gemm<<<dim3(512), 256, 0, stream>>>(
                    ob, Wo_pk, bo, x, g1, be1, hb);
    k_ffn1_gemm <<<dim3(512, 4), 256, 0, stream>>>(hb, W1_pk, b1, ff);
    k_ffn2_gemm <<<dim3(512), 256, 0, stream>>>(ff, W2_pk, b2, hb, g2, be2, out);
}

// Round 8
// 548.306 us; speedup vs baseline: 1.8047x; 1.0994x over previous
//
#include <hip/hip_runtime.h>
#include <hip/hip_bf16.h>

// Problem constants
#define B_ 4
#define S1_ 64
#define S2_ 256
#define D_ 256
#define H_ 8
#define HD_ 32
#define F_ 1024
#define EPS_ 1e-5f
#define NEG_ 0.01f

typedef __attribute__((ext_vector_type(8))) short bfrag;   // 8 x bf16 (4 VGPRs)
typedef __attribute__((ext_vector_type(4))) float f32x4;   // MFMA C/D
typedef __attribute__((ext_vector_type(8))) unsigned short us8;
typedef __attribute__((ext_vector_type(4))) unsigned short us4;

__device__ __forceinline__ unsigned short bf16rn(float f) {
    union { float f; unsigned int u; } c; c.f = f;
    unsigned int u = c.u;
    u = (u + 0x7FFFu + ((u >> 16) & 1u)) >> 16;   // round-to-nearest-even
    return (unsigned short)u;
}
__device__ __forceinline__ float bf2f(unsigned short s) {
    union { unsigned int u; float f; } c; c.u = ((unsigned int)s) << 16;
    return c.f;
}

// async global->LDS, 16B per lane. lds base must be wave-uniform; HW adds lane*16.
__device__ __forceinline__ void gload_lds16(const void* g, void* l) {
    __builtin_amdgcn_global_load_lds(
        (const __attribute__((address_space(1))) void*)g,
        (__attribute__((address_space(3))) void*)l,
        16, 0, 0);
}

// ---------------------------------------------------------------------------
// x (fp32) -> xb16 (bf16), flat cast. 8 elems/thread.
// ---------------------------------------------------------------------------
__global__ __launch_bounds__(256) void k_xcast(
    const float* __restrict__ x, unsigned short* __restrict__ xb16)
{
    const size_t i = ((size_t)blockIdx.x * 256 + threadIdx.x) * 8;
    float4 f0 = *(const float4*)(x + i);
    float4 f1 = *(const float4*)(x + i + 4);
    us8 v;
    v[0] = bf16rn(f0.x); v[1] = bf16rn(f0.y); v[2] = bf16rn(f0.z); v[3] = bf16rn(f0.w);
    v[4] = bf16rn(f1.x); v[5] = bf16rn(f1.y); v[6] = bf16rn(f1.z); v[7] = bf16rn(f1.w);
    *(us8*)(xb16 + i) = v;
}

// ---------------------------------------------------------------------------
// Weight pack (unchanged): [k][n] -> MFMA fragment order per BK=64 chunk.
// ---------------------------------------------------------------------------
__global__ __launch_bounds__(256) void k_pack(
    const float* __restrict__ Wq, const float* __restrict__ Wk,
    const float* __restrict__ Wv, const float* __restrict__ Wo,
    const float* __restrict__ W1, const float* __restrict__ W2,
    unsigned short* __restrict__ Wq_pk, unsigned short* __restrict__ Wk_pk,
    unsigned short* __restrict__ Wv_pk, unsigned short* __restrict__ Wo_pk,
    unsigned short* __restrict__ W1_pk, unsigned short* __restrict__ W2_pk)
{
    const int blk = blockIdx.x;
    const float* src; unsigned short* dst; int Ntot = 256, n0 = 0, k0;
    if (blk < 12)      { src = Wq; k0 = blk * 64;        dst = Wq_pk + (size_t)blk * 16384; }
    else if (blk < 24) { src = Wk; k0 = (blk - 12) * 64; dst = Wk_pk + (size_t)(blk - 12) * 16384; }
    else if (blk < 28) { src = Wv; k0 = (blk - 24) * 64; dst = Wv_pk + (size_t)(blk - 24) * 16384; }
    else if (blk < 44) {
        const int i = blk - 28; const int p = i >> 2, c = i & 3;
        src = W1; Ntot = 1024; n0 = p * 256; k0 = c * 64;
        dst = W1_pk + (size_t)i * 16384;
    }
    else if (blk < 60) { src = W2; k0 = (blk - 44) * 64; dst = W2_pk + (size_t)(blk - 44) * 16384; }
    else               { src = Wo; k0 = (blk - 60) * 64; dst = Wo_pk + (size_t)(blk - 60) * 16384; }

    const int tid = threadIdx.x;
    for (int j = 0; j < 8; ++j) {
        const int fi = j * 256 + tid;
        const int lane = fi & 63;
        const int t2 = fi >> 6;          // nt*2+kk
        const int nt = t2 >> 1, kk = t2 & 1;
        const int col = lane & 15, q4 = lane >> 4;
        const int n = n0 + nt * 16 + col;
        const int kbase = k0 + kk * 32 + q4 * 8;
        us8 v;
        #pragma unroll
        for (int e = 0; e < 8; ++e)
            v[e] = bf16rn(src[(size_t)(kbase + e) * Ntot + n]);
        *(us8*)(dst + (size_t)fi * 8) = v;
    }
}

// ---------------------------------------------------------------------------
// Kernel 1: q/k time-conv + v GEMMs. 512 threads / 8 waves; each wave owns
// a 64x64 sub-tile (wr=w>>2 row-half, wc=w&3 col-quarter). acc[4][4]=64 VGPR
// -> __launch_bounds__(512,4) pins <=128 VGPR = 4 waves/SIMD (2 blocks/CU).
// ---------------------------------------------------------------------------
__global__ __launch_bounds__(512, 4) void k_qkv_gemm(
    const unsigned short* __restrict__ xb16,
    const unsigned short* __restrict__ Wq_pk, const unsigned short* __restrict__ Wk_pk,
    const unsigned short* __restrict__ Wv_pk,
    const float* __restrict__ bq, const float* __restrict__ bk,
    const float* __restrict__ bv,
    unsigned short* __restrict__ qpk, unsigned short* __restrict__ kpk,
    unsigned short* __restrict__ vpk)
{
    __shared__ __align__(16) unsigned short As[128][72];
    __shared__ __align__(16) unsigned short Bs[16384];   // 32 KB, fragment-linear

    const int tid = threadIdx.x, w = tid >> 6, lane = tid & 63;
    const int col = lane & 15, q4 = lane >> 4;
    const int wr = w >> 2, wc = w & 3;
    const int y = blockIdx.y;
    const int bn = blockIdx.x >> 1, half = blockIdx.x & 1, t0 = half * 128;
    const int nch = (y == 2) ? 4 : 12;
    const unsigned short* Wpk = (y == 0) ? Wq_pk : (y == 1) ? Wk_pk : Wv_pk;

    f32x4 acc[4][4];
    #pragma unroll
    for (int m = 0; m < 4; ++m)
        #pragma unroll
        for (int n = 0; n < 4; ++n)
            acc[m][n] = (f32x4){0.f, 0.f, 0.f, 0.f};

    const int arow = tid >> 2, aq = (tid & 3) * 16;

    for (int c = 0; c < nch; ++c) {
        const int s  = (y == 2) ? 1 : (c >> 2);
        const int c0 = (y == 2) ? (c * 64) : ((c & 3) * 64);

        // A: issue global loads (conv-shifted row; clamp + zero at seq edges)
        const int trow = t0 + s - 1 + arow;
        const bool ok = (trow >= 0) && (trow < 256);
        const int trc = ok ? trow : (trow < 0 ? 0 : 255);
        const unsigned short* ap = xb16 + ((size_t)bn * 256 + trc) * 256 + c0 + aq;
        us8 av[2];
        #pragma unroll
        for (int j = 0; j < 2; ++j)
            av[j] = *(const us8*)(ap + j * 8);

        // B: async global->LDS, 4 x 1KB per wave, fully linear
        const char* wb = (const char*)(Wpk + (size_t)c * 16384);
        #pragma unroll
        for (int r = 0; r < 4; ++r) {
            const int boff = (r * 8 + w) * 1024;
            gload_lds16(wb + boff + lane * 16, ((char*)Bs) + boff);
        }

        // A: write to padded LDS (zero OOB rows)
        #pragma unroll
        for (int j = 0; j < 2; ++j) {
            us8 v = av[j];
            if (!ok) v = (us8){0, 0, 0, 0, 0, 0, 0, 0};
            *(us8*)&As[arow][aq + j * 8] = v;
        }
        __syncthreads();

        #pragma unroll
        for (int kk = 0; kk < 2; ++kk) {
            bfrag a[4], b[4];
            #pragma unroll
            for (int m = 0; m < 4; ++m)
                a[m] = *(const bfrag*)&As[wr * 64 + m * 16 + col][kk * 32 + q4 * 8];
            #pragma unroll
            for (int n = 0; n < 4; ++n)
                b[n] = *(const bfrag*)&Bs[(((wc * 4 + n) * 2 + kk) * 64 + lane) * 8];
            #pragma unroll
            for (int n = 0; n < 4; ++n)
                #pragma unroll
                for (int m = 0; m < 4; ++m)
                    acc[m][n] = __builtin_amdgcn_mfma_f32_16x16x32_bf16(a[m], b[n], acc[m][n], 0, 0, 0);
        }
        __syncthreads();
    }

    if (y == 2) {
        // V: fragment-packed (PV B-operand order), us4 stores (4 consecutive s).
        #pragma unroll
        for (int n = 0; n < 4; ++n) {
            const int nn = wc * 64 + n * 16 + col;
            const int hh = nn >> 5, d = nn & 31;
            const float bb = bv[nn];
            #pragma unroll
            for (int m = 0; m < 4; ++m) {
                const int s0 = t0 + wr * 64 + m * 16 + q4 * 4;
                us4 pk;
                #pragma unroll
                for (int r = 0; r < 4; ++r)
                    pk[r] = bf16rn(acc[m][n][r] + bb);
                const int kc = (s0 >> 5) & 7, q3 = (s0 >> 3) & 3, e0 = s0 & 7;
                *(us4*)(vpk + (((((size_t)bn * 8 + hh) * 8 + kc) * 2 + (d >> 4)) * 64
                               + (d & 15) + 16 * q3) * 8 + e0) = pk;
            }
        }
    } else {
        // Q/K: fragment-packed (QK A/B operand order), scalar u16 stores.
        unsigned short* dst = (y == 0) ? qpk : kpk;
        const float* bias = (y == 0) ? bq : bk;
        #pragma unroll
        for (int n = 0; n < 4; ++n) {
            const int nn = wc * 64 + n * 16 + col;
            const int hh = nn >> 5, hd = nn & 31;
            const float bb = bias[nn];
            #pragma unroll
            for (int m = 0; m < 4; ++m) {
                const int tile = (t0 >> 4) + wr * 4 + m;
                unsigned short* dp = dst
                    + ((((size_t)bn * 8 + hh) * 16 + tile) * 64 + 16 * (hd >> 3)) * 8
                    + (hd & 7);
                #pragma unroll
                for (int r = 0; r < 4; ++r)
                    dp[(q4 * 4 + r) * 8] = bf16rn(acc[m][n][r] + bb);
            }
        }
    }
}

// ---------------------------------------------------------------------------
// Kernel 2: MFMA attention. (unchanged)
// ---------------------------------------------------------------------------
__global__ __launch_bounds__(256) void k_attn_mfma(
    const unsigned short* __restrict__ qpk, const unsigned short* __restrict__ kpk,
    const unsigned short* __restrict__ vpk, unsigned short* __restrict__ ob)
{
    __shared__ __align__(16) unsigned short KsL[8192];     // 16 KB, frag-linear
    __shared__ __align__(16) unsigned short Pw[4][16][264];// per-wave P scratch

    const int bn   = blockIdx.x;
    const int h    = blockIdx.y;
    const int tid  = threadIdx.x;
    const int w    = tid >> 6;
    const int lane = tid & 63;
    const int col  = lane & 15;
    const int q4   = lane >> 4;
    const size_t bhi = (size_t)bn * 8 + h;
    const size_t obase = (size_t)bn * S2_ * D_ + h * HD_;
    const unsigned short* qbase = qpk + bhi * 8192;
    const unsigned short* vbase = vpk + bhi * 8192;
    const float SCL2E = 0.17677669529663687f * 1.4426950408889634f; // 1/sqrt(32)*log2(e)

    // ---- stage K frags via async DMA: 16 x 1KB chunks, wave-linear ----
    {
        const char* kb = (const char*)(kpk + bhi * 8192);
        #pragma unroll
        for (int r = 0; r < 4; ++r) {
            const int fi = r * 4 + w;
            gload_lds16(kb + fi * 1024 + lane * 16, ((char*)KsL) + fi * 1024);
        }
    }
    __syncthreads();

    for (int mt = 0; mt < 4; ++mt) {
        // ---- Q A-frag (one 16B load, frag-linear) ----
        bfrag qa = *(const bfrag*)(qbase + ((size_t)(w * 4 + mt) * 64 + lane) * 8);

        // ---- scores: 16 n-tiles, one MFMA each (K=32 = full HD) ----
        f32x4 sc[16];
        #pragma unroll
        for (int nt = 0; nt < 16; ++nt) {
            bfrag kf = *(const bfrag*)&KsL[(nt * 64 + lane) * 8];
            f32x4 z = {0.f, 0.f, 0.f, 0.f};
            sc[nt] = __builtin_amdgcn_mfma_f32_16x16x32_bf16(qa, kf, z, 0, 0, 0);
        }

        // ---- softmax over 256 cols (scale folded with log2e; exp2) ----
        float mx[4] = {-1e30f, -1e30f, -1e30f, -1e30f};
        #pragma unroll
        for (int nt = 0; nt < 16; ++nt)
            #pragma unroll
            for (int r = 0; r < 4; ++r) {
                sc[nt][r] *= SCL2E;
                mx[r] = fmaxf(mx[r], sc[nt][r]);
            }
        #pragma unroll
        for (int r = 0; r < 4; ++r) {
            mx[r] = fmaxf(mx[r], __shfl_xor(mx[r], 1));
            mx[r] = fmaxf(mx[r], __shfl_xor(mx[r], 2));
            mx[r] = fmaxf(mx[r], __shfl_xor(mx[r], 4));
            mx[r] = fmaxf(mx[r], __shfl_xor(mx[r], 8));
        }
        float l[4] = {0.f, 0.f, 0.f, 0.f};
        #pragma unroll
        for (int nt = 0; nt < 16; ++nt)
            #pragma unroll
            for (int r = 0; r < 4; ++r) {
                const float e = exp2f(sc[nt][r] - mx[r]);
                sc[nt][r] = e;
                l[r] += e;
            }
        #pragma unroll
        for (int r = 0; r < 4; ++r) {
            l[r] += __shfl_xor(l[r], 1);
            l[r] += __shfl_xor(l[r], 2);
            l[r] += __shfl_xor(l[r], 4);
            l[r] += __shfl_xor(l[r], 8);
        }

        // ---- P -> per-wave LDS (bf16), direct all-lane u16 stores ----
        #pragma unroll
        for (int nt = 0; nt < 16; ++nt)
            #pragma unroll
            for (int r = 0; r < 4; ++r)
                Pw[w][q4 * 4 + r][nt * 16 + col] = bf16rn(sc[nt][r]);
        // same-wave DS ordering: reads below see the writes (in-order DS pipe)

        // ---- PV: o[16 x 32], V B-frags direct from packed global ----
        f32x4 oacc[2];
        oacc[0] = (f32x4){0.f, 0.f, 0.f, 0.f};
        oacc[1] = (f32x4){0.f, 0.f, 0.f, 0.f};
        #pragma unroll
        for (int kc = 0; kc < 8; ++kc) {
            bfrag pa = *(const bfrag*)&Pw[w][col][kc * 32 + q4 * 8];
            bfrag v0 = *(const bfrag*)(vbase + ((size_t)(kc * 2 + 0) * 64 + lane) * 8);
            bfrag v1 = *(const bfrag*)(vbase + ((size_t)(kc * 2 + 1) * 64 + lane) * 8);
            oacc[0] = __builtin_amdgcn_mfma_f32_16x16x32_bf16(pa, v0, oacc[0], 0, 0, 0);
            oacc[1] = __builtin_amdgcn_mfma_f32_16x16x32_bf16(pa, v1, oacc[1], 0, 0, 0);
        }

        // ---- normalize + write ----
        const int r0w = w * 64;
        float inv[4];
        #pragma unroll
        for (int r = 0; r < 4; ++r) inv[r] = 1.f / l[r];
        #pragma unroll
        for (int dt = 0; dt < 2; ++dt)
            #pragma unroll
            for (int r = 0; r < 4; ++r)
                ob[obase + (size_t)(r0w + mt * 16 + q4 * 4 + r) * D_ + dt * 16 + col]
                    = bf16rn(oacc[dt][r] * inv[r]);
    }
}

// ---------------------------------------------------------------------------
// Kernel 3: o @ Wo + bo + residual(x) -> LN1 -> hb (bf16), MFMA. (unchanged)
// ---------------------------------------------------------------------------
__global__ __launch_bounds__(256) void k_oproj_gemm(
    const unsigned short* __restrict__ ob,
    const unsigned short* __restrict__ Wo_pk, const float* __restrict__ bo,
    const float* __restrict__ x,
    const float* __restrict__ g1, const float* __restrict__ be1,
    unsigned short* __restrict__ hb)
{
    __shared__ __align__(16) unsigned short As[128][72];
    __shared__ __align__(16) unsigned short Bs[16384];
    __shared__ float red[128][2][2];

    const int tid = threadIdx.x, w = tid >> 6, lane = tid & 63;
    const int col = lane & 15, q4 = lane >> 4;
    const int wr = w >> 1, wc = w & 1;
    const size_t tok0 = (size_t)blockIdx.x * 128;

    f32x4 acc[4][8];
    #pragma unroll
    for (int m = 0; m < 4; ++m)
        #pragma unroll
        for (int n = 0; n < 8; ++n)
            acc[m][n] = (f32x4){0.f, 0.f, 0.f, 0.f};

    const int arow = tid >> 1, ahalf = (tid & 1) * 32;

    for (int c = 0; c < 4; ++c) {
        const unsigned short* ap = ob + (tok0 + arow) * D_ + c * 64 + ahalf;
        us8 av[4];
        #pragma unroll
        for (int j = 0; j < 4; ++j)
            av[j] = *(const us8*)(ap + j * 8);

        const char* wb = (const char*)(Wo_pk + (size_t)c * 16384);
        #pragma unroll
        for (int r = 0; r < 8; ++r) {
            const int boff = (r * 4 + w) * 1024;
            gload_lds16(wb + boff + lane * 16, ((char*)Bs) + boff);
        }

        #pragma unroll
        for (int j = 0; j < 4; ++j)
            *(us8*)&As[arow][ahalf + j * 8] = av[j];
        __syncthreads();

        #pragma unroll
        for (int kk = 0; kk < 2; ++kk) {
            bfrag a[4], b[8];
            #pragma unroll
            for (int m = 0; m < 4; ++m)
                a[m] = *(const bfrag*)&As[wr * 64 + m * 16 + col][kk * 32 + q4 * 8];
            #pragma unroll
            for (int n = 0; n < 8; ++n)
                b[n] = *(const bfrag*)&Bs[(((wc * 8 + n) * 2 + kk) * 64 + lane) * 8];
            #pragma unroll
            for (int n = 0; n < 8; ++n)
                #pragma unroll
                for (int m = 0; m < 4; ++m)
                    acc[m][n] = __builtin_amdgcn_mfma_f32_16x16x32_bf16(a[m], b[n], acc[m][n], 0, 0, 0);
        }
        __syncthreads();
    }

    float bov[8];
    #pragma unroll
    for (int n = 0; n < 8; ++n)
        bov[n] = bo[wc * 128 + n * 16 + col];

    float s[4][4], s2[4][4];
    #pragma unroll
    for (int m = 0; m < 4; ++m)
        #pragma unroll
        for (int r = 0; r < 4; ++r) { s[m][r] = 0.f; s2[m][r] = 0.f; }

    #pragma unroll
    for (int m = 0; m < 4; ++m)
        #pragma unroll
        for (int r = 0; r < 4; ++r) {
            const size_t row = tok0 + wr * 64 + m * 16 + q4 * 4 + r;
            #pragma unroll
            for (int n = 0; n < 8; ++n) {
                const int nn = wc * 128 + n * 16 + col;
                const float yv = acc[m][n][r] + bov[n] + x[row * D_ + nn];
                acc[m][n][r] = yv;
                s[m][r] += yv;
                s2[m][r] = fmaf(yv, yv, s2[m][r]);
            }
        }

    #pragma unroll
    for (int m = 0; m < 4; ++m)
        #pragma unroll
        for (int r = 0; r < 4; ++r) {
            #pragma unroll
            for (int d = 1; d < 16; d <<= 1) {
                s[m][r]  += __shfl_xor(s[m][r],  d);
                s2[m][r] += __shfl_xor(s2[m][r], d);
            }
        }

    if (col == 0) {
        #pragma unroll
        for (int m = 0; m < 4; ++m)
            #pragma unroll
            for (int r = 0; r < 4; ++r) {
                const int rl = wr * 64 + m * 16 + q4 * 4 + r;
                red[rl][wc][0] = s[m][r];
                red[rl][wc][1] = s2[m][r];
            }
    }
    __syncthreads();

    float mu[4][4], rs[4][4];
    #pragma unroll
    for (int m = 0; m < 4; ++m)
        #pragma unroll
        for (int r = 0; r < 4; ++r) {
            const int rl = wr * 64 + m * 16 + q4 * 4 + r;
            const float ts  = red[rl][0][0] + red[rl][1][0];
            const float ts2 = red[rl][0][1] + red[rl][1][1];
            const float m_  = ts * (1.f / 256.f);
            mu[m][r] = m_;
            rs[m][r] = rsqrtf(ts2 * (1.f / 256.f) - m_ * m_ + EPS_);
        }

    #pragma unroll
    for (int n = 0; n < 8; ++n) {
        const int nn = wc * 128 + n * 16 + col;
        const float gv = g1[nn], bev = be1[nn];
        #pragma unroll
        for (int m = 0; m < 4; ++m)
            #pragma unroll
            for (int r = 0; r < 4; ++r) {
                const size_t row = tok0 + wr * 64 + m * 16 + q4 * 4 + r;
                hb[row * D_ + nn] = bf16rn((acc[m][n][r] - mu[m][r]) * rs[m][r] * gv + bev);
            }
    }
}

// ---------------------------------------------------------------------------
// Kernel 4a: ff = leaky(hb @ W1 + b1). (unchanged)
// ---------------------------------------------------------------------------
__global__ __launch_bounds__(256) void k_ffn1_gemm(
    const unsigned short* __restrict__ hb,
    const unsigned short* __restrict__ W1_pk, const float* __restrict__ b1,
    unsigned short* __restrict__ ff)
{
    __shared__ __align__(16) unsigned short As[128][72];
    __shared__ __align__(16) unsigned short Bs[16384];

    const int tid = threadIdx.x, w = tid >> 6, lane = tid & 63;
    const int col = lane & 15, q4 = lane >> 4;
    const int wr = w >> 1, wc = w & 1;
    const size_t tok0 = (size_t)blockIdx.x * 128;
    const int y = blockIdx.y;                 // n-panel
    const unsigned short* Wpk = W1_pk + (size_t)y * 4 * 16384;

    f32x4 acc[4][8];
    #pragma unroll
    for (int m = 0; m < 4; ++m)
        #pragma unroll
        for (int n = 0; n < 8; ++n)
            acc[m][n] = (f32x4){0.f, 0.f, 0.f, 0.f};

    const int arow = tid >> 1, ahalf = (tid & 1) * 32;

    for (int c = 0; c < 4; ++c) {
        const unsigned short* ap = hb + (tok0 + arow) * D_ + c * 64 + ahalf;
        us8 av[4];
        #pragma unroll
        for (int j = 0; j < 4; ++j)
            av[j] = *(const us8*)(ap + j * 8);

        const char* wb = (const char*)(Wpk + (size_t)c * 16384);
        #pragma unroll
        for (int r = 0; r < 8; ++r) {
            const int boff = (r * 4 + w) * 1024;
            gload_lds16(wb + boff + lane * 16, ((char*)Bs) + boff);
        }

        #pragma unroll
        for (int j = 0; j < 4; ++j)
            *(us8*)&As[arow][ahalf + j * 8] = av[j];
        __syncthreads();

        #pragma unroll
        for (int kk = 0; kk < 2; ++kk) {
            bfrag a[4], b[8];
            #pragma unroll
            for (int m = 0; m < 4; ++m)
                a[m] = *(const bfrag*)&As[wr * 64 + m * 16 + col][kk * 32 + q4 * 8];
            #pragma unroll
            for (int n = 0; n < 8; ++n)
                b[n] = *(const bfrag*)&Bs[(((wc * 8 + n) * 2 + kk) * 64 + lane) * 8];
            #pragma unroll
            for (int n = 0; n < 8; ++n)
                #pragma unroll
                for (int m = 0; m < 4; ++m)
                    acc[m][n] = __builtin_amdgcn_mfma_f32_16x16x32_bf16(a[m], b[n], acc[m][n], 0, 0, 0);
        }
        __syncthreads();
    }

    #pragma unroll
    for (int n = 0; n < 8; ++n) {
        const int nglob = y * 256 + wc * 128 + n * 16 + col;
        const float bb = b1[nglob];
        #pragma unroll
        for (int m = 0; m < 4; ++m)
            #pragma unroll
            for (int r = 0; r < 4; ++r) {
                float v = acc[m][n][r] + bb;
                v = (v > 0.f) ? v : NEG_ * v;
                ff[(tok0 + wr * 64 + m * 16 + q4 * 4 + r) * (size_t)F_ + nglob] = bf16rn(v);
            }
    }
}

// ---------------------------------------------------------------------------
// Kernel 4b: out = LN2(ff @ W2 + b2 + hb). (unchanged)
// ---------------------------------------------------------------------------
__global__ __launch_bounds__(256) void k_ffn2_gemm(
    const unsigned short* __restrict__ ff,
    const unsigned short* __restrict__ W2_pk, const float* __restrict__ b2,
    const unsigned short* __restrict__ hb,
    const float* __restrict__ g2, const float* __restrict__ be2,
    float* __restrict__ out)
{
    __shared__ __align__(16) unsigned short As[128][72];
    __shared__ __align__(16) unsigned short Bs[16384];
    __shared__ float red[128][2][2];

    const int tid = threadIdx.x, w = tid >> 6, lane = tid & 63;
    const int col = lane & 15, q4 = lane >> 4;
    const int wr = w >> 1, wc = w & 1;
    const size_t tok0 = (size_t)blockIdx.x * 128;

    f32x4 acc[4][8];
    #pragma unroll
    for (int m = 0; m < 4; ++m)
        #pragma unroll
        for (int n = 0; n < 8; ++n)
            acc[m][n] = (f32x4){0.f, 0.f, 0.f, 0.f};

    const int arow = tid >> 1, ahalf = (tid & 1) * 32;

    for (int c = 0; c < 16; ++c) {
        const unsigned short* ap = ff + (tok0 + arow) * (size_t)F_ + c * 64 + ahalf;
        us8 av[4];
        #pragma unroll
        for (int j = 0; j < 4; ++j)
            av[j] = *(const us8*)(ap + j * 8);

        const char* wb = (const char*)(W2_pk + (size_t)c * 16384);
        #pragma unroll
        for (int r = 0; r < 8; ++r) {
            const int boff = (r * 4 + w) * 1024;
            gload_lds16(wb + boff + lane * 16, ((char*)Bs) + boff);
        }

        #pragma unroll
        for (int j = 0; j < 4; ++j)
            *(us8*)&As[arow][ahalf + j * 8] = av[j];
        __syncthreads();

        #pragma unroll
        for (int kk = 0; kk < 2; ++kk) {
            bfrag a[4], b[8];
            #pragma unroll
            for (int m = 0; m < 4; ++m)
                a[m] = *(const bfrag*)&As[wr * 64 + m * 16 + col][kk * 32 + q4 * 8];
            #pragma unroll
            for (int n = 0; n < 8; ++n)
                b[n] = *(const bfrag*)&Bs[(((wc * 8 + n) * 2 + kk) * 64 + lane) * 8];
            #pragma unroll
            for (int n = 0; n < 8; ++n)
                #pragma unroll
                for (int m = 0; m < 4; ++m)
                    acc[m][n] = __builtin_amdgcn_mfma_f32_16x16x32_bf16(a[m], b[n], acc[m][n], 0, 0, 0);
        }
        __syncthreads();
    }

    float b2v[8];
    #pragma unroll
    for (int n = 0; n < 8; ++n)
        b2v[n] = b2[wc * 128 + n * 16 + col];

    float s[4][4], s2[4][4];
    #pragma unroll
    for (int m = 0; m < 4; ++m)
        #pragma unroll
        for (int r = 0; r < 4; ++r) { s[m][r] = 0.f; s2[m][r] = 0.f; }

    #pragma unroll
    for (int m = 0; m < 4; ++m)
        #pragma unroll
        for (int r = 0; r < 4; ++r) {
            const size_t row = tok0 + wr * 64 + m * 16 + q4 * 4 + r;
            #pragma unroll
            for (int n = 0; n < 8; ++n) {
                const int nn = wc * 128 + n * 16 + col;
                const float yv = acc[m][n][r] + b2v[n] + bf2f(hb[row * D_ + nn]);
                acc[m][n][r] = yv;
                s[m][r] += yv;
                s2[m][r] = fmaf(yv, yv, s2[m][r]);
            }
        }

    #pragma unroll
    for (int m = 0; m < 4; ++m)
        #pragma unroll
        for (int r = 0; r < 4; ++r) {
            #pragma unroll
            for (int d = 1; d < 16; d <<= 1) {
                s[m][r]  += __shfl_xor(s[m][r],  d);
                s2[m][r] += __shfl_xor(s2[m][r], d);
            }
        }

    if (col == 0) {
        #pragma unroll
        for (int m = 0; m < 4; ++m)
            #pragma unroll
            for (int r = 0; r < 4; ++r) {
                const int rl = wr * 64 + m * 16 + q4 * 4 + r;
                red[rl][wc][0] = s[m][r];
                red[rl][wc][1] = s2[m][r];
            }
    }
    __syncthreads();

    float mu[4][4], rs[4][4];
    #pragma unroll
    for (int m = 0; m < 4; ++m)
        #pragma unroll
        for (int r = 0; r < 4; ++r) {
            const int rl = wr * 64 + m * 16 + q4 * 4 + r;
            const float ts  = red[rl][0][0] + red[rl][1][0];
            const float ts2 = red[rl][0][1] + red[rl][1][1];
            const float m_  = ts * (1.f / 256.f);
            mu[m][r] = m_;
            rs[m][r] = rsqrtf(ts2 * (1.f / 256.f) - m_ * m_ + EPS_);
        }

    #pragma unroll
    for (int n = 0; n < 8; ++n) {
        const int nn = wc * 128 + n * 16 + col;
        const float gv = g2[nn], bev = be2[nn];
        #pragma unroll
        for (int m = 0; m < 4; ++m)
            #pragma unroll
            for (int r = 0; r < 4; ++r) {
                const size_t row = tok0 + wr * 64 + m * 16 + q4 * 4 + r;
                out[row * D_ + nn] = (acc[m][n][r] - mu[m][r]) * rs[m][r] * gv + bev;
            }
    }
}

// ---------------------------------------------------------------------------
extern "C" void kernel_launch(void* const* d_in, const int* in_sizes, int n_in,
                              void* d_out, int out_size, void* d_ws, size_t ws_size,
                              hipStream_t stream)
{
    const float* x   = (const float*)d_in[0];
    const float* Wq  = (const float*)d_in[1];
    const float* bq  = (const float*)d_in[2];
    const float* Wk  = (const float*)d_in[3];
    const float* bk  = (const float*)d_in[4];
    const float* Wv  = (const float*)d_in[5];
    const float* bv  = (const float*)d_in[6];
    const float* Wo  = (const float*)d_in[7];
    const float* bo  = (const float*)d_in[8];
    const float* W1  = (const float*)d_in[9];
    const float* b1  = (const float*)d_in[10];
    const float* W2  = (const float*)d_in[11];
    const float* b2  = (const float*)d_in[12];
    const float* g1  = (const float*)d_in[13];
    const float* be1 = (const float*)d_in[14];
    const float* g2  = (const float*)d_in[15];
    const float* be2 = (const float*)d_in[16];
    float* out = (float*)d_out;

    const size_t N = (size_t)B_ * S1_ * S2_ * D_;   // 16,777,216 elements

    unsigned short* qpk = (unsigned short*)d_ws;    // frag-packed per (bn,h)
    unsigned short* kpk = qpk + N;
    unsigned short* vpk = kpk + N;
    unsigned short* ob  = vpk + N;
    float*          h   = (float*)(ob + N);         // region reserved (2N shorts)
    unsigned short* Wq_pk = (unsigned short*)(h + N);
    unsigned short* Wk_pk = Wq_pk + (size_t)12 * 16384;   // 196608
    unsigned short* Wv_pk = Wk_pk + (size_t)12 * 16384;
    unsigned short* Wo_pk = Wv_pk + (size_t)4 * 16384;    // 65536
    unsigned short* W1_pk = Wo_pk + (size_t)4 * 16384;
    unsigned short* W2_pk = W1_pk + (size_t)16 * 16384;   // 262144
    const size_t need = (size_t)(W2_pk + (size_t)16 * 16384 - (unsigned short*)d_ws) * 2;
    if (ws_size < need) return;

    // Aliases (lifetime-disjoint):
    unsigned short* xb16 = (unsigned short*)h;   // dead after k_qkv_gemm
    unsigned short* hb   = (unsigned short*)h;   // written by oproj (after xb16 dead)
    unsigned short* ff   = qpk;                  // spans qpk..ob; all dead after oproj

    k_xcast     <<<dim3((unsigned)(N / 2048)), 256, 0, stream>>>(x, xb16);
    k_pack      <<<dim3(64), 256, 0, stream>>>(Wq, Wk, Wv, Wo, W1, W2,
                    Wq_pk, Wk_pk, Wv_pk, Wo_pk, W1_pk, W2_pk);
    k_qkv_gemm  <<<dim3(512, 3), 512, 0, stream>>>(
                    xb16, Wq_pk, Wk_pk, Wv_pk, bq, bk, bv, qpk, kpk, vpk);
    k_attn_mfma <<<dim3(B_ * S1_, H_), 256, 0, stream>>>(qpk, kpk, vpk, ob);
    k_oproj_gemm<<<dim3(512), 256, 0, stream>>>(
                    ob, Wo_pk, bo, x, g1, be1, hb);
    k_ffn1_gemm <<<dim3(512, 4), 256, 0, stream>>>(hb, W1_pk, b1, ff);
    k_ffn2_gemm <<<dim3(512), 256, 0, stream>>>(ff, W2_pk, b2, hb, g2, be2, out);
}